// Round 7
// baseline (54274.011 us; speedup 1.0000x reference)
//
#include <hip/hip_runtime.h>
#include <math.h>

// Problem dims
#define TSTEPS 512
#define BSZ    64
#define INDIM  256
#define HDIM   1024
#define G4     4096
#define N0TOT  5120   // 4096 gate cols + 1024 proj cols
#define K0TOT  1280   // 256 (x) + 1024 (h0)
#define K1TOT  2048   // 1024 (h0') + 1024 (h1)
#define LN_EPS 1e-5f

#define NBLK   256
#define NTHR   1024

// LDS: W1 strip [16 cols][2056] hi then lo (pad 8)
#define LDS_LDK    2056
#define LDS_LO_OFF (16 * LDS_LDK)
#define LDS_W_BYTES (2 * 16 * LDS_LDK * 2)      // 131,584
#define LDS_BYTES  (LDS_W_BYTES + 256)          // + reduce scratch

typedef short          s8v __attribute__((ext_vector_type(8)));
typedef float          f4v __attribute__((ext_vector_type(4)));
typedef unsigned short u16;

__device__ __forceinline__ u16 f2bf(float f) {
    unsigned u = __float_as_uint(f);
    u += 0x7FFFu + ((u >> 16) & 1u);            // RNE
    return (u16)(u >> 16);
}
__device__ __forceinline__ float bf2f(u16 h) {
    return __uint_as_float(((unsigned)h) << 16);
}
__device__ __forceinline__ float sigm(float x) { return 1.f / (1.f + expf(-x)); }

// ---- coherent (sc1, L2-bypass) accessors for cross-block mutable data ----
// R4 lesson: agent ACQUIRE-load spin -> buffer_inv per poll -> cache death.
// R5 lesson: RMW polls serialize on one line at the coherent point.
// R6 lesson: the remaining cost was the per-barrier agent FENCES themselves:
//   release->buffer_wbl2, acquire->buffer_inv, whole-L2 tag walks issued
//   32x/XCD per barrier; they also evict W0 every step (FETCH ~24MB/step).
// R7: NO fences at all. Cross-block data uses relaxed agent atomics (sc1:
// write-through to L3, read from L3). Read-only data (x, W0, W1-staging,
// bias, LN params) uses normal cached loads -> L2 stays warm forever.
__device__ __forceinline__ unsigned long long ald64(const void* p) {
    return __hip_atomic_load((unsigned long long*)p, __ATOMIC_RELAXED,
                             __HIP_MEMORY_SCOPE_AGENT);
}
__device__ __forceinline__ s8v ald16B(const u16* p) {
    union { unsigned long long q[2]; s8v v; } u;
    u.q[0] = ald64((const void*)p);
    u.q[1] = ald64((const void*)(p + 4));
    return u.v;
}
__device__ __forceinline__ float aldf(const float* p) {
    unsigned v = __hip_atomic_load((unsigned*)p, __ATOMIC_RELAXED,
                                   __HIP_MEMORY_SCOPE_AGENT);
    return __uint_as_float(v);
}
__device__ __forceinline__ void astf(float* p, float v) {
    __hip_atomic_store((unsigned*)p, __float_as_uint(v), __ATOMIC_RELAXED,
                       __HIP_MEMORY_SCOPE_AGENT);
}
__device__ __forceinline__ void asth(u16* p, u16 v) {
    __hip_atomic_store(p, v, __ATOMIC_RELAXED, __HIP_MEMORY_SCOPE_AGENT);
}

// ---------------- grid barrier (fence-free) -------------------------------
// Every thread drains its sc1 stores (vmcnt), block syncs, thread0 arrives
// with one relaxed RMW (pipelined at L3), polls with relaxed LOADS (plain
// L3 reads: concurrent, non-invalidating), s_sleep backoff.
__device__ __forceinline__ void grid_barrier(int* ctr, int expect_total)
{
    asm volatile("s_waitcnt vmcnt(0)" ::: "memory");
    __syncthreads();
    if (threadIdx.x == 0) {
        __hip_atomic_fetch_add(ctr, 1, __ATOMIC_RELAXED,
                               __HIP_MEMORY_SCOPE_AGENT);
        while (__hip_atomic_load(ctr, __ATOMIC_RELAXED,
                                 __HIP_MEMORY_SCOPE_AGENT) < expect_total)
            __builtin_amdgcn_s_sleep(4);                 // ~0.1us backoff
        asm volatile("" ::: "memory");
    }
    __syncthreads();
}

// ---------------- GEMM0 task: one 16x16 tile, K-split 2 ------------------
__device__ __forceinline__ void taskA(int task, int t, int lane,
    const u16* __restrict__ xhi, const u16* __restrict__ xlo,
    const u16* __restrict__ h0hi, const u16* __restrict__ h0lo,
    const u16* __restrict__ W0thi, const u16* __restrict__ W0tlo,
    float* __restrict__ parts0)
{
    const int ks  = task & 1;
    const int tile = task >> 1;
    const int rt  = tile & 3;
    const int ct  = tile >> 2;
    const int row = lane & 15;
    const int kg  = lane >> 4;
    const int m   = rt * 16 + row;
    const int n   = ct * 16 + row;
    int kbeg = ks * 640, kend = kbeg + 640;
    const int klim = (ct >= 256) ? INDIM : K0TOT;
    if (kend > klim) kend = klim;

    f4v acc = {0.f, 0.f, 0.f, 0.f};
    const u16* wh = W0thi + (size_t)n * K0TOT;
    const u16* wl = W0tlo + (size_t)n * K0TOT;

    for (int kc = kbeg; kc < kend; kc += 32) {
        const int kk = kc + kg * 8;
        s8v Ah, Al;
        if (kc < INDIM) {                       // x segment: read-only, cached
            size_t o = ((size_t)(t * BSZ + m)) * INDIM + kk;
            Ah = *(const s8v*)(xhi + o);
            Al = *(const s8v*)(xlo + o);
        } else {                                // h segment: coherent sc1
            size_t o = (size_t)m * HDIM + (kk - INDIM);
            Ah = ald16B(h0hi + o);
            Al = ald16B(h0lo + o);
        }
        s8v Bh = *(const s8v*)(wh + kk);        // W0: cached, L2-resident
        s8v Bl = *(const s8v*)(wl + kk);
        acc = __builtin_amdgcn_mfma_f32_16x16x32_bf16(Ah, Bh, acc, 0, 0, 0);
        acc = __builtin_amdgcn_mfma_f32_16x16x32_bf16(Ah, Bl, acc, 0, 0, 0);
        acc = __builtin_amdgcn_mfma_f32_16x16x32_bf16(Al, Bh, acc, 0, 0, 0);
    }
    float* Cp = parts0 + (size_t)ks * BSZ * N0TOT;
#pragma unroll
    for (int r = 0; r < 4; ++r)
        astf(&Cp[(size_t)(rt * 16 + kg * 4 + r) * N0TOT + ct * 16 + row], acc[r]);
}

// ---------------- GEMM1 task: block owns 16 cols (LDS strip) --------------
__device__ __forceinline__ void taskC(int blk, int wv, int lane,
    const u16* __restrict__ shW,
    const u16* __restrict__ h0hi, const u16* __restrict__ h0lo,
    const u16* __restrict__ h1hi, const u16* __restrict__ h1lo,
    float* __restrict__ parts1)
{
    const int rt  = wv & 3;
    const int ks  = wv >> 2;
    const int row = lane & 15;
    const int kg  = lane >> 4;
    const int m   = rt * 16 + row;
    const u16* ahB = (ks < 2) ? h0hi : h1hi;
    const u16* alB = (ks < 2) ? h0lo : h1lo;
    const u16* ah0 = ahB + (size_t)m * HDIM + (ks & 1) * 512;
    const u16* al0 = alB + (size_t)m * HDIM + (ks & 1) * 512;
    const u16* sh  = shW + row * LDS_LDK + ks * 512;
    const u16* sl  = shW + LDS_LO_OFF + row * LDS_LDK + ks * 512;

    f4v acc = {0.f, 0.f, 0.f, 0.f};
#pragma unroll 4
    for (int i = 0; i < 16; ++i) {
        const int kloc = i * 32 + kg * 8;
        s8v Ah = ald16B(ah0 + kloc);
        s8v Al = ald16B(al0 + kloc);
        s8v Bh = *(const s8v*)(sh + kloc);
        s8v Bl = *(const s8v*)(sl + kloc);
        acc = __builtin_amdgcn_mfma_f32_16x16x32_bf16(Ah, Bh, acc, 0, 0, 0);
        acc = __builtin_amdgcn_mfma_f32_16x16x32_bf16(Ah, Bl, acc, 0, 0, 0);
        acc = __builtin_amdgcn_mfma_f32_16x16x32_bf16(Al, Bh, acc, 0, 0, 0);
    }
    float* Cp = parts1 + (size_t)ks * BSZ * G4;
#pragma unroll
    for (int r = 0; r < 4; ++r)
        astf(&Cp[(size_t)(rt * 16 + kg * 4 + r) * G4 + blk * 16 + row], acc[r]);
}

// ---------------- block-wide sum of (s, q) over 1024 threads --------------
__device__ __forceinline__ float2 blk_sum2(float s, float q, float* red, int tid)
{
#pragma unroll
    for (int off = 32; off; off >>= 1) {
        s += __shfl_down(s, off);
        q += __shfl_down(q, off);
    }
    if ((tid & 63) == 0) { red[(tid >> 6) * 2] = s; red[(tid >> 6) * 2 + 1] = q; }
    __syncthreads();
    float ts = 0.f, tq = 0.f;
#pragma unroll
    for (int i = 0; i < 16; ++i) { ts += red[2 * i]; tq += red[2 * i + 1]; }
    __syncthreads();
    return make_float2(ts, tq);
}

__device__ __forceinline__ float lnorm(float v, float2 sq, float g, float b)
{
    float mean = sq.x * (1.f / 1024.f);
    float var  = sq.y * (1.f / 1024.f) - mean * mean;
    return (v - mean) * rsqrtf(var + LN_EPS) * g + b;
}

// =====================================================================
__global__ __launch_bounds__(NTHR, 4) void persistent(
    const u16* __restrict__ xhi,  const u16* __restrict__ xlo,
    const u16* __restrict__ W0thi, const u16* __restrict__ W0tlo,
    const u16* __restrict__ W1ghi, const u16* __restrict__ W1glo,
    const float* __restrict__ b0, const float* __restrict__ b1,
    const float* __restrict__ lncg, const float* __restrict__ lncb,
    const float* __restrict__ lnhg, const float* __restrict__ lnhb,
    const float* __restrict__ lnog, const float* __restrict__ lnob,
    float* __restrict__ parts0, float* __restrict__ parts1,
    u16* __restrict__ h0hi, u16* __restrict__ h0lo,
    u16* __restrict__ h1hi, u16* __restrict__ h1lo,
    float* __restrict__ out, int* bar)
{
    extern __shared__ char smem[];
    u16*   shW = (u16*)smem;
    float* red = (float*)(smem + LDS_W_BYTES);

    const int blk  = blockIdx.x;
    const int tid  = threadIdx.x;
    const int wv   = tid >> 6;
    const int lane = tid & 63;
    int nbar = 0;

    // per-thread recurrent state (blocks 0..63 own batch row b=blk, elem n=tid)
    float c0reg = 0.f, c1reg = 0.f, h0reg = 0.f, h1reg = 0.f;

    // ---- prologue: LDS W1 strip (block owns cols blk*16..+16) ----
    {
        const size_t gcol = (size_t)(blk * 16 + wv) * K1TOT;
        for (int j = lane * 8; j < K1TOT; j += 512) {
            *(s8v*)(shW + wv * LDS_LDK + j)              = *(const s8v*)(W1ghi + gcol + j);
            *(s8v*)(shW + LDS_LO_OFF + wv * LDS_LDK + j) = *(const s8v*)(W1glo + gcol + j);
        }
    }
    // ---- zero bf16 h states (coherent stores) ----
    if (blk < 64) {
        asth(&h0hi[blk * HDIM + tid], 0);
        asth(&h0lo[blk * HDIM + tid], 0);
        asth(&h1hi[blk * HDIM + tid], 0);
        asth(&h1lo[blk * HDIM + tid], 0);
    }
    grid_barrier(bar, (++nbar) * NBLK);

    // ---- A(0) ----
    if (blk >= 64) {
        int wid = (blk - 64) * 16 + wv;
        if (wid < 2560)
            taskA(wid, 0, lane, xhi, xlo, h0hi, h0lo, W0thi, W0tlo, parts0);
    }
    grid_barrier(bar, (++nbar) * NBLK);

    for (int t = 0; t < TSTEPS; ++t) {
        // ---- phase B: cell0 (blocks 0..63, row b = blk) ----
        if (blk < 64) {
            const int b = blk, n = tid;
            const float* P0 = parts0 + (size_t)b * N0TOT;
            const float* P1 = parts0 + (size_t)(BSZ + b) * N0TOT;
            float gi = aldf(&P0[n])        + aldf(&P1[n])        + b0[n];
            float gf = aldf(&P0[1024 + n]) + aldf(&P1[1024 + n]) + b0[1024 + n];
            float gg = aldf(&P0[2048 + n]) + aldf(&P1[2048 + n]) + b0[2048 + n];
            float go = aldf(&P0[3072 + n]) + aldf(&P1[3072 + n]) + b0[3072 + n];
            float xp = aldf(&P0[4096 + n]) + aldf(&P1[4096 + n]);
            float cv = sigm(gf) * c0reg + expf(gi) * tanhf(gg);
            float2 r = blk_sum2(cv, cv * cv, red, tid);
            float cl = lnorm(cv, r, lncg[n], lncb[n]);
            c0reg = cl;
            float hv = sigm(go) * tanhf(cl);
            r = blk_sum2(hv, hv * hv, red, tid);
            float hl = lnorm(hv, r, lnhg[n], lnhb[n]) + xp;
            r = blk_sum2(hl, hl * hl, red, tid);
            float hn = lnorm(hl, r, lnog[n], lnob[n]);
            h0reg = hn;
            u16 hi = f2bf(hn);
            asth(&h0hi[b * HDIM + n], hi);
            asth(&h0lo[b * HDIM + n], f2bf(hn - bf2f(hi)));
        }
        grid_barrier(bar, (++nbar) * NBLK);

        // ---- phase C: GEMM1 (all blocks, own 16-col LDS strip) ----
        taskC(blk, wv, lane, shW, h0hi, h0lo, h1hi, h1lo, parts1);
        grid_barrier(bar, (++nbar) * NBLK);

        // ---- phase D (cell1, blocks 0..63) || A(t+1) (blocks 64..255) ----
        if (blk < 64) {
            const int b = blk, n = tid;
            const float* P0 = parts1 + (size_t)b * G4;
            const float* P1 = parts1 + (size_t)(64 + b) * G4;
            const float* P2 = parts1 + (size_t)(128 + b) * G4;
            const float* P3 = parts1 + (size_t)(192 + b) * G4;
            float gi = aldf(&P0[n]) + aldf(&P1[n]) + aldf(&P2[n]) + aldf(&P3[n]) + b1[n];
            float gf = aldf(&P0[1024 + n]) + aldf(&P1[1024 + n]) + aldf(&P2[1024 + n]) + aldf(&P3[1024 + n]) + b1[1024 + n];
            float gg = aldf(&P0[2048 + n]) + aldf(&P1[2048 + n]) + aldf(&P2[2048 + n]) + aldf(&P3[2048 + n]) + b1[2048 + n];
            float go = aldf(&P0[3072 + n]) + aldf(&P1[3072 + n]) + aldf(&P2[3072 + n]) + aldf(&P3[3072 + n]) + b1[3072 + n];
            float cv = sigm(gf) * c1reg + expf(gi) * tanhf(gg);
            float2 r = blk_sum2(cv, cv * cv, red, tid);
            float cl = lnorm(cv, r, lncg[HDIM + n], lncb[HDIM + n]);
            c1reg = cl;
            float hv = sigm(go) * tanhf(cl);
            r = blk_sum2(hv, hv * hv, red, tid);
            float hl = lnorm(hv, r, lnhg[HDIM + n], lnhb[HDIM + n]) + h0reg;
            r = blk_sum2(hl, hl * hl, red, tid);
            float hn = lnorm(hl, r, lnog[HDIM + n], lnob[HDIM + n]);
            h1reg = hn;
            u16 hi = f2bf(hn);
            asth(&h1hi[b * HDIM + n], hi);
            asth(&h1lo[b * HDIM + n], f2bf(hn - bf2f(hi)));
            out[(size_t)t * BSZ * HDIM + b * HDIM + n] = hn;   // normal store
        } else if (t + 1 < TSTEPS) {
            int wid = (blk - 64) * 16 + wv;
            if (wid < 2560)
                taskA(wid, t + 1, lane, xhi, xlo, h0hi, h0lo, W0thi, W0tlo, parts0);
        }
        grid_barrier(bar, (++nbar) * NBLK);
    }

    // ---- final states from registers: h0,h1 then c0,c1 ----
    if (blk < 64) {
        const size_t F = (size_t)TSTEPS * BSZ * HDIM;
        out[F +          blk * HDIM + tid] = h0reg;
        out[F +  65536 + blk * HDIM + tid] = h1reg;
        out[F + 131072 + blk * HDIM + tid] = c0reg;
        out[F + 196608 + blk * HDIM + tid] = c1reg;
    }
}

// =====================================================================
// prep kernels
// =====================================================================
__global__ __launch_bounds__(256) void transpose_split(
    const float* __restrict__ src, int N,
    u16* __restrict__ dsthi, u16* __restrict__ dstlo,
    int ldd, int noff, int koff)
{
    __shared__ float tile[32][33];
    const int n0 = blockIdx.x * 32, k0 = blockIdx.y * 32;
    const int tx = threadIdx.x & 31, ty = threadIdx.x >> 5;
#pragma unroll
    for (int i = 0; i < 4; ++i)
        tile[ty + i * 8][tx] = src[(size_t)(k0 + ty + i * 8) * N + n0 + tx];
    __syncthreads();
#pragma unroll
    for (int i = 0; i < 4; ++i) {
        float v = tile[tx][ty + i * 8];
        u16 hi = f2bf(v);
        u16 lo = f2bf(v - bf2f(hi));
        size_t idx = (size_t)(n0 + ty + i * 8 + noff) * ldd + k0 + koff + tx;
        dsthi[idx] = hi;
        dstlo[idx] = lo;
    }
}

__global__ void conv_split(const float* __restrict__ src,
                           u16* __restrict__ hi, u16* __restrict__ lo, int n4)
{
    int i = blockIdx.x * 256 + threadIdx.x;
    if (i < n4) {
        float4 v = ((const float4*)src)[i];
        ushort4 h, l;
        h.x = f2bf(v.x); l.x = f2bf(v.x - bf2f(h.x));
        h.y = f2bf(v.y); l.y = f2bf(v.y - bf2f(h.y));
        h.z = f2bf(v.z); l.z = f2bf(v.z - bf2f(h.z));
        h.w = f2bf(v.w); l.w = f2bf(v.w - bf2f(h.w));
        ((ushort4*)hi)[i] = h;
        ((ushort4*)lo)[i] = l;
    }
}

// =====================================================================
extern "C" void kernel_launch(void* const* d_in, const int* in_sizes, int n_in,
                              void* d_out, int out_size, void* d_ws, size_t ws_size,
                              hipStream_t stream)
{
    const float* x     = (const float*)d_in[0];
    const float* Wproj = (const float*)d_in[1];
    const float* Wx0   = (const float*)d_in[2];
    const float* Wh0   = (const float*)d_in[3];
    const float* b0    = (const float*)d_in[4];
    const float* Wx1   = (const float*)d_in[5];
    const float* Wh1   = (const float*)d_in[6];
    const float* b1    = (const float*)d_in[7];
    const float* lnc_g = (const float*)d_in[8];
    const float* lnc_b = (const float*)d_in[9];
    const float* lnh_g = (const float*)d_in[10];
    const float* lnh_b = (const float*)d_in[11];
    const float* lno_g = (const float*)d_in[12];
    const float* lno_b = (const float*)d_in[13];
    float* out = (float*)d_out;

    // ---- ws layout ----
    char* base = (char*)d_ws;
    size_t o = 0;
    u16* x_hi  = (u16*)(base + o); o += (size_t)TSTEPS * BSZ * INDIM * 2;
    u16* x_lo  = (u16*)(base + o); o += (size_t)TSTEPS * BSZ * INDIM * 2;
    u16* W0thi = (u16*)(base + o); o += (size_t)N0TOT * K0TOT * 2;
    u16* W0tlo = (u16*)(base + o); o += (size_t)N0TOT * K0TOT * 2;
    u16* W1ghi = (u16*)(base + o); o += (size_t)G4 * K1TOT * 2;
    u16* W1glo = (u16*)(base + o); o += (size_t)G4 * K1TOT * 2;
    float* parts0 = (float*)(base + o); o += (size_t)2 * BSZ * N0TOT * 4;
    float* parts1 = (float*)(base + o); o += (size_t)4 * BSZ * G4 * 4;
    u16* h0hi = (u16*)(base + o); o += 65536 * 2;
    u16* h0lo = (u16*)(base + o); o += 65536 * 2;
    u16* h1hi = (u16*)(base + o); o += 65536 * 2;
    u16* h1lo = (u16*)(base + o); o += 65536 * 2;
    int* bar  = (int*)(base + o); o += 256;
    if (ws_size < o) return;

    // ---- prep ----
    conv_split<<<dim3(8192), 256, 0, stream>>>(x, x_hi, x_lo, 2097152);
    hipMemsetAsync(W0thi, 0, (size_t)2 * N0TOT * K0TOT * 2, stream);
    transpose_split<<<dim3(128, 8),  256, 0, stream>>>(Wx0,   G4,   W0thi, W0tlo, K0TOT, 0,    0);
    transpose_split<<<dim3(128, 32), 256, 0, stream>>>(Wh0,   G4,   W0thi, W0tlo, K0TOT, 0,    256);
    transpose_split<<<dim3(32, 8),   256, 0, stream>>>(Wproj, HDIM, W0thi, W0tlo, K0TOT, 4096, 0);
    transpose_split<<<dim3(128, 32), 256, 0, stream>>>(Wx1,   G4,   W1ghi, W1glo, K1TOT, 0,    0);
    transpose_split<<<dim3(128, 32), 256, 0, stream>>>(Wh1,   G4,   W1ghi, W1glo, K1TOT, 0,    1024);
    hipMemsetAsync(bar, 0, 256, stream);

    // ---- the whole recurrence: one persistent kernel ----
    persistent<<<dim3(NBLK), dim3(NTHR), LDS_BYTES, stream>>>(
        x_hi, x_lo, W0thi, W0tlo, W1ghi, W1glo, b0, b1,
        lnc_g, lnc_b, lnh_g, lnh_b, lno_g, lno_b,
        parts0, parts1,
        h0hi, h0lo, h1hi, h1lo, out, bar);
}

// Round 8
// 49373.715 us; speedup vs baseline: 1.0992x; 1.0992x over previous
//
#include <hip/hip_runtime.h>
#include <math.h>

// Problem dims
#define TSTEPS 512
#define BSZ    64
#define INDIM  256
#define HDIM   1024
#define G4     4096
#define N0TOT  5120   // 4096 gate cols + 1024 proj cols
#define K0TOT  1280   // 256 (x) + 1024 (h0)
#define K1TOT  2048   // 1024 (h0') + 1024 (h1)
#define LN_EPS 1e-5f

#define NBLK   256
#define NTHR   1024

// LDS: W1 strip [16 cols][2054] hi then lo.
// Stride 2054 u16 = 1027 dwords == 3 (mod 32): ds_read_b128 bank starts
// (3r + 4kg) mod 32 -> at most a couple of free 2-way aliases (was 8-way
// at stride 1028 == 4 mod 32: SQ_LDS_BANK_CONFLICT 2.68e8).
#define LDS_LDK    2054
#define LDS_LO_OFF (16 * LDS_LDK)
#define LDS_W_BYTES (2 * 16 * LDS_LDK * 2)          // 131,456
#define LDS_STG_OFF LDS_W_BYTES                     // u16 stg[2048] = 4096 B
#define LDS_RED_OFF (LDS_W_BYTES + 4096)            // float red[16] + pad
#define LDS_BYTES   (LDS_W_BYTES + 4096 + 256)

typedef short          s8v __attribute__((ext_vector_type(8)));
typedef float          f4v __attribute__((ext_vector_type(4)));
typedef unsigned short u16;

__device__ __forceinline__ u16 f2bf(float f) {
    unsigned u = __float_as_uint(f);
    u += 0x7FFFu + ((u >> 16) & 1u);            // RNE
    return (u16)(u >> 16);
}
__device__ __forceinline__ float bf2f(u16 h) {
    return __uint_as_float(((unsigned)h) << 16);
}
__device__ __forceinline__ float sigm(float x) { return 1.f / (1.f + expf(-x)); }

// ---- coherent (sc1, L2-bypass) accessors for cross-block mutable data ----
__device__ __forceinline__ unsigned long long ald64(const void* p) {
    return __hip_atomic_load((unsigned long long*)p, __ATOMIC_RELAXED,
                             __HIP_MEMORY_SCOPE_AGENT);
}
__device__ __forceinline__ s8v ald16B(const u16* p) {
    union { unsigned long long q[2]; s8v v; } u;
    u.q[0] = ald64((const void*)p);
    u.q[1] = ald64((const void*)(p + 4));
    return u.v;
}
__device__ __forceinline__ float aldf(const float* p) {
    unsigned v = __hip_atomic_load((unsigned*)p, __ATOMIC_RELAXED,
                                   __HIP_MEMORY_SCOPE_AGENT);
    return __uint_as_float(v);
}
__device__ __forceinline__ void astf(float* p, float v) {
    __hip_atomic_store((unsigned*)p, __float_as_uint(v), __ATOMIC_RELAXED,
                       __HIP_MEMORY_SCOPE_AGENT);
}
// 16B coherent store (inline asm; drained by barrier's vmcnt(0))
__device__ __forceinline__ void ast16B(u16* p, s8v v) {
    asm volatile("global_store_dwordx4 %0, %1, off sc1"
                 :: "v"(p), "v"(v) : "memory");
}

// ---------------- tree grid barrier ---------------------------------------
// R4: acquire-load spin -> buffer_inv storm.   R5: RMW polls serialize.
// R6/R7: poll/fence changes -> NO effect => the invariant was 256
// same-line arrival RMWs serializing at ~100ns each (~30us/barrier).
// R8: 16 groups x 16 blocks. Group g = blk & 15 (all 16 blocks of a group
// live on XCD g%8). Arrive: RMW group line (16-way parallel across 2KB-
// strided lines). 16th arrival pushes root. Leaders (blk<16) poll root,
// then broadcast per-group go word; members poll their go word. Poll
// fan-in per line <= 16. Monotonic counters, no fences (sc1 data plane).
#define GRPS    16
#define GSTRIDE 512   // ints (2 KB) between group lines
__device__ __forceinline__ void grid_barrier(int* bar, int nbar)
{
    asm volatile("s_waitcnt vmcnt(0)" ::: "memory");
    __syncthreads();
    if (threadIdx.x == 0) {
        const int blk = blockIdx.x;
        const int g   = blk & 15;
        int* gctr = bar + g * GSTRIDE;
        int* ggo  = gctr + 32;                   // +128 B, same 2KB area
        int* root = bar + GRPS * GSTRIDE;
        int v = __hip_atomic_fetch_add(gctr, 1, __ATOMIC_RELAXED,
                                       __HIP_MEMORY_SCOPE_AGENT);
        if (v == nbar * 16 - 1)                  // group closer
            __hip_atomic_fetch_add(root, 1, __ATOMIC_RELAXED,
                                   __HIP_MEMORY_SCOPE_AGENT);
        if (blk < 16) {                          // leader of group blk
            while (__hip_atomic_load(root, __ATOMIC_RELAXED,
                                     __HIP_MEMORY_SCOPE_AGENT) < nbar * 16)
                __builtin_amdgcn_s_sleep(8);
            __hip_atomic_store(ggo, nbar, __ATOMIC_RELAXED,
                               __HIP_MEMORY_SCOPE_AGENT);
        } else {
            while (__hip_atomic_load(ggo, __ATOMIC_RELAXED,
                                     __HIP_MEMORY_SCOPE_AGENT) < nbar)
                __builtin_amdgcn_s_sleep(8);
        }
        asm volatile("" ::: "memory");
    }
    __syncthreads();
}

// ---------------- GEMM0 task: one 16x16 tile, K-split 2 ------------------
__device__ __forceinline__ void taskA(int task, int t, int lane,
    const u16* __restrict__ xhi, const u16* __restrict__ xlo,
    const u16* __restrict__ h0hi, const u16* __restrict__ h0lo,
    const u16* __restrict__ W0thi, const u16* __restrict__ W0tlo,
    float* __restrict__ parts0)
{
    const int ks  = task & 1;
    const int tile = task >> 1;
    const int rt  = tile & 3;
    const int ct  = tile >> 2;
    const int row = lane & 15;
    const int kg  = lane >> 4;
    const int m   = rt * 16 + row;
    const int n   = ct * 16 + row;
    int kbeg = ks * 640, kend = kbeg + 640;
    const int klim = (ct >= 256) ? INDIM : K0TOT;
    if (kend > klim) kend = klim;

    f4v acc = {0.f, 0.f, 0.f, 0.f};
    const u16* wh = W0thi + (size_t)n * K0TOT;
    const u16* wl = W0tlo + (size_t)n * K0TOT;

    for (int kc = kbeg; kc < kend; kc += 32) {
        const int kk = kc + kg * 8;
        s8v Ah, Al;
        if (kc < INDIM) {                       // x segment: read-only, cached
            size_t o = ((size_t)(t * BSZ + m)) * INDIM + kk;
            Ah = *(const s8v*)(xhi + o);
            Al = *(const s8v*)(xlo + o);
        } else {                                // h segment: coherent sc1
            size_t o = (size_t)m * HDIM + (kk - INDIM);
            Ah = ald16B(h0hi + o);
            Al = ald16B(h0lo + o);
        }
        s8v Bh = *(const s8v*)(wh + kk);        // W0: cached
        s8v Bl = *(const s8v*)(wl + kk);
        acc = __builtin_amdgcn_mfma_f32_16x16x32_bf16(Ah, Bh, acc, 0, 0, 0);
        acc = __builtin_amdgcn_mfma_f32_16x16x32_bf16(Ah, Bl, acc, 0, 0, 0);
        acc = __builtin_amdgcn_mfma_f32_16x16x32_bf16(Al, Bh, acc, 0, 0, 0);
    }
    float* Cp = parts0 + (size_t)ks * BSZ * N0TOT;
#pragma unroll
    for (int r = 0; r < 4; ++r)
        astf(&Cp[(size_t)(rt * 16 + kg * 4 + r) * N0TOT + ct * 16 + row], acc[r]);
}

// ---------------- GEMM1 task: block owns 16 cols (LDS strip) --------------
__device__ __forceinline__ void taskC(int blk, int wv, int lane,
    const u16* __restrict__ shW,
    const u16* __restrict__ h0hi, const u16* __restrict__ h0lo,
    const u16* __restrict__ h1hi, const u16* __restrict__ h1lo,
    float* __restrict__ parts1)
{
    const int rt  = wv & 3;
    const int ks  = wv >> 2;
    const int row = lane & 15;
    const int kg  = lane >> 4;
    const int m   = rt * 16 + row;
    const u16* ahB = (ks < 2) ? h0hi : h1hi;
    const u16* alB = (ks < 2) ? h0lo : h1lo;
    const u16* ah0 = ahB + (size_t)m * HDIM + (ks & 1) * 512;
    const u16* al0 = alB + (size_t)m * HDIM + (ks & 1) * 512;
    const u16* sh  = shW + row * LDS_LDK + ks * 512;
    const u16* sl  = shW + LDS_LO_OFF + row * LDS_LDK + ks * 512;

    f4v acc = {0.f, 0.f, 0.f, 0.f};
#pragma unroll 4
    for (int i = 0; i < 16; ++i) {
        const int kloc = i * 32 + kg * 8;
        s8v Ah = ald16B(ah0 + kloc);
        s8v Al = ald16B(al0 + kloc);
        s8v Bh = *(const s8v*)(sh + kloc);
        s8v Bl = *(const s8v*)(sl + kloc);
        acc = __builtin_amdgcn_mfma_f32_16x16x32_bf16(Ah, Bh, acc, 0, 0, 0);
        acc = __builtin_amdgcn_mfma_f32_16x16x32_bf16(Ah, Bl, acc, 0, 0, 0);
        acc = __builtin_amdgcn_mfma_f32_16x16x32_bf16(Al, Bh, acc, 0, 0, 0);
    }
    float* Cp = parts1 + (size_t)ks * BSZ * G4;
#pragma unroll
    for (int r = 0; r < 4; ++r)
        astf(&Cp[(size_t)(rt * 16 + kg * 4 + r) * G4 + blk * 16 + row], acc[r]);
}

// ---------------- block-wide sum of (s, q) over 1024 threads --------------
__device__ __forceinline__ float2 blk_sum2(float s, float q, float* red, int tid)
{
#pragma unroll
    for (int off = 32; off; off >>= 1) {
        s += __shfl_down(s, off);
        q += __shfl_down(q, off);
    }
    if ((tid & 63) == 0) { red[(tid >> 6) * 2] = s; red[(tid >> 6) * 2 + 1] = q; }
    __syncthreads();
    float ts = 0.f, tq = 0.f;
#pragma unroll
    for (int i = 0; i < 16; ++i) { ts += red[2 * i]; tq += red[2 * i + 1]; }
    __syncthreads();
    return make_float2(ts, tq);
}

__device__ __forceinline__ float lnorm(float v, float2 sq, float g, float b)
{
    float mean = sq.x * (1.f / 1024.f);
    float var  = sq.y * (1.f / 1024.f) - mean * mean;
    return (v - mean) * rsqrtf(var + LN_EPS) * g + b;
}

// stage h (hi,lo per-thread u16) through LDS -> 16B coherent stores
__device__ __forceinline__ void store_h_16B(u16* stg, int tid,
                                            u16 hi, u16 lo,
                                            u16* dhi, u16* dlo, int base)
{
    stg[tid] = hi;
    stg[1024 + tid] = lo;
    __syncthreads();
    if (tid < 256) {
        const u16* src = stg + (tid >> 7) * 1024 + (tid & 127) * 8;
        s8v v = *(const s8v*)src;
        u16* dst = ((tid >> 7) == 0 ? dhi : dlo) + base + (tid & 127) * 8;
        ast16B(dst, v);
    }
    __syncthreads();
}

// =====================================================================
__global__ __launch_bounds__(NTHR, 4) void persistent(
    const u16* __restrict__ xhi,  const u16* __restrict__ xlo,
    const u16* __restrict__ W0thi, const u16* __restrict__ W0tlo,
    const u16* __restrict__ W1ghi, const u16* __restrict__ W1glo,
    const float* __restrict__ b0, const float* __restrict__ b1,
    const float* __restrict__ lncg, const float* __restrict__ lncb,
    const float* __restrict__ lnhg, const float* __restrict__ lnhb,
    const float* __restrict__ lnog, const float* __restrict__ lnob,
    float* __restrict__ parts0, float* __restrict__ parts1,
    u16* __restrict__ h0hi, u16* __restrict__ h0lo,
    u16* __restrict__ h1hi, u16* __restrict__ h1lo,
    float* __restrict__ out, int* bar)
{
    extern __shared__ char smem[];
    u16*   shW = (u16*)smem;
    u16*   stg = (u16*)(smem + LDS_STG_OFF);
    float* red = (float*)(smem + LDS_RED_OFF);

    const int blk  = blockIdx.x;
    const int tid  = threadIdx.x;
    const int wv   = tid >> 6;
    const int lane = tid & 63;
    int nbar = 0;

    // per-thread recurrent state (blocks 0..63 own batch row b=blk, elem n=tid)
    float c0reg = 0.f, c1reg = 0.f, h0reg = 0.f, h1reg = 0.f;

    // ---- prologue: LDS W1 strip (block owns cols blk*16..+16) ----
    {
        const size_t gcol = (size_t)(blk * 16 + wv) * K1TOT;
        for (int j = lane * 8; j < K1TOT; j += 512) {
            *(s8v*)(shW + wv * LDS_LDK + j)              = *(const s8v*)(W1ghi + gcol + j);
            *(s8v*)(shW + LDS_LO_OFF + wv * LDS_LDK + j) = *(const s8v*)(W1glo + gcol + j);
        }
    }
    // ---- zero bf16 h states (coherent 16B stores) ----
    if (blk < 64 && tid < 128) {
        s8v z = {0,0,0,0,0,0,0,0};
        ast16B(h0hi + blk * HDIM + tid * 8, z);
        ast16B(h0lo + blk * HDIM + tid * 8, z);
        ast16B(h1hi + blk * HDIM + tid * 8, z);
        ast16B(h1lo + blk * HDIM + tid * 8, z);
    }
    grid_barrier(bar, ++nbar);

    // ---- A(0) ----
    if (blk >= 64) {
        int wid = (blk - 64) * 16 + wv;
        if (wid < 2560)
            taskA(wid, 0, lane, xhi, xlo, h0hi, h0lo, W0thi, W0tlo, parts0);
    }
    grid_barrier(bar, ++nbar);

    for (int t = 0; t < TSTEPS; ++t) {
        // ---- phase B: cell0 (blocks 0..63, row b = blk) ----
        if (blk < 64) {
            const int b = blk, n = tid;
            const float* P0 = parts0 + (size_t)b * N0TOT;
            const float* P1 = parts0 + (size_t)(BSZ + b) * N0TOT;
            float gi = aldf(&P0[n])        + aldf(&P1[n])        + b0[n];
            float gf = aldf(&P0[1024 + n]) + aldf(&P1[1024 + n]) + b0[1024 + n];
            float gg = aldf(&P0[2048 + n]) + aldf(&P1[2048 + n]) + b0[2048 + n];
            float go = aldf(&P0[3072 + n]) + aldf(&P1[3072 + n]) + b0[3072 + n];
            float xp = aldf(&P0[4096 + n]) + aldf(&P1[4096 + n]);
            float cv = sigm(gf) * c0reg + expf(gi) * tanhf(gg);
            float2 r = blk_sum2(cv, cv * cv, red, tid);
            float cl = lnorm(cv, r, lncg[n], lncb[n]);
            c0reg = cl;
            float hv = sigm(go) * tanhf(cl);
            r = blk_sum2(hv, hv * hv, red, tid);
            float hl = lnorm(hv, r, lnhg[n], lnhb[n]) + xp;
            r = blk_sum2(hl, hl * hl, red, tid);
            float hn = lnorm(hl, r, lnog[n], lnob[n]);
            h0reg = hn;
            u16 hi = f2bf(hn);
            store_h_16B(stg, tid, hi, f2bf(hn - bf2f(hi)), h0hi, h0lo, b * HDIM);
        }
        grid_barrier(bar, ++nbar);

        // ---- phase C: GEMM1 (all blocks, own 16-col LDS strip) ----
        taskC(blk, wv, lane, shW, h0hi, h0lo, h1hi, h1lo, parts1);
        grid_barrier(bar, ++nbar);

        // ---- phase D (cell1, blocks 0..63) || A(t+1) (blocks 64..255) ----
        if (blk < 64) {
            const int b = blk, n = tid;
            const float* P0 = parts1 + (size_t)b * G4;
            const float* P1 = parts1 + (size_t)(64 + b) * G4;
            const float* P2 = parts1 + (size_t)(128 + b) * G4;
            const float* P3 = parts1 + (size_t)(192 + b) * G4;
            float gi = aldf(&P0[n]) + aldf(&P1[n]) + aldf(&P2[n]) + aldf(&P3[n]) + b1[n];
            float gf = aldf(&P0[1024 + n]) + aldf(&P1[1024 + n]) + aldf(&P2[1024 + n]) + aldf(&P3[1024 + n]) + b1[1024 + n];
            float gg = aldf(&P0[2048 + n]) + aldf(&P1[2048 + n]) + aldf(&P2[2048 + n]) + aldf(&P3[2048 + n]) + b1[2048 + n];
            float go = aldf(&P0[3072 + n]) + aldf(&P1[3072 + n]) + aldf(&P2[3072 + n]) + aldf(&P3[3072 + n]) + b1[3072 + n];
            float cv = sigm(gf) * c1reg + expf(gi) * tanhf(gg);
            float2 r = blk_sum2(cv, cv * cv, red, tid);
            float cl = lnorm(cv, r, lncg[HDIM + n], lncb[HDIM + n]);
            c1reg = cl;
            float hv = sigm(go) * tanhf(cl);
            r = blk_sum2(hv, hv * hv, red, tid);
            float hl = lnorm(hv, r, lnhg[HDIM + n], lnhb[HDIM + n]) + h0reg;
            r = blk_sum2(hl, hl * hl, red, tid);
            float hn = lnorm(hl, r, lnog[HDIM + n], lnob[HDIM + n]);
            h1reg = hn;
            u16 hi = f2bf(hn);
            out[(size_t)t * BSZ * HDIM + b * HDIM + n] = hn;   // normal store
            store_h_16B(stg, tid, hi, f2bf(hn - bf2f(hi)), h1hi, h1lo, b * HDIM);
        } else if (t + 1 < TSTEPS) {
            int wid = (blk - 64) * 16 + wv;
            if (wid < 2560)
                taskA(wid, t + 1, lane, xhi, xlo, h0hi, h0lo, W0thi, W0tlo, parts0);
        }
        grid_barrier(bar, ++nbar);
    }

    // ---- final states from registers: h0,h1 then c0,c1 ----
    if (blk < 64) {
        const size_t F = (size_t)TSTEPS * BSZ * HDIM;
        out[F +          blk * HDIM + tid] = h0reg;
        out[F +  65536 + blk * HDIM + tid] = h1reg;
        out[F + 131072 + blk * HDIM + tid] = c0reg;
        out[F + 196608 + blk * HDIM + tid] = c1reg;
    }
}

// =====================================================================
// prep kernels
// =====================================================================
__global__ __launch_bounds__(256) void transpose_split(
    const float* __restrict__ src, int N,
    u16* __restrict__ dsthi, u16* __restrict__ dstlo,
    int ldd, int noff, int koff)
{
    __shared__ float tile[32][33];
    const int n0 = blockIdx.x * 32, k0 = blockIdx.y * 32;
    const int tx = threadIdx.x & 31, ty = threadIdx.x >> 5;
#pragma unroll
    for (int i = 0; i < 4; ++i)
        tile[ty + i * 8][tx] = src[(size_t)(k0 + ty + i * 8) * N + n0 + tx];
    __syncthreads();
#pragma unroll
    for (int i = 0; i < 4; ++i) {
        float v = tile[tx][ty + i * 8];
        u16 hi = f2bf(v);
        u16 lo = f2bf(v - bf2f(hi));
        size_t idx = (size_t)(n0 + ty + i * 8 + noff) * ldd + k0 + koff + tx;
        dsthi[idx] = hi;
        dstlo[idx] = lo;
    }
}

__global__ void conv_split(const float* __restrict__ src,
                           u16* __restrict__ hi, u16* __restrict__ lo, int n4)
{
    int i = blockIdx.x * 256 + threadIdx.x;
    if (i < n4) {
        float4 v = ((const float4*)src)[i];
        ushort4 h, l;
        h.x = f2bf(v.x); l.x = f2bf(v.x - bf2f(h.x));
        h.y = f2bf(v.y); l.y = f2bf(v.y - bf2f(h.y));
        h.z = f2bf(v.z); l.z = f2bf(v.z - bf2f(h.z));
        h.w = f2bf(v.w); l.w = f2bf(v.w - bf2f(h.w));
        ((ushort4*)hi)[i] = h;
        ((ushort4*)lo)[i] = l;
    }
}

// =====================================================================
extern "C" void kernel_launch(void* const* d_in, const int* in_sizes, int n_in,
                              void* d_out, int out_size, void* d_ws, size_t ws_size,
                              hipStream_t stream)
{
    const float* x     = (const float*)d_in[0];
    const float* Wproj = (const float*)d_in[1];
    const float* Wx0   = (const float*)d_in[2];
    const float* Wh0   = (const float*)d_in[3];
    const float* b0    = (const float*)d_in[4];
    const float* Wx1   = (const float*)d_in[5];
    const float* Wh1   = (const float*)d_in[6];
    const float* b1    = (const float*)d_in[7];
    const float* lnc_g = (const float*)d_in[8];
    const float* lnc_b = (const float*)d_in[9];
    const float* lnh_g = (const float*)d_in[10];
    const float* lnh_b = (const float*)d_in[11];
    const float* lno_g = (const float*)d_in[12];
    const float* lno_b = (const float*)d_in[13];
    float* out = (float*)d_out;

    // ---- ws layout ----
    char* base = (char*)d_ws;
    size_t o = 0;
    u16* x_hi  = (u16*)(base + o); o += (size_t)TSTEPS * BSZ * INDIM * 2;
    u16* x_lo  = (u16*)(base + o); o += (size_t)TSTEPS * BSZ * INDIM * 2;
    u16* W0thi = (u16*)(base + o); o += (size_t)N0TOT * K0TOT * 2;
    u16* W0tlo = (u16*)(base + o); o += (size_t)N0TOT * K0TOT * 2;
    u16* W1ghi = (u16*)(base + o); o += (size_t)G4 * K1TOT * 2;
    u16* W1glo = (u16*)(base + o); o += (size_t)G4 * K1TOT * 2;
    float* parts0 = (float*)(base + o); o += (size_t)2 * BSZ * N0TOT * 4;
    float* parts1 = (float*)(base + o); o += (size_t)4 * BSZ * G4 * 4;
    u16* h0hi = (u16*)(base + o); o += 65536 * 2;
    u16* h0lo = (u16*)(base + o); o += 65536 * 2;
    u16* h1hi = (u16*)(base + o); o += 65536 * 2;
    u16* h1lo = (u16*)(base + o); o += 65536 * 2;
    int* bar  = (int*)(base + o); o += 40960;   // 16 group lines (2KB) + root
    if (ws_size < o) return;

    // ---- prep ----
    conv_split<<<dim3(8192), 256, 0, stream>>>(x, x_hi, x_lo, 2097152);
    hipMemsetAsync(W0thi, 0, (size_t)2 * N0TOT * K0TOT * 2, stream);
    transpose_split<<<dim3(128, 8),  256, 0, stream>>>(Wx0,   G4,   W0thi, W0tlo, K0TOT, 0,    0);
    transpose_split<<<dim3(128, 32), 256, 0, stream>>>(Wh0,   G4,   W0thi, W0tlo, K0TOT, 0,    256);
    transpose_split<<<dim3(32, 8),   256, 0, stream>>>(Wproj, HDIM, W0thi, W0tlo, K0TOT, 4096, 0);
    transpose_split<<<dim3(128, 32), 256, 0, stream>>>(Wx1,   G4,   W1ghi, W1glo, K1TOT, 0,    0);
    transpose_split<<<dim3(128, 32), 256, 0, stream>>>(Wh1,   G4,   W1ghi, W1glo, K1TOT, 0,    1024);
    hipMemsetAsync(bar, 0, 40960, stream);

    // ---- the whole recurrence: one persistent kernel ----
    persistent<<<dim3(NBLK), dim3(NTHR), LDS_BYTES, stream>>>(
        x_hi, x_lo, W0thi, W0tlo, W1ghi, W1glo, b0, b1,
        lnc_g, lnc_b, lnh_g, lnh_b, lno_g, lno_b,
        parts0, parts1,
        h0hi, h0lo, h1hi, h1lo, out, bar);
}

// Round 9
// 45849.466 us; speedup vs baseline: 1.1837x; 1.0769x over previous
//
#include <hip/hip_runtime.h>
#include <math.h>

// Problem dims
#define TSTEPS 512
#define BSZ    64
#define INDIM  256
#define HDIM   1024
#define G4     4096
#define N0TOT  5120   // 4096 gate cols + 1024 proj cols
#define K0TOT  1280   // 256 (x) + 1024 (h0)
#define K1TOT  2048   // 1024 (h0') + 1024 (h1)
#define LN_EPS 1e-5f

#define NBLK   256
#define NTHR   1024

// LDS: W1 strip [16 cols][2054] hi then lo.
// Stride 2054 u16 == 3 (mod 32) dwords: conflict-free (R8: SQ_LDS_BANK_CONFLICT -> 0)
#define LDS_LDK    2054
#define LDS_LO_OFF (16 * LDS_LDK)
#define LDS_W_BYTES (2 * 16 * LDS_LDK * 2)          // 131,456
#define LDS_STG_OFF LDS_W_BYTES                     // u16 stg[2048] = 4096 B
#define LDS_RED_OFF (LDS_W_BYTES + 4096)            // float red[16] + pad
#define LDS_BYTES   (LDS_W_BYTES + 4096 + 256)

typedef short          s8v __attribute__((ext_vector_type(8)));
typedef float          f4v __attribute__((ext_vector_type(4)));
typedef unsigned short u16;

__device__ __forceinline__ u16 f2bf(float f) {
    unsigned u = __float_as_uint(f);
    u += 0x7FFFu + ((u >> 16) & 1u);            // RNE
    return (u16)(u >> 16);
}
__device__ __forceinline__ float bf2f(u16 h) {
    return __uint_as_float(((unsigned)h) << 16);
}
__device__ __forceinline__ float sigm(float x) { return 1.f / (1.f + expf(-x)); }

// ---------------- tree grid barrier ---------------------------------------
// History: R4 acquire-load spin -> per-poll buffer_inv storm (cache death).
//          R5 256-way same-line RMW arrivals serialize (~30us/barrier).
//          R6/R7 changed polls/fences only -> no effect.
//          R8 tree arrivals (-5ms) but kept s_sleep polls + sc1 data plane.
// R9 theory: (a) s_sleep wake latency is the per-barrier invariant ->
// busy-spin relaxed load-polls (R6-R8 prove load-polls observe updates;
// relaxed loads don't invalidate caches, fan-in <=16 per line is cheap).
// (b) data plane back to NORMAL CACHED loads/stores (R7's 8B sc1 atomics
// made all GEMM operand traffic uncached request-granular); cross-XCD
// correctness via ONE release/acquire fence pair per barrier (R6 vs R7
// showed per-barrier fences are cheap).
#define GRPS    16
#define GSTRIDE 512   // ints (2 KB) between group lines
__device__ __forceinline__ void grid_barrier(int* bar, int nbar)
{
    asm volatile("s_waitcnt vmcnt(0)" ::: "memory");   // drain this wave's stores
    __syncthreads();                                    // all waves' stores in L2
    if (threadIdx.x == 0) {
        __builtin_amdgcn_fence(__ATOMIC_RELEASE, "agent");  // wb L2 -> L3
        const int blk = blockIdx.x;
        const int g   = blk & 15;
        int* gctr = bar + g * GSTRIDE;
        int* ggo  = gctr + 32;                   // +128 B, separate line
        int* root = bar + GRPS * GSTRIDE;
        int v = __hip_atomic_fetch_add(gctr, 1, __ATOMIC_RELAXED,
                                       __HIP_MEMORY_SCOPE_AGENT);
        if (v == nbar * 16 - 1)                  // group closer
            __hip_atomic_fetch_add(root, 1, __ATOMIC_RELAXED,
                                   __HIP_MEMORY_SCOPE_AGENT);
        if (blk < 16) {                          // leader of group blk
            while (__hip_atomic_load(root, __ATOMIC_RELAXED,
                                     __HIP_MEMORY_SCOPE_AGENT) < nbar * 16) {}
            __hip_atomic_store(ggo, nbar, __ATOMIC_RELAXED,
                               __HIP_MEMORY_SCOPE_AGENT);
        } else {
            while (__hip_atomic_load(ggo, __ATOMIC_RELAXED,
                                     __HIP_MEMORY_SCOPE_AGENT) < nbar) {}
        }
        __builtin_amdgcn_fence(__ATOMIC_ACQUIRE, "agent");  // inv L1/L2
    }
    __syncthreads();
}

// ---------------- GEMM0 task: one 16x16 tile, K-split 2 ------------------
__device__ __forceinline__ void taskA(int task, int t, int lane,
    const u16* __restrict__ xhi, const u16* __restrict__ xlo,
    const u16* __restrict__ h0hi, const u16* __restrict__ h0lo,
    const u16* __restrict__ W0thi, const u16* __restrict__ W0tlo,
    float* __restrict__ parts0)
{
    const int ks  = task & 1;
    const int tile = task >> 1;
    const int rt  = tile & 3;
    const int ct  = tile >> 2;
    const int row = lane & 15;
    const int kg  = lane >> 4;
    const int m   = rt * 16 + row;
    const int n   = ct * 16 + row;
    int kbeg = ks * 640, kend = kbeg + 640;
    const int klim = (ct >= 256) ? INDIM : K0TOT;
    if (kend > klim) kend = klim;

    f4v acc = {0.f, 0.f, 0.f, 0.f};
    const u16* wh = W0thi + (size_t)n * K0TOT;
    const u16* wl = W0tlo + (size_t)n * K0TOT;

    for (int kc = kbeg; kc < kend; kc += 32) {
        const int kk = kc + kg * 8;
        s8v Ah, Al;
        if (kc < INDIM) {                       // x segment
            size_t o = ((size_t)(t * BSZ + m)) * INDIM + kk;
            Ah = *(const s8v*)(xhi + o);
            Al = *(const s8v*)(xlo + o);
        } else {                                // h segment (fresh after fence)
            size_t o = (size_t)m * HDIM + (kk - INDIM);
            Ah = *(const s8v*)(h0hi + o);
            Al = *(const s8v*)(h0lo + o);
        }
        s8v Bh = *(const s8v*)(wh + kk);        // W0: cached
        s8v Bl = *(const s8v*)(wl + kk);
        acc = __builtin_amdgcn_mfma_f32_16x16x32_bf16(Ah, Bh, acc, 0, 0, 0);
        acc = __builtin_amdgcn_mfma_f32_16x16x32_bf16(Ah, Bl, acc, 0, 0, 0);
        acc = __builtin_amdgcn_mfma_f32_16x16x32_bf16(Al, Bh, acc, 0, 0, 0);
    }
    float* Cp = parts0 + (size_t)ks * BSZ * N0TOT;
#pragma unroll
    for (int r = 0; r < 4; ++r)
        Cp[(size_t)(rt * 16 + kg * 4 + r) * N0TOT + ct * 16 + row] = acc[r];
}

// ---------------- GEMM1 task: block owns 16 cols (LDS strip) --------------
__device__ __forceinline__ void taskC(int blk, int wv, int lane,
    const u16* __restrict__ shW,
    const u16* __restrict__ h0hi, const u16* __restrict__ h0lo,
    const u16* __restrict__ h1hi, const u16* __restrict__ h1lo,
    float* __restrict__ parts1)
{
    const int rt  = wv & 3;
    const int ks  = wv >> 2;
    const int row = lane & 15;
    const int kg  = lane >> 4;
    const int m   = rt * 16 + row;
    const u16* ahB = (ks < 2) ? h0hi : h1hi;
    const u16* alB = (ks < 2) ? h0lo : h1lo;
    const u16* ah0 = ahB + (size_t)m * HDIM + (ks & 1) * 512;
    const u16* al0 = alB + (size_t)m * HDIM + (ks & 1) * 512;
    const u16* sh  = shW + row * LDS_LDK + ks * 512;
    const u16* sl  = shW + LDS_LO_OFF + row * LDS_LDK + ks * 512;

    f4v acc = {0.f, 0.f, 0.f, 0.f};
#pragma unroll 4
    for (int i = 0; i < 16; ++i) {
        const int kloc = i * 32 + kg * 8;
        s8v Ah = *(const s8v*)(ah0 + kloc);
        s8v Al = *(const s8v*)(al0 + kloc);
        s8v Bh = *(const s8v*)(sh + kloc);
        s8v Bl = *(const s8v*)(sl + kloc);
        acc = __builtin_amdgcn_mfma_f32_16x16x32_bf16(Ah, Bh, acc, 0, 0, 0);
        acc = __builtin_amdgcn_mfma_f32_16x16x32_bf16(Ah, Bl, acc, 0, 0, 0);
        acc = __builtin_amdgcn_mfma_f32_16x16x32_bf16(Al, Bh, acc, 0, 0, 0);
    }
    float* Cp = parts1 + (size_t)ks * BSZ * G4;
#pragma unroll
    for (int r = 0; r < 4; ++r)
        Cp[(size_t)(rt * 16 + kg * 4 + r) * G4 + blk * 16 + row] = acc[r];
}

// ---------------- block-wide sum of (s, q) over 1024 threads --------------
__device__ __forceinline__ float2 blk_sum2(float s, float q, float* red, int tid)
{
#pragma unroll
    for (int off = 32; off; off >>= 1) {
        s += __shfl_down(s, off);
        q += __shfl_down(q, off);
    }
    if ((tid & 63) == 0) { red[(tid >> 6) * 2] = s; red[(tid >> 6) * 2 + 1] = q; }
    __syncthreads();
    float ts = 0.f, tq = 0.f;
#pragma unroll
    for (int i = 0; i < 16; ++i) { ts += red[2 * i]; tq += red[2 * i + 1]; }
    __syncthreads();
    return make_float2(ts, tq);
}

__device__ __forceinline__ float lnorm(float v, float2 sq, float g, float b)
{
    float mean = sq.x * (1.f / 1024.f);
    float var  = sq.y * (1.f / 1024.f) - mean * mean;
    return (v - mean) * rsqrtf(var + LN_EPS) * g + b;
}

// stage h (hi,lo per-thread u16) through LDS -> plain 16B stores
__device__ __forceinline__ void store_h_16B(u16* stg, int tid,
                                            u16 hi, u16 lo,
                                            u16* dhi, u16* dlo, int base)
{
    stg[tid] = hi;
    stg[1024 + tid] = lo;
    __syncthreads();
    if (tid < 256) {
        const u16* src = stg + (tid >> 7) * 1024 + (tid & 127) * 8;
        s8v v = *(const s8v*)src;
        u16* dst = ((tid >> 7) == 0 ? dhi : dlo) + base + (tid & 127) * 8;
        *(s8v*)dst = v;
    }
    __syncthreads();
}

// =====================================================================
__global__ __launch_bounds__(NTHR, 4) void persistent(
    const u16* __restrict__ xhi,  const u16* __restrict__ xlo,
    const u16* __restrict__ W0thi, const u16* __restrict__ W0tlo,
    const u16* __restrict__ W1ghi, const u16* __restrict__ W1glo,
    const float* __restrict__ b0, const float* __restrict__ b1,
    const float* __restrict__ lncg, const float* __restrict__ lncb,
    const float* __restrict__ lnhg, const float* __restrict__ lnhb,
    const float* __restrict__ lnog, const float* __restrict__ lnob,
    float* __restrict__ parts0, float* __restrict__ parts1,
    u16* __restrict__ h0hi, u16* __restrict__ h0lo,
    u16* __restrict__ h1hi, u16* __restrict__ h1lo,
    float* __restrict__ out, int* bar)
{
    extern __shared__ char smem[];
    u16*   shW = (u16*)smem;
    u16*   stg = (u16*)(smem + LDS_STG_OFF);
    float* red = (float*)(smem + LDS_RED_OFF);

    const int blk  = blockIdx.x;
    const int tid  = threadIdx.x;
    const int wv   = tid >> 6;
    const int lane = tid & 63;
    int nbar = 0;

    // per-thread recurrent state (blocks 0..63 own batch row b=blk, elem n=tid)
    float c0reg = 0.f, c1reg = 0.f, h0reg = 0.f, h1reg = 0.f;

    // ---- prologue: LDS W1 strip (block owns cols blk*16..+16) ----
    {
        const size_t gcol = (size_t)(blk * 16 + wv) * K1TOT;
        for (int j = lane * 8; j < K1TOT; j += 512) {
            *(s8v*)(shW + wv * LDS_LDK + j)              = *(const s8v*)(W1ghi + gcol + j);
            *(s8v*)(shW + LDS_LO_OFF + wv * LDS_LDK + j) = *(const s8v*)(W1glo + gcol + j);
        }
    }
    // ---- zero bf16 h states ----
    if (blk < 64 && tid < 128) {
        s8v z = {0,0,0,0,0,0,0,0};
        *(s8v*)(h0hi + blk * HDIM + tid * 8) = z;
        *(s8v*)(h0lo + blk * HDIM + tid * 8) = z;
        *(s8v*)(h1hi + blk * HDIM + tid * 8) = z;
        *(s8v*)(h1lo + blk * HDIM + tid * 8) = z;
    }
    grid_barrier(bar, ++nbar);

    // ---- A(0) ----
    if (blk >= 64) {
        int wid = (blk - 64) * 16 + wv;
        if (wid < 2560)
            taskA(wid, 0, lane, xhi, xlo, h0hi, h0lo, W0thi, W0tlo, parts0);
    }
    grid_barrier(bar, ++nbar);

    for (int t = 0; t < TSTEPS; ++t) {
        // ---- phase B: cell0 (blocks 0..63, row b = blk) ----
        if (blk < 64) {
            const int b = blk, n = tid;
            const float* P0 = parts0 + (size_t)b * N0TOT;
            const float* P1 = parts0 + (size_t)(BSZ + b) * N0TOT;
            float gi = P0[n]        + P1[n]        + b0[n];
            float gf = P0[1024 + n] + P1[1024 + n] + b0[1024 + n];
            float gg = P0[2048 + n] + P1[2048 + n] + b0[2048 + n];
            float go = P0[3072 + n] + P1[3072 + n] + b0[3072 + n];
            float xp = P0[4096 + n] + P1[4096 + n];
            float cv = sigm(gf) * c0reg + expf(gi) * tanhf(gg);
            float2 r = blk_sum2(cv, cv * cv, red, tid);
            float cl = lnorm(cv, r, lncg[n], lncb[n]);
            c0reg = cl;
            float hv = sigm(go) * tanhf(cl);
            r = blk_sum2(hv, hv * hv, red, tid);
            float hl = lnorm(hv, r, lnhg[n], lnhb[n]) + xp;
            r = blk_sum2(hl, hl * hl, red, tid);
            float hn = lnorm(hl, r, lnog[n], lnob[n]);
            h0reg = hn;
            u16 hi = f2bf(hn);
            store_h_16B(stg, tid, hi, f2bf(hn - bf2f(hi)), h0hi, h0lo, b * HDIM);
        }
        grid_barrier(bar, ++nbar);

        // ---- phase C: GEMM1 (all blocks, own 16-col LDS strip) ----
        taskC(blk, wv, lane, shW, h0hi, h0lo, h1hi, h1lo, parts1);
        grid_barrier(bar, ++nbar);

        // ---- phase D (cell1, blocks 0..63) || A(t+1) (blocks 64..255) ----
        if (blk < 64) {
            const int b = blk, n = tid;
            const float* P0 = parts1 + (size_t)b * G4;
            const float* P1 = parts1 + (size_t)(64 + b) * G4;
            const float* P2 = parts1 + (size_t)(128 + b) * G4;
            const float* P3 = parts1 + (size_t)(192 + b) * G4;
            float gi = P0[n] + P1[n] + P2[n] + P3[n] + b1[n];
            float gf = P0[1024 + n] + P1[1024 + n] + P2[1024 + n] + P3[1024 + n] + b1[1024 + n];
            float gg = P0[2048 + n] + P1[2048 + n] + P2[2048 + n] + P3[2048 + n] + b1[2048 + n];
            float go = P0[3072 + n] + P1[3072 + n] + P2[3072 + n] + P3[3072 + n] + b1[3072 + n];
            float cv = sigm(gf) * c1reg + expf(gi) * tanhf(gg);
            float2 r = blk_sum2(cv, cv * cv, red, tid);
            float cl = lnorm(cv, r, lncg[HDIM + n], lncb[HDIM + n]);
            c1reg = cl;
            float hv = sigm(go) * tanhf(cl);
            r = blk_sum2(hv, hv * hv, red, tid);
            float hl = lnorm(hv, r, lnhg[HDIM + n], lnhb[HDIM + n]) + h0reg;
            r = blk_sum2(hl, hl * hl, red, tid);
            float hn = lnorm(hl, r, lnog[HDIM + n], lnob[HDIM + n]);
            h1reg = hn;
            u16 hi = f2bf(hn);
            out[(size_t)t * BSZ * HDIM + b * HDIM + n] = hn;
            store_h_16B(stg, tid, hi, f2bf(hn - bf2f(hi)), h1hi, h1lo, b * HDIM);
        } else if (t + 1 < TSTEPS) {
            int wid = (blk - 64) * 16 + wv;
            if (wid < 2560)
                taskA(wid, t + 1, lane, xhi, xlo, h0hi, h0lo, W0thi, W0tlo, parts0);
        }
        grid_barrier(bar, ++nbar);
    }

    // ---- final states from registers: h0,h1 then c0,c1 ----
    if (blk < 64) {
        const size_t F = (size_t)TSTEPS * BSZ * HDIM;
        out[F +          blk * HDIM + tid] = h0reg;
        out[F +  65536 + blk * HDIM + tid] = h1reg;
        out[F + 131072 + blk * HDIM + tid] = c0reg;
        out[F + 196608 + blk * HDIM + tid] = c1reg;
    }
}

// =====================================================================
// prep kernels
// =====================================================================
__global__ __launch_bounds__(256) void transpose_split(
    const float* __restrict__ src, int N,
    u16* __restrict__ dsthi, u16* __restrict__ dstlo,
    int ldd, int noff, int koff)
{
    __shared__ float tile[32][33];
    const int n0 = blockIdx.x * 32, k0 = blockIdx.y * 32;
    const int tx = threadIdx.x & 31, ty = threadIdx.x >> 5;
#pragma unroll
    for (int i = 0; i < 4; ++i)
        tile[ty + i * 8][tx] = src[(size_t)(k0 + ty + i * 8) * N + n0 + tx];
    __syncthreads();
#pragma unroll
    for (int i = 0; i < 4; ++i) {
        float v = tile[tx][ty + i * 8];
        u16 hi = f2bf(v);
        u16 lo = f2bf(v - bf2f(hi));
        size_t idx = (size_t)(n0 + ty + i * 8 + noff) * ldd + k0 + koff + tx;
        dsthi[idx] = hi;
        dstlo[idx] = lo;
    }
}

__global__ void conv_split(const float* __restrict__ src,
                           u16* __restrict__ hi, u16* __restrict__ lo, int n4)
{
    int i = blockIdx.x * 256 + threadIdx.x;
    if (i < n4) {
        float4 v = ((const float4*)src)[i];
        ushort4 h, l;
        h.x = f2bf(v.x); l.x = f2bf(v.x - bf2f(h.x));
        h.y = f2bf(v.y); l.y = f2bf(v.y - bf2f(h.y));
        h.z = f2bf(v.z); l.z = f2bf(v.z - bf2f(h.z));
        h.w = f2bf(v.w); l.w = f2bf(v.w - bf2f(h.w));
        ((ushort4*)hi)[i] = h;
        ((ushort4*)lo)[i] = l;
    }
}

// =====================================================================
extern "C" void kernel_launch(void* const* d_in, const int* in_sizes, int n_in,
                              void* d_out, int out_size, void* d_ws, size_t ws_size,
                              hipStream_t stream)
{
    const float* x     = (const float*)d_in[0];
    const float* Wproj = (const float*)d_in[1];
    const float* Wx0   = (const float*)d_in[2];
    const float* Wh0   = (const float*)d_in[3];
    const float* b0    = (const float*)d_in[4];
    const float* Wx1   = (const float*)d_in[5];
    const float* Wh1   = (const float*)d_in[6];
    const float* b1    = (const float*)d_in[7];
    const float* lnc_g = (const float*)d_in[8];
    const float* lnc_b = (const float*)d_in[9];
    const float* lnh_g = (const float*)d_in[10];
    const float* lnh_b = (const float*)d_in[11];
    const float* lno_g = (const float*)d_in[12];
    const float* lno_b = (const float*)d_in[13];
    float* out = (float*)d_out;

    // ---- ws layout ----
    char* base = (char*)d_ws;
    size_t o = 0;
    u16* x_hi  = (u16*)(base + o); o += (size_t)TSTEPS * BSZ * INDIM * 2;
    u16* x_lo  = (u16*)(base + o); o += (size_t)TSTEPS * BSZ * INDIM * 2;
    u16* W0thi = (u16*)(base + o); o += (size_t)N0TOT * K0TOT * 2;
    u16* W0tlo = (u16*)(base + o); o += (size_t)N0TOT * K0TOT * 2;
    u16* W1ghi = (u16*)(base + o); o += (size_t)G4 * K1TOT * 2;
    u16* W1glo = (u16*)(base + o); o += (size_t)G4 * K1TOT * 2;
    float* parts0 = (float*)(base + o); o += (size_t)2 * BSZ * N0TOT * 4;
    float* parts1 = (float*)(base + o); o += (size_t)4 * BSZ * G4 * 4;
    u16* h0hi = (u16*)(base + o); o += 65536 * 2;
    u16* h0lo = (u16*)(base + o); o += 65536 * 2;
    u16* h1hi = (u16*)(base + o); o += 65536 * 2;
    u16* h1lo = (u16*)(base + o); o += 65536 * 2;
    int* bar  = (int*)(base + o); o += 40960;   // 16 group lines (2KB) + root
    if (ws_size < o) return;

    // ---- prep ----
    conv_split<<<dim3(8192), 256, 0, stream>>>(x, x_hi, x_lo, 2097152);
    hipMemsetAsync(W0thi, 0, (size_t)2 * N0TOT * K0TOT * 2, stream);
    transpose_split<<<dim3(128, 8),  256, 0, stream>>>(Wx0,   G4,   W0thi, W0tlo, K0TOT, 0,    0);
    transpose_split<<<dim3(128, 32), 256, 0, stream>>>(Wh0,   G4,   W0thi, W0tlo, K0TOT, 0,    256);
    transpose_split<<<dim3(32, 8),   256, 0, stream>>>(Wproj, HDIM, W0thi, W0tlo, K0TOT, 4096, 0);
    transpose_split<<<dim3(128, 32), 256, 0, stream>>>(Wx1,   G4,   W1ghi, W1glo, K1TOT, 0,    0);
    transpose_split<<<dim3(128, 32), 256, 0, stream>>>(Wh1,   G4,   W1ghi, W1glo, K1TOT, 0,    1024);
    hipMemsetAsync(bar, 0, 40960, stream);

    // ---- the whole recurrence: one persistent kernel ----
    persistent<<<dim3(NBLK), dim3(NTHR), LDS_BYTES, stream>>>(
        x_hi, x_lo, W0thi, W0tlo, W1ghi, W1glo, b0, b1,
        lnc_g, lnc_b, lnh_g, lnh_b, lno_g, lno_b,
        parts0, parts1,
        h0hi, h0lo, h1hi, h1lo, out, bar);
}

// Round 10
// 36751.694 us; speedup vs baseline: 1.4768x; 1.2475x over previous
//
#include <hip/hip_runtime.h>
#include <math.h>

// Problem dims
#define TSTEPS 512
#define BSZ    64
#define INDIM  256
#define HDIM   1024
#define G4     4096
#define NX     5120   // xg cols: 4096 gate + 1024 proj
#define LN_EPS 1e-5f

#define NBLK   256
#define NTHR   1024
#define CHUNK  8              // xg chunk = 8 steps
#define CROWS  (CHUNK * BSZ)  // 512 rows per chunk
#define NCHUNK (TSTEPS / CHUNK)

// LDS: W1 strip [16 cols][2054] hi then lo (stride == 3 mod 32 dwords:
// conflict-free, R8-verified SQ_LDS_BANK_CONFLICT -> 0)
#define LDS_LDK    2054
#define LDS_LO_OFF (16 * LDS_LDK)
#define LDS_W_BYTES (2 * 16 * LDS_LDK * 2)
#define LDS_STG_OFF LDS_W_BYTES
#define LDS_RED_OFF (LDS_W_BYTES + 4096)
#define LDS_BYTES   (LDS_W_BYTES + 4096 + 256)

typedef short          s8v __attribute__((ext_vector_type(8)));
typedef float          f4v __attribute__((ext_vector_type(4)));
typedef unsigned short u16;

#define MFMA __builtin_amdgcn_mfma_f32_16x16x32_bf16

__device__ __forceinline__ u16 f2bf(float f) {
    unsigned u = __float_as_uint(f);
    u += 0x7FFFu + ((u >> 16) & 1u);
    return (u16)(u >> 16);
}
__device__ __forceinline__ float bf2f(u16 h) {
    return __uint_as_float(((unsigned)h) << 16);
}
__device__ __forceinline__ float sigm(float x) { return 1.f / (1.f + expf(-x)); }

// ---------------- tree grid barrier (R9: proven) --------------------------
#define GSTRIDE 512
__device__ __forceinline__ void grid_barrier(int* bar, int nbar)
{
    asm volatile("s_waitcnt vmcnt(0)" ::: "memory");
    __syncthreads();
    if (threadIdx.x == 0) {
        __builtin_amdgcn_fence(__ATOMIC_RELEASE, "agent");
        const int blk = blockIdx.x;
        const int g   = blk & 15;
        int* gctr = bar + g * GSTRIDE;
        int* ggo  = gctr + 32;
        int* root = bar + 16 * GSTRIDE;
        int v = __hip_atomic_fetch_add(gctr, 1, __ATOMIC_RELAXED,
                                       __HIP_MEMORY_SCOPE_AGENT);
        if (v == nbar * 16 - 1)
            __hip_atomic_fetch_add(root, 1, __ATOMIC_RELAXED,
                                   __HIP_MEMORY_SCOPE_AGENT);
        if (blk < 16) {
            while (__hip_atomic_load(root, __ATOMIC_RELAXED,
                                     __HIP_MEMORY_SCOPE_AGENT) < nbar * 16) {}
            __hip_atomic_store(ggo, nbar, __ATOMIC_RELAXED,
                               __HIP_MEMORY_SCOPE_AGENT);
        } else {
            while (__hip_atomic_load(ggo, __ATOMIC_RELAXED,
                                     __HIP_MEMORY_SCOPE_AGENT) < nbar) {}
        }
        __builtin_amdgcn_fence(__ATOMIC_ACQUIRE, "agent");
    }
    __syncthreads();
}

// ---------------- taskA: gates0 h-part, one 16x16 tile, K-split 2 ---------
// task in [0,2048): ks=task&1 (K 512), tile=task>>1: rt=tile&3, ct=tile>>2
__device__ __forceinline__ void taskA(int task, int lane,
    const u16* __restrict__ h0hi_b, const u16* __restrict__ h0lo_b,
    const u16* __restrict__ Whthi, const u16* __restrict__ Whtlo,
    float* __restrict__ p0buf)
{
    const int ks = task & 1, tile = task >> 1;
    const int rt = tile & 3, ct = tile >> 2;
    const int row = lane & 15, kg = lane >> 4;
    const int m = rt * 16 + row;
    const u16* wh = Whthi + (size_t)(ct * 16 + row) * HDIM;
    const u16* wl = Whtlo + (size_t)(ct * 16 + row) * HDIM;
    const u16* ah = h0hi_b + (size_t)m * HDIM;
    const u16* al = h0lo_b + (size_t)m * HDIM;
    f4v acc = {0.f, 0.f, 0.f, 0.f};
    const int kbeg = ks * 512;
    for (int kc = kbeg; kc < kbeg + 512; kc += 32) {
        const int kk = kc + kg * 8;
        s8v Ah = *(const s8v*)(ah + kk);
        s8v Al = *(const s8v*)(al + kk);
        s8v Bh = *(const s8v*)(wh + kk);
        s8v Bl = *(const s8v*)(wl + kk);
        acc = MFMA(Ah, Bh, acc, 0, 0, 0);
        acc = MFMA(Ah, Bl, acc, 0, 0, 0);
        acc = MFMA(Al, Bh, acc, 0, 0, 0);
    }
    float* Cp = p0buf + (size_t)ks * BSZ * G4;
#pragma unroll
    for (int r = 0; r < 4; ++r)
        Cp[(size_t)(rt * 16 + kg * 4 + r) * G4 + ct * 16 + row] = acc[r];
}

// ---------------- taskX: xg chunk GEMM, one 16x16 tile, K=256 -------------
// task in [0,10240): mt=task&31, ct=task>>5 (0..319)
__device__ __forceinline__ void taskX(int task, int c, int lane,
    const u16* __restrict__ xhi, const u16* __restrict__ xlo,
    const u16* __restrict__ Wxthi, const u16* __restrict__ Wxtlo,
    float* __restrict__ xgbuf)
{
    const int mt = task & 31, ct = task >> 5;
    const int row = lane & 15, kg = lane >> 4;
    const int mr = mt * 16 + row;
    const u16* ah = xhi + ((size_t)c * CROWS + mr) * INDIM;
    const u16* al = xlo + ((size_t)c * CROWS + mr) * INDIM;
    const u16* wh = Wxthi + (size_t)(ct * 16 + row) * INDIM;
    const u16* wl = Wxtlo + (size_t)(ct * 16 + row) * INDIM;
    f4v acc = {0.f, 0.f, 0.f, 0.f};
    for (int kc = 0; kc < INDIM; kc += 32) {
        const int kk = kc + kg * 8;
        s8v Ah = *(const s8v*)(ah + kk);
        s8v Al = *(const s8v*)(al + kk);
        s8v Bh = *(const s8v*)(wh + kk);
        s8v Bl = *(const s8v*)(wl + kk);
        acc = MFMA(Ah, Bh, acc, 0, 0, 0);
        acc = MFMA(Ah, Bl, acc, 0, 0, 0);
        acc = MFMA(Al, Bh, acc, 0, 0, 0);
    }
#pragma unroll
    for (int r = 0; r < 4; ++r)
        xgbuf[(size_t)(mt * 16 + kg * 4 + r) * NX + ct * 16 + row] = acc[r];
}

// ---------------- taskC: GEMM1, block owns 16 cols (LDS strip) ------------
__device__ __forceinline__ void taskC(int blk, int wv, int lane,
    const u16* __restrict__ shW,
    const u16* __restrict__ h0hi_b, const u16* __restrict__ h0lo_b,
    const u16* __restrict__ h1hi, const u16* __restrict__ h1lo,
    float* __restrict__ p1buf)
{
    const int rt = wv & 3, ks = wv >> 2;
    const int row = lane & 15, kg = lane >> 4;
    const int m = rt * 16 + row;
    const u16* ahB = (ks < 2) ? h0hi_b : h1hi;
    const u16* alB = (ks < 2) ? h0lo_b : h1lo;
    const u16* ah0 = ahB + (size_t)m * HDIM + (ks & 1) * 512;
    const u16* al0 = alB + (size_t)m * HDIM + (ks & 1) * 512;
    const u16* sh  = shW + row * LDS_LDK + ks * 512;
    const u16* sl  = shW + LDS_LO_OFF + row * LDS_LDK + ks * 512;
    f4v acc = {0.f, 0.f, 0.f, 0.f};
#pragma unroll 4
    for (int i = 0; i < 16; ++i) {
        const int kloc = i * 32 + kg * 8;
        s8v Ah = *(const s8v*)(ah0 + kloc);
        s8v Al = *(const s8v*)(al0 + kloc);
        s8v Bh = *(const s8v*)(sh + kloc);
        s8v Bl = *(const s8v*)(sl + kloc);
        acc = MFMA(Ah, Bh, acc, 0, 0, 0);
        acc = MFMA(Ah, Bl, acc, 0, 0, 0);
        acc = MFMA(Al, Bh, acc, 0, 0, 0);
    }
    float* Cp = p1buf + (size_t)ks * BSZ * G4;
#pragma unroll
    for (int r = 0; r < 4; ++r)
        Cp[(size_t)(rt * 16 + kg * 4 + r) * G4 + blk * 16 + row] = acc[r];
}

// ---------------- block reduction + LN helpers ----------------------------
__device__ __forceinline__ float2 blk_sum2(float s, float q, float* red, int tid)
{
#pragma unroll
    for (int off = 32; off; off >>= 1) {
        s += __shfl_down(s, off);
        q += __shfl_down(q, off);
    }
    if ((tid & 63) == 0) { red[(tid >> 6) * 2] = s; red[(tid >> 6) * 2 + 1] = q; }
    __syncthreads();
    float ts = 0.f, tq = 0.f;
#pragma unroll
    for (int i = 0; i < 16; ++i) { ts += red[2 * i]; tq += red[2 * i + 1]; }
    __syncthreads();
    return make_float2(ts, tq);
}

__device__ __forceinline__ float lnorm(float v, float2 sq, float g, float b)
{
    float mean = sq.x * (1.f / 1024.f);
    float var  = sq.y * (1.f / 1024.f) - mean * mean;
    return (v - mean) * rsqrtf(var + LN_EPS) * g + b;
}

__device__ __forceinline__ void store_h_16B(u16* stg, int tid,
                                            u16 hi, u16 lo,
                                            u16* dhi, u16* dlo, int base)
{
    stg[tid] = hi;
    stg[1024 + tid] = lo;
    __syncthreads();
    if (tid < 256) {
        const u16* src = stg + (tid >> 7) * 1024 + (tid & 127) * 8;
        s8v v = *(const s8v*)src;
        u16* dst = ((tid >> 7) == 0 ? dhi : dlo) + base + (tid & 127) * 8;
        *(s8v*)dst = v;
    }
    __syncthreads();
}

// =====================================================================
__global__ __launch_bounds__(NTHR, 4) void persistent(
    const u16* __restrict__ xhi,  const u16* __restrict__ xlo,
    const u16* __restrict__ Whthi, const u16* __restrict__ Whtlo,
    const u16* __restrict__ Wxthi, const u16* __restrict__ Wxtlo,
    const u16* __restrict__ W1thi, const u16* __restrict__ W1tlo,
    const float* __restrict__ b0, const float* __restrict__ b1,
    const float* __restrict__ lncg, const float* __restrict__ lncb,
    const float* __restrict__ lnhg, const float* __restrict__ lnhb,
    const float* __restrict__ lnog, const float* __restrict__ lnob,
    float* __restrict__ xg,                        // [2][512][5120]
    float* __restrict__ parts0,                    // [2][2][64][4096]
    float* __restrict__ parts1,                    // [2][4][64][4096]
    u16* __restrict__ h0hi, u16* __restrict__ h0lo,// [2][64][1024]
    u16* __restrict__ h1hi, u16* __restrict__ h1lo,// [64][1024]
    float* __restrict__ out, int* bar)
{
    extern __shared__ char smem[];
    u16*   shW = (u16*)smem;
    u16*   stg = (u16*)(smem + LDS_STG_OFF);
    float* red = (float*)(smem + LDS_RED_OFF);

    const int blk  = blockIdx.x;
    const int tid  = threadIdx.x;
    const int wv   = tid >> 6;
    const int lane = tid & 63;
    int nbar = 0;

    // recurrent per-thread state:
    //   blocks 0..63:  c0, h0 for batch row b=blk, elem n=tid
    //   blocks 64..127: c1, h1 for batch row b=blk-64
    float c0reg = 0.f, h0reg = 0.f, c1reg = 0.f, h1reg = 0.f;

    // ---- prologue: LDS W1 strip (cols blk*16..+16 of [h0|h1], K=2048) ----
    {
        const size_t gcol = (size_t)(blk * 16 + wv) * 2048;
        for (int j = lane * 8; j < 2048; j += 512) {
            *(s8v*)(shW + wv * LDS_LDK + j)              = *(const s8v*)(W1thi + gcol + j);
            *(s8v*)(shW + LDS_LO_OFF + wv * LDS_LDK + j) = *(const s8v*)(W1tlo + gcol + j);
        }
    }
    // ---- zero h states (both h0 bufs + h1) ----
    if (blk < 64 && tid < 128) {
        s8v z = {0,0,0,0,0,0,0,0};
        *(s8v*)(h0hi + blk * HDIM + tid * 8) = z;
        *(s8v*)(h0lo + blk * HDIM + tid * 8) = z;
        *(s8v*)(h0hi + 65536 + blk * HDIM + tid * 8) = z;
        *(s8v*)(h0lo + 65536 + blk * HDIM + tid * 8) = z;
        *(s8v*)(h1hi + blk * HDIM + tid * 8) = z;
        *(s8v*)(h1lo + blk * HDIM + tid * 8) = z;
    }
    grid_barrier(bar, ++nbar);

    // ---- prologue: xg chunk 0 (all blocks; 10240 tasks / 4096 waves) ----
    {
        const int g = blk * 16 + wv;
        for (int task = g; task < 10240; task += 4096)
            taskX(task, 0, lane, xhi, xlo, Wxthi, Wxtlo, xg);
    }
    grid_barrier(bar, ++nbar);
    // parts0 buf0 zeroed host-side (h0(-1)=0 -> gates0 h-part = 0)

    for (int t = 0; t < TSTEPS; ++t) {
        const int pb   = t & 1;            // parity buffer index
        const int pbp  = pb ^ 1;           // previous parity
        float* p0buf = parts0 + (size_t)pb * 2 * BSZ * G4;
        float* p1buf = parts1 + (size_t)pb * 4 * BSZ * G4;
        const u16* h0hi_c = h0hi + pb * 65536;   // h0(t) written this step
        const u16* h0lo_c = h0lo + pb * 65536;

        // ================= phase 1: cells =================
        if (blk < 64) {
            // ---- cell0(t): row b = blk ----
            const int b = blk, n = tid;
            const float* XG = xg + (size_t)((t >> 3) & 1) * CROWS * NX
                                 + (size_t)((t & 7) * BSZ + b) * NX;
            const float* P0 = p0buf + (size_t)b * G4;
            const float* P1 = p0buf + (size_t)(BSZ + b) * G4;
            float gi = XG[n]        + P0[n]        + P1[n]        + b0[n];
            float gf = XG[1024 + n] + P0[1024 + n] + P1[1024 + n] + b0[1024 + n];
            float gg = XG[2048 + n] + P0[2048 + n] + P1[2048 + n] + b0[2048 + n];
            float go = XG[3072 + n] + P0[3072 + n] + P1[3072 + n] + b0[3072 + n];
            float xp = XG[4096 + n];                       // x @ Wproj residual
            float cv = sigm(gf) * c0reg + expf(gi) * tanhf(gg);
            float2 r = blk_sum2(cv, cv * cv, red, tid);
            float cl = lnorm(cv, r, lncg[n], lncb[n]);
            c0reg = cl;
            float hv = sigm(go) * tanhf(cl);
            r = blk_sum2(hv, hv * hv, red, tid);
            float hl = lnorm(hv, r, lnhg[n], lnhb[n]) + xp;
            r = blk_sum2(hl, hl * hl, red, tid);
            float hn = lnorm(hl, r, lnog[n], lnob[n]);
            h0reg = hn;
            u16 hi = f2bf(hn);
            store_h_16B(stg, tid, hi, f2bf(hn - bf2f(hi)),
                        h0hi + pb * 65536, h0lo + pb * 65536, b * HDIM);
        } else if (blk < 128 && t > 0) {
            // ---- cell1(t-1): row b = blk-64 ----
            const int b = blk - 64, n = tid;
            const int tp = t - 1;
            float* p1prev = parts1 + (size_t)(tp & 1) * 4 * BSZ * G4;
            const float* P0 = p1prev + (size_t)b * G4;
            const float* P1 = p1prev + (size_t)(64 + b) * G4;
            const float* P2 = p1prev + (size_t)(128 + b) * G4;
            const float* P3 = p1prev + (size_t)(192 + b) * G4;
            float gi = P0[n] + P1[n] + P2[n] + P3[n] + b1[n];
            float gf = P0[1024+n] + P1[1024+n] + P2[1024+n] + P3[1024+n] + b1[1024+n];
            float gg = P0[2048+n] + P1[2048+n] + P2[2048+n] + P3[2048+n] + b1[2048+n];
            float go = P0[3072+n] + P1[3072+n] + P2[3072+n] + P3[3072+n] + b1[3072+n];
            float cv = sigm(gf) * c1reg + expf(gi) * tanhf(gg);
            float2 r = blk_sum2(cv, cv * cv, red, tid);
            float cl = lnorm(cv, r, lncg[HDIM + n], lncb[HDIM + n]);
            c1reg = cl;
            float hv = sigm(go) * tanhf(cl);
            r = blk_sum2(hv, hv * hv, red, tid);
            // residual: h0(t-1) from its parity buffer (hi+lo ~ fp32)
            float h0v = bf2f(h0hi[(tp & 1) * 65536 + b * HDIM + n])
                      + bf2f(h0lo[(tp & 1) * 65536 + b * HDIM + n]);
            float hl = lnorm(hv, r, lnhg[HDIM + n], lnhb[HDIM + n]) + h0v;
            r = blk_sum2(hl, hl * hl, red, tid);
            float hn = lnorm(hl, r, lnog[HDIM + n], lnob[HDIM + n]);
            h1reg = hn;
            u16 hi = f2bf(hn);
            out[(size_t)tp * BSZ * HDIM + b * HDIM + n] = hn;
            store_h_16B(stg, tid, hi, f2bf(hn - bf2f(hi)), h1hi, h1lo, b * HDIM);
        }
        grid_barrier(bar, ++nbar);

        // ================= phase 2: GEMMs =================
        // C(t): all blocks (16-col LDS strip), reads h0(t) + h1(t-1)
        taskC(blk, wv, lane, shW, h0hi_c, h0lo_c, h1hi, h1lo, p1buf);
        // A(t+1): blocks 0..127, 2048 tasks, writes parts0[(t+1)&1]
        if (blk < 128) {
            if (t + 1 < TSTEPS)
                taskA(blk * 16 + wv, lane, h0hi_c, h0lo_c, Whthi, Whtlo,
                      parts0 + (size_t)pbp * 2 * BSZ * G4);
        } else if ((t & 7) == 7 && (t >> 3) + 1 < NCHUNK) {
            // xg chunk (t>>3)+1 on blocks 128..255 (10240 tasks / 2048 waves)
            const int c = (t >> 3) + 1;
            float* xgbuf = xg + (size_t)(c & 1) * CROWS * NX;
            const int g = (blk - 128) * 16 + wv;
            for (int i = 0; i < 5; ++i)
                taskX(g + 2048 * i, c, lane, xhi, xlo, Wxthi, Wxtlo, xgbuf);
        }
        grid_barrier(bar, ++nbar);
    }

    // ---- epilogue: cell1(511) ----
    if (blk >= 64 && blk < 128) {
        const int b = blk - 64, n = tid;
        const int tp = TSTEPS - 1;
        float* p1prev = parts1 + (size_t)(tp & 1) * 4 * BSZ * G4;
        const float* P0 = p1prev + (size_t)b * G4;
        const float* P1 = p1prev + (size_t)(64 + b) * G4;
        const float* P2 = p1prev + (size_t)(128 + b) * G4;
        const float* P3 = p1prev + (size_t)(192 + b) * G4;
        float gi = P0[n] + P1[n] + P2[n] + P3[n] + b1[n];
        float gf = P0[1024+n] + P1[1024+n] + P2[1024+n] + P3[1024+n] + b1[1024+n];
        float gg = P0[2048+n] + P1[2048+n] + P2[2048+n] + P3[2048+n] + b1[2048+n];
        float go = P0[3072+n] + P1[3072+n] + P2[3072+n] + P3[3072+n] + b1[3072+n];
        float cv = sigm(gf) * c1reg + expf(gi) * tanhf(gg);
        float2 r = blk_sum2(cv, cv * cv, red, tid);
        float cl = lnorm(cv, r, lncg[HDIM + n], lncb[HDIM + n]);
        c1reg = cl;
        float hv = sigm(go) * tanhf(cl);
        r = blk_sum2(hv, hv * hv, red, tid);
        float h0v = bf2f(h0hi[(tp & 1) * 65536 + b * HDIM + n])
                  + bf2f(h0lo[(tp & 1) * 65536 + b * HDIM + n]);
        float hl = lnorm(hv, r, lnhg[HDIM + n], lnhb[HDIM + n]) + h0v;
        r = blk_sum2(hl, hl * hl, red, tid);
        float hn = lnorm(hl, r, lnog[HDIM + n], lnob[HDIM + n]);
        h1reg = hn;
        out[(size_t)tp * BSZ * HDIM + b * HDIM + n] = hn;
    }

    // ---- final states: h0, h1, c0, c1 ----
    {
        const size_t F = (size_t)TSTEPS * BSZ * HDIM;
        if (blk < 64) {
            out[F +          blk * HDIM + tid] = h0reg;
            out[F + 131072 + blk * HDIM + tid] = c0reg;
        } else if (blk < 128) {
            const int b = blk - 64;
            out[F +  65536 + b * HDIM + tid] = h1reg;
            out[F + 196608 + b * HDIM + tid] = c1reg;
        }
    }
}

// =====================================================================
// prep kernels
// =====================================================================
__global__ __launch_bounds__(256) void transpose_split(
    const float* __restrict__ src, int N,
    u16* __restrict__ dsthi, u16* __restrict__ dstlo,
    int ldd, int noff, int koff)
{
    __shared__ float tile[32][33];
    const int n0 = blockIdx.x * 32, k0 = blockIdx.y * 32;
    const int tx = threadIdx.x & 31, ty = threadIdx.x >> 5;
#pragma unroll
    for (int i = 0; i < 4; ++i)
        tile[ty + i * 8][tx] = src[(size_t)(k0 + ty + i * 8) * N + n0 + tx];
    __syncthreads();
#pragma unroll
    for (int i = 0; i < 4; ++i) {
        float v = tile[tx][ty + i * 8];
        u16 hi = f2bf(v);
        u16 lo = f2bf(v - bf2f(hi));
        size_t idx = (size_t)(n0 + ty + i * 8 + noff) * ldd + k0 + koff + tx;
        dsthi[idx] = hi;
        dstlo[idx] = lo;
    }
}

__global__ void conv_split(const float* __restrict__ src,
                           u16* __restrict__ hi, u16* __restrict__ lo, int n4)
{
    int i = blockIdx.x * 256 + threadIdx.x;
    if (i < n4) {
        float4 v = ((const float4*)src)[i];
        ushort4 h, l;
        h.x = f2bf(v.x); l.x = f2bf(v.x - bf2f(h.x));
        h.y = f2bf(v.y); l.y = f2bf(v.y - bf2f(h.y));
        h.z = f2bf(v.z); l.z = f2bf(v.z - bf2f(h.z));
        h.w = f2bf(v.w); l.w = f2bf(v.w - bf2f(h.w));
        ((ushort4*)hi)[i] = h;
        ((ushort4*)lo)[i] = l;
    }
}

// =====================================================================
extern "C" void kernel_launch(void* const* d_in, const int* in_sizes, int n_in,
                              void* d_out, int out_size, void* d_ws, size_t ws_size,
                              hipStream_t stream)
{
    const float* x     = (const float*)d_in[0];
    const float* Wproj = (const float*)d_in[1];
    const float* Wx0   = (const float*)d_in[2];
    const float* Wh0   = (const float*)d_in[3];
    const float* b0    = (const float*)d_in[4];
    const float* Wx1   = (const float*)d_in[5];
    const float* Wh1   = (const float*)d_in[6];
    const float* b1    = (const float*)d_in[7];
    const float* lnc_g = (const float*)d_in[8];
    const float* lnc_b = (const float*)d_in[9];
    const float* lnh_g = (const float*)d_in[10];
    const float* lnh_b = (const float*)d_in[11];
    const float* lno_g = (const float*)d_in[12];
    const float* lno_b = (const float*)d_in[13];
    float* out = (float*)d_out;

    // ---- ws layout ----
    char* base = (char*)d_ws;
    size_t o = 0;
    u16* x_hi  = (u16*)(base + o); o += (size_t)TSTEPS * BSZ * INDIM * 2;   // 16.8M
    u16* x_lo  = (u16*)(base + o); o += (size_t)TSTEPS * BSZ * INDIM * 2;
    u16* Whthi = (u16*)(base + o); o += (size_t)G4 * HDIM * 2;              // 8.4M
    u16* Whtlo = (u16*)(base + o); o += (size_t)G4 * HDIM * 2;
    u16* Wxthi = (u16*)(base + o); o += (size_t)NX * INDIM * 2;             // 2.6M
    u16* Wxtlo = (u16*)(base + o); o += (size_t)NX * INDIM * 2;
    u16* W1thi = (u16*)(base + o); o += (size_t)G4 * 2048 * 2;              // 16.8M
    u16* W1tlo = (u16*)(base + o); o += (size_t)G4 * 2048 * 2;
    float* xg     = (float*)(base + o); o += (size_t)2 * CROWS * NX * 4;    // 21.0M
    float* parts0 = (float*)(base + o); o += (size_t)2 * 2 * BSZ * G4 * 4;  //  4.2M
    float* parts1 = (float*)(base + o); o += (size_t)2 * 4 * BSZ * G4 * 4;  //  8.4M
    u16* h0hi = (u16*)(base + o); o += 2 * 65536 * 2;
    u16* h0lo = (u16*)(base + o); o += 2 * 65536 * 2;
    u16* h1hi = (u16*)(base + o); o += 65536 * 2;
    u16* h1lo = (u16*)(base + o); o += 65536 * 2;
    int* bar  = (int*)(base + o); o += 40960;
    if (ws_size < o) return;   // fail loudly (poisoned out) if ws too small

    // ---- prep ----
    conv_split<<<dim3(8192), 256, 0, stream>>>(x, x_hi, x_lo, 2097152);
    // Wht[4096][1024] from Wh0[1024][4096]
    transpose_split<<<dim3(128, 32), 256, 0, stream>>>(Wh0, G4, Whthi, Whtlo, HDIM, 0, 0);
    // Wxt[5120][256] from Wx0[256][4096] and Wproj[256][1024]
    transpose_split<<<dim3(128, 8),  256, 0, stream>>>(Wx0,   G4,   Wxthi, Wxtlo, INDIM, 0,    0);
    transpose_split<<<dim3(32, 8),   256, 0, stream>>>(Wproj, HDIM, Wxthi, Wxtlo, INDIM, 4096, 0);
    // W1t[4096][2048] = [Wx1 ; Wh1] transposed
    transpose_split<<<dim3(128, 32), 256, 0, stream>>>(Wx1, G4, W1thi, W1tlo, 2048, 0, 0);
    transpose_split<<<dim3(128, 32), 256, 0, stream>>>(Wh1, G4, W1thi, W1tlo, 2048, 0, 1024);
    // zero parts0 buf0 (gates0 h-part at t=0 is h0(-1)=0) + barrier block
    hipMemsetAsync(parts0, 0, (size_t)2 * BSZ * G4 * 4, stream);
    hipMemsetAsync(bar, 0, 40960, stream);

    // ---- the whole recurrence: one persistent kernel ----
    persistent<<<dim3(NBLK), dim3(NTHR), LDS_BYTES, stream>>>(
        x_hi, x_lo, Whthi, Whtlo, Wxthi, Wxtlo, W1thi, W1tlo, b0, b1,
        lnc_g, lnc_b, lnh_g, lnh_b, lno_g, lno_b,
        xg, parts0, parts1,
        h0hi, h0lo, h1hi, h1lo, out, bar);
}

// Round 11
// 27434.195 us; speedup vs baseline: 1.9783x; 1.3396x over previous
//
#include <hip/hip_runtime.h>
#include <math.h>

// Problem dims
#define TSTEPS 512
#define BSZ    64
#define INDIM  256
#define HDIM   1024
#define G4     4096
#define NX     5120   // xg cols: 4096 gate + 1024 proj
#define LN_EPS 1e-5f

#define NBLK   256
#define NTHR   1024
#define CHUNK  8
#define CROWS  (CHUNK * BSZ)
#define NCHUNK (TSTEPS / CHUNK)
#define HRING  16            // h ring slots; acquire fence every 8 steps
#define HSLOT  65536         // u16 per slot (64 x 1024)

// LDS: W1 strip [16 cols][2054] hi then lo (stride == 3 mod 32 dwords: conflict-free)
#define LDS_LDK    2054
#define LDS_LO_OFF (16 * LDS_LDK)
#define LDS_W_BYTES (2 * 16 * LDS_LDK * 2)
#define LDS_STG_OFF LDS_W_BYTES
#define LDS_RED_OFF (LDS_W_BYTES + 4096)
#define LDS_BYTES   (LDS_W_BYTES + 4096 + 256)

typedef short          s8v __attribute__((ext_vector_type(8)));
typedef float          f4v __attribute__((ext_vector_type(4)));
typedef unsigned short u16;

#define MFMA __builtin_amdgcn_mfma_f32_16x16x32_bf16

__device__ __forceinline__ u16 f2bf(float f) {
    unsigned u = __float_as_uint(f);
    u += 0x7FFFu + ((u >> 16) & 1u);
    return (u16)(u >> 16);
}
__device__ __forceinline__ float bf2f(u16 h) {
    return __uint_as_float(((unsigned)h) << 16);
}
__device__ __forceinline__ float sigm(float x) { return 1.f / (1.f + expf(-x)); }

// ---- sc1 (L2-bypass, always-fresh) accessors for read-once mutable data ----
__device__ __forceinline__ float aldf(const float* p) {
    unsigned v = __hip_atomic_load((unsigned*)p, __ATOMIC_RELAXED,
                                   __HIP_MEMORY_SCOPE_AGENT);
    return __uint_as_float(v);
}
__device__ __forceinline__ void astf(float* p, float v) {
    __hip_atomic_store((unsigned*)p, __float_as_uint(v), __ATOMIC_RELAXED,
                       __HIP_MEMORY_SCOPE_AGENT);
}
// 16B sc1 store (write-through to L3; drained by barrier's vmcnt(0))
__device__ __forceinline__ void ast16B(u16* p, s8v v) {
    asm volatile("global_store_dwordx4 %0, %1, off sc1"
                 :: "v"(p), "v"(v) : "memory");
}

// ---------------- tree grid barrier ---------------------------------------
// R4-R10 lessons: tree arrivals (16 groups x 16, 2KB-strided lines) + busy
// -spin relaxed load polls. NO per-barrier fences: all cross-block mutable
// data is sc1 (at L3 once vmcnt drains) or ring-addressed. Acquire fence
// only when `fence` (every 8th step) to bound ring-slot cache lifetime;
// weights stay L2-resident 7 of 8 steps.
#define GSTRIDE 512
__device__ __forceinline__ void grid_barrier(int* bar, int nbar, bool fence)
{
    asm volatile("s_waitcnt vmcnt(0)" ::: "memory");
    __syncthreads();
    if (threadIdx.x == 0) {
        const int blk = blockIdx.x;
        const int g   = blk & 15;
        int* gctr = bar + g * GSTRIDE;
        int* ggo  = gctr + 32;
        int* root = bar + 16 * GSTRIDE;
        int v = __hip_atomic_fetch_add(gctr, 1, __ATOMIC_RELAXED,
                                       __HIP_MEMORY_SCOPE_AGENT);
        if (v == nbar * 16 - 1)
            __hip_atomic_fetch_add(root, 1, __ATOMIC_RELAXED,
                                   __HIP_MEMORY_SCOPE_AGENT);
        if (blk < 16) {
            while (__hip_atomic_load(root, __ATOMIC_RELAXED,
                                     __HIP_MEMORY_SCOPE_AGENT) < nbar * 16) {}
            __hip_atomic_store(ggo, nbar, __ATOMIC_RELAXED,
                               __HIP_MEMORY_SCOPE_AGENT);
        } else {
            while (__hip_atomic_load(ggo, __ATOMIC_RELAXED,
                                     __HIP_MEMORY_SCOPE_AGENT) < nbar) {}
        }
        if (fence)
            __builtin_amdgcn_fence(__ATOMIC_ACQUIRE, "agent");  // inv L1/L2
        asm volatile("" ::: "memory");
    }
    __syncthreads();
}

// ---------------- taskA: gates0 h-part. g in [0,2048) ---------------------
// ks=g&1 (K window 512), tile=g>>1: rt=tile&3, ct=tile>>2 (256 col-tiles)
__device__ __forceinline__ void taskA(int g, int lane,
    const u16* __restrict__ h0hi_s, const u16* __restrict__ h0lo_s,
    const u16* __restrict__ Whthi, const u16* __restrict__ Whtlo,
    float* __restrict__ parts0)
{
    const int ks = g & 1, tile = g >> 1;
    const int rt = tile & 3, ct = tile >> 2;
    const int row = lane & 15, kg = lane >> 4;
    const int m = rt * 16 + row;
    const u16* wh = Whthi + (size_t)(ct * 16 + row) * HDIM;   // cached (L2-warm)
    const u16* wl = Whtlo + (size_t)(ct * 16 + row) * HDIM;
    const u16* ah = h0hi_s + (size_t)m * HDIM;                // cached ring slot
    const u16* al = h0lo_s + (size_t)m * HDIM;
    f4v acc = {0.f, 0.f, 0.f, 0.f};
    const int kbeg = ks * 512;
#pragma unroll 8
    for (int kc = kbeg; kc < kbeg + 512; kc += 32) {
        const int kk = kc + kg * 8;
        s8v Ah = *(const s8v*)(ah + kk);
        s8v Al = *(const s8v*)(al + kk);
        s8v Bh = *(const s8v*)(wh + kk);
        s8v Bl = *(const s8v*)(wl + kk);
        acc = MFMA(Ah, Bh, acc, 0, 0, 0);
        acc = MFMA(Ah, Bl, acc, 0, 0, 0);
        acc = MFMA(Al, Bh, acc, 0, 0, 0);
    }
    float* Cp = parts0 + (size_t)ks * BSZ * G4;
#pragma unroll
    for (int r = 0; r < 4; ++r)
        astf(&Cp[(size_t)(rt * 16 + kg * 4 + r) * G4 + ct * 16 + row], acc[r]);
}

// ---------------- taskX: xg chunk GEMM, one 16x16 tile, K=256 -------------
__device__ __forceinline__ void taskX(int task, int c, int lane,
    const u16* __restrict__ xhi, const u16* __restrict__ xlo,
    const u16* __restrict__ Wxthi, const u16* __restrict__ Wxtlo,
    float* __restrict__ xgbuf)
{
    const int mt = task & 31, ct = task >> 5;
    const int row = lane & 15, kg = lane >> 4;
    const int mr = mt * 16 + row;
    const u16* ah = xhi + ((size_t)c * CROWS + mr) * INDIM;
    const u16* al = xlo + ((size_t)c * CROWS + mr) * INDIM;
    const u16* wh = Wxthi + (size_t)(ct * 16 + row) * INDIM;
    const u16* wl = Wxtlo + (size_t)(ct * 16 + row) * INDIM;
    f4v acc = {0.f, 0.f, 0.f, 0.f};
#pragma unroll 4
    for (int kc = 0; kc < INDIM; kc += 32) {
        const int kk = kc + kg * 8;
        s8v Ah = *(const s8v*)(ah + kk);
        s8v Al = *(const s8v*)(al + kk);
        s8v Bh = *(const s8v*)(wh + kk);
        s8v Bl = *(const s8v*)(wl + kk);
        acc = MFMA(Ah, Bh, acc, 0, 0, 0);
        acc = MFMA(Ah, Bl, acc, 0, 0, 0);
        acc = MFMA(Al, Bh, acc, 0, 0, 0);
    }
#pragma unroll
    for (int r = 0; r < 4; ++r)
        astf(&xgbuf[(size_t)(mt * 16 + kg * 4 + r) * NX + ct * 16 + row], acc[r]);
}

// ---------------- taskC: GEMM1, block owns 16 cols (LDS strip) ------------
// wv in 0..7: rt=wv&3, hs=wv>>2 (0: h0 K-half, 1: h1 K-half)
__device__ __forceinline__ void taskC(int blk, int wv, int lane,
    const u16* __restrict__ shW,
    const u16* __restrict__ h0hi_s, const u16* __restrict__ h0lo_s,
    const u16* __restrict__ h1hi_s, const u16* __restrict__ h1lo_s,
    float* __restrict__ parts1)
{
    const int rt = wv & 3, hs = wv >> 2;
    const int row = lane & 15, kg = lane >> 4;
    const int m = rt * 16 + row;
    const u16* ah0 = (hs ? h1hi_s : h0hi_s) + (size_t)m * HDIM;
    const u16* al0 = (hs ? h1lo_s : h0lo_s) + (size_t)m * HDIM;
    const u16* sh  = shW + row * LDS_LDK + hs * 1024;
    const u16* sl  = shW + LDS_LO_OFF + row * LDS_LDK + hs * 1024;
    f4v acc = {0.f, 0.f, 0.f, 0.f};
#pragma unroll 8
    for (int i = 0; i < 32; ++i) {
        const int kloc = i * 32 + kg * 8;
        s8v Ah = *(const s8v*)(ah0 + kloc);
        s8v Al = *(const s8v*)(al0 + kloc);
        s8v Bh = *(const s8v*)(sh + kloc);
        s8v Bl = *(const s8v*)(sl + kloc);
        acc = MFMA(Ah, Bh, acc, 0, 0, 0);
        acc = MFMA(Ah, Bl, acc, 0, 0, 0);
        acc = MFMA(Al, Bh, acc, 0, 0, 0);
    }
    float* Cp = parts1 + (size_t)hs * BSZ * G4;
#pragma unroll
    for (int r = 0; r < 4; ++r)
        astf(&Cp[(size_t)(rt * 16 + kg * 4 + r) * G4 + blk * 16 + row], acc[r]);
}

// ---------------- block reduction + LN helpers ----------------------------
__device__ __forceinline__ float2 blk_sum2(float s, float q, float* red, int tid)
{
#pragma unroll
    for (int off = 32; off; off >>= 1) {
        s += __shfl_down(s, off);
        q += __shfl_down(q, off);
    }
    if ((tid & 63) == 0) { red[(tid >> 6) * 2] = s; red[(tid >> 6) * 2 + 1] = q; }
    __syncthreads();
    float ts = 0.f, tq = 0.f;
#pragma unroll
    for (int i = 0; i < 16; ++i) { ts += red[2 * i]; tq += red[2 * i + 1]; }
    __syncthreads();
    return make_float2(ts, tq);
}

__device__ __forceinline__ float lnorm(float v, float2 sq, float g, float b)
{
    float mean = sq.x * (1.f / 1024.f);
    float var  = sq.y * (1.f / 1024.f) - mean * mean;
    return (v - mean) * rsqrtf(var + LN_EPS) * g + b;
}

// stage h (hi,lo per-thread u16) through LDS -> 16B sc1 stores
__device__ __forceinline__ void store_h_16B(u16* stg, int tid,
                                            u16 hi, u16 lo,
                                            u16* dhi, u16* dlo, int base)
{
    stg[tid] = hi;
    stg[1024 + tid] = lo;
    __syncthreads();
    if (tid < 256) {
        const u16* src = stg + (tid >> 7) * 1024 + (tid & 127) * 8;
        s8v v = *(const s8v*)src;
        u16* dst = ((tid >> 7) == 0 ? dhi : dlo) + base + (tid & 127) * 8;
        ast16B(dst, v);
    }
    __syncthreads();
}

// =====================================================================
__global__ __launch_bounds__(NTHR, 4) void persistent(
    const u16* __restrict__ xhi,  const u16* __restrict__ xlo,
    const u16* __restrict__ Whthi, const u16* __restrict__ Whtlo,
    const u16* __restrict__ Wxthi, const u16* __restrict__ Wxtlo,
    const u16* __restrict__ W1thi, const u16* __restrict__ W1tlo,
    const float* __restrict__ b0, const float* __restrict__ b1,
    const float* __restrict__ lncg, const float* __restrict__ lncb,
    const float* __restrict__ lnhg, const float* __restrict__ lnhb,
    const float* __restrict__ lnog, const float* __restrict__ lnob,
    float* __restrict__ xg,                        // [2][512][5120]  (sc1)
    float* __restrict__ parts0,                    // [2][64][4096]   (sc1)
    float* __restrict__ parts1,                    // [2][64][4096]   (sc1)
    u16* __restrict__ h0hi, u16* __restrict__ h0lo,// [HRING][64][1024]
    u16* __restrict__ h1hi, u16* __restrict__ h1lo,// [HRING][64][1024]
    float* __restrict__ out, int* bar)
{
    extern __shared__ char smem[];
    u16*   shW = (u16*)smem;
    u16*   stg = (u16*)(smem + LDS_STG_OFF);
    float* red = (float*)(smem + LDS_RED_OFF);

    const int blk  = blockIdx.x;
    const int tid  = threadIdx.x;
    const int wv   = tid >> 6;
    const int lane = tid & 63;
    int nbar = 0;

    // recurrent per-thread state:
    //   blocks 0..63: c0,h0 of batch row blk; blocks 64..127: c1,h1 of row blk-64
    float c0reg = 0.f, h0reg = 0.f, c1reg = 0.f, h1reg = 0.f;

    // ---- prologue: LDS W1 strip (cols blk*16..+16, K=2048) ----
    {
        const size_t gcol = (size_t)(blk * 16 + wv) * 2048;
        for (int j = lane * 8; j < 2048; j += 512) {
            *(s8v*)(shW + wv * LDS_LDK + j)              = *(const s8v*)(W1thi + gcol + j);
            *(s8v*)(shW + LDS_LO_OFF + wv * LDS_LDK + j) = *(const s8v*)(W1tlo + gcol + j);
        }
    }
    grid_barrier(bar, ++nbar, false);

    // ---- prologue: xg chunk 0 (all blocks; 10240 tasks / 4096 waves) ----
    {
        const int g = blk * 16 + wv;
        for (int task = g; task < 10240; task += 4096)
            taskX(task, 0, lane, xhi, xlo, Wxthi, Wxtlo, xg);
    }
    grid_barrier(bar, ++nbar, false);
    // parts0 zeroed host-side (h0(-1)=0); h rings zeroed host-side.

    for (int t = 0; t < TSTEPS; ++t) {
        const int s0  = t & (HRING - 1);            // h0(t) slot
        const int s0p = (t - 1) & (HRING - 1);      // h0(t-1) slot
        const int s1p = (t - 1) & (HRING - 1);      // h1(t-1) slot
        const bool fence = ((t & 7) == 7);

        // ================= phase 1: cells (+ xg chunk on idle blocks) =====
        if (blk < 64) {
            // ---- cell0(t): row b = blk ----
            const int b = blk, n = tid;
            const float* XG = xg + (size_t)((t >> 3) & 1) * CROWS * NX
                                 + (size_t)((t & 7) * BSZ + b) * NX;
            const float* P0 = parts0 + (size_t)b * G4;
            const float* P1 = parts0 + (size_t)(BSZ + b) * G4;
            float gi = aldf(&XG[n])        + aldf(&P0[n])        + aldf(&P1[n])        + b0[n];
            float gf = aldf(&XG[1024 + n]) + aldf(&P0[1024 + n]) + aldf(&P1[1024 + n]) + b0[1024 + n];
            float gg = aldf(&XG[2048 + n]) + aldf(&P0[2048 + n]) + aldf(&P1[2048 + n]) + b0[2048 + n];
            float go = aldf(&XG[3072 + n]) + aldf(&P0[3072 + n]) + aldf(&P1[3072 + n]) + b0[3072 + n];
            float xp = aldf(&XG[4096 + n]);
            float cv = sigm(gf) * c0reg + expf(gi) * tanhf(gg);
            float2 r = blk_sum2(cv, cv * cv, red, tid);
            float cl = lnorm(cv, r, lncg[n], lncb[n]);
            c0reg = cl;
            float hv = sigm(go) * tanhf(cl);
            r = blk_sum2(hv, hv * hv, red, tid);
            float hl = lnorm(hv, r, lnhg[n], lnhb[n]) + xp;
            r = blk_sum2(hl, hl * hl, red, tid);
            float hn = lnorm(hl, r, lnog[n], lnob[n]);
            h0reg = hn;
            u16 hi = f2bf(hn);
            store_h_16B(stg, tid, hi, f2bf(hn - bf2f(hi)),
                        h0hi + (size_t)s0 * HSLOT, h0lo + (size_t)s0 * HSLOT,
                        b * HDIM);
        } else if (blk < 128) {
            if (t > 0) {
                // ---- cell1(t-1): row b = blk-64 ----
                const int b = blk - 64, n = tid;
                const float* P0 = parts1 + (size_t)b * G4;
                const float* P1 = parts1 + (size_t)(BSZ + b) * G4;
                float gi = aldf(&P0[n])        + aldf(&P1[n])        + b1[n];
                float gf = aldf(&P0[1024 + n]) + aldf(&P1[1024 + n]) + b1[1024 + n];
                float gg = aldf(&P0[2048 + n]) + aldf(&P1[2048 + n]) + b1[2048 + n];
                float go = aldf(&P0[3072 + n]) + aldf(&P1[3072 + n]) + b1[3072 + n];
                float cv = sigm(gf) * c1reg + expf(gi) * tanhf(gg);
                float2 r = blk_sum2(cv, cv * cv, red, tid);
                float cl = lnorm(cv, r, lncg[HDIM + n], lncb[HDIM + n]);
                c1reg = cl;
                float hv = sigm(go) * tanhf(cl);
                r = blk_sum2(hv, hv * hv, red, tid);
                // residual h0(t-1): cached ring read (hi+lo ~ fp32)
                float h0v = bf2f(h0hi[(size_t)s0p * HSLOT + b * HDIM + n])
                          + bf2f(h0lo[(size_t)s0p * HSLOT + b * HDIM + n]);
                float hl = lnorm(hv, r, lnhg[HDIM + n], lnhb[HDIM + n]) + h0v;
                r = blk_sum2(hl, hl * hl, red, tid);
                float hn = lnorm(hl, r, lnog[HDIM + n], lnob[HDIM + n]);
                h1reg = hn;
                u16 hi = f2bf(hn);
                out[(size_t)(t - 1) * BSZ * HDIM + b * HDIM + n] = hn;
                store_h_16B(stg, tid, hi, f2bf(hn - bf2f(hi)),
                            h1hi + (size_t)s1p * HSLOT, h1lo + (size_t)s1p * HSLOT,
                            b * HDIM);
            }
        } else if ((t & 7) == 7 && (t >> 3) + 1 < NCHUNK) {
            // xg chunk (t>>3)+1 on blocks 128..255 (10240 tasks / 2048 waves)
            const int c = (t >> 3) + 1;
            float* xgbuf = xg + (size_t)(c & 1) * CROWS * NX;
            const int g = (blk - 128) * 16 + wv;
            for (int i = 0; i < 5; ++i)
                taskX(g + 2048 * i, c, lane, xhi, xlo, Wxthi, Wxtlo, xgbuf);
        }
        grid_barrier(bar, ++nbar, false);

        // ================= phase 2: GEMMs (all blocks) ====================
        // wv 0-7: taskC(t) reads h0(t) slot s0, h1(t-1) slot s1p
        // wv 8-15: taskA(t+1) reads h0(t) slot s0
        if (wv < 8) {
            taskC(blk, wv, lane, shW,
                  h0hi + (size_t)s0 * HSLOT,  h0lo + (size_t)s0 * HSLOT,
                  h1hi + (size_t)s1p * HSLOT, h1lo + (size_t)s1p * HSLOT,
                  parts1);
        } else if (t + 1 < TSTEPS) {
            taskA(blk * 8 + (wv - 8), lane,
                  h0hi + (size_t)s0 * HSLOT, h0lo + (size_t)s0 * HSLOT,
                  Whthi, Whtlo, parts0);
        }
        grid_barrier(bar, ++nbar, fence);
    }

    // ---- epilogue: cell1(511) ----
    if (blk >= 64 && blk < 128) {
        const int b = blk - 64, n = tid;
        const int tp = TSTEPS - 1;
        const int sp = tp & (HRING - 1);
        const float* P0 = parts1 + (size_t)b * G4;
        const float* P1 = parts1 + (size_t)(BSZ + b) * G4;
        float gi = aldf(&P0[n])        + aldf(&P1[n])        + b1[n];
        float gf = aldf(&P0[1024 + n]) + aldf(&P1[1024 + n]) + b1[1024 + n];
        float gg = aldf(&P0[2048 + n]) + aldf(&P1[2048 + n]) + b1[2048 + n];
        float go = aldf(&P0[3072 + n]) + aldf(&P1[3072 + n]) + b1[3072 + n];
        float cv = sigm(gf) * c1reg + expf(gi) * tanhf(gg);
        float2 r = blk_sum2(cv, cv * cv, red, tid);
        float cl = lnorm(cv, r, lncg[HDIM + n], lncb[HDIM + n]);
        c1reg = cl;
        float hv = sigm(go) * tanhf(cl);
        r = blk_sum2(hv, hv * hv, red, tid);
        float h0v = bf2f(h0hi[(size_t)sp * HSLOT + b * HDIM + n])
                  + bf2f(h0lo[(size_t)sp * HSLOT + b * HDIM + n]);
        float hl = lnorm(hv, r, lnhg[HDIM + n], lnhb[HDIM + n]) + h0v;
        r = blk_sum2(hl, hl * hl, red, tid);
        float hn = lnorm(hl, r, lnog[HDIM + n], lnob[HDIM + n]);
        h1reg = hn;
        out[(size_t)tp * BSZ * HDIM + b * HDIM + n] = hn;
    }

    // ---- final states: h0, h1, c0, c1 ----
    {
        const size_t F = (size_t)TSTEPS * BSZ * HDIM;
        if (blk < 64) {
            out[F +          blk * HDIM + tid] = h0reg;
            out[F + 131072 + blk * HDIM + tid] = c0reg;
        } else if (blk < 128) {
            const int b = blk - 64;
            out[F +  65536 + b * HDIM + tid] = h1reg;
            out[F + 196608 + b * HDIM + tid] = c1reg;
        }
    }
}

// =====================================================================
// prep kernels
// =====================================================================
__global__ __launch_bounds__(256) void transpose_split(
    const float* __restrict__ src, int N,
    u16* __restrict__ dsthi, u16* __restrict__ dstlo,
    int ldd, int noff, int koff)
{
    __shared__ float tile[32][33];
    const int n0 = blockIdx.x * 32, k0 = blockIdx.y * 32;
    const int tx = threadIdx.x & 31, ty = threadIdx.x >> 5;
#pragma unroll
    for (int i = 0; i < 4; ++i)
        tile[ty + i * 8][tx] = src[(size_t)(k0 + ty + i * 8) * N + n0 + tx];
    __syncthreads();
#pragma unroll
    for (int i = 0; i < 4; ++i) {
        float v = tile[tx][ty + i * 8];
        u16 hi = f2bf(v);
        u16 lo = f2bf(v - bf2f(hi));
        size_t idx = (size_t)(n0 + ty + i * 8 + noff) * ldd + k0 + koff + tx;
        dsthi[idx] = hi;
        dstlo[idx] = lo;
    }
}

__global__ void conv_split(const float* __restrict__ src,
                           u16* __restrict__ hi, u16* __restrict__ lo, int n4)
{
    int i = blockIdx.x * 256 + threadIdx.x;
    if (i < n4) {
        float4 v = ((const float4*)src)[i];
        ushort4 h, l;
        h.x = f2bf(v.x); l.x = f2bf(v.x - bf2f(h.x));
        h.y = f2bf(v.y); l.y = f2bf(v.y - bf2f(h.y));
        h.z = f2bf(v.z); l.z = f2bf(v.z - bf2f(h.z));
        h.w = f2bf(v.w); l.w = f2bf(v.w - bf2f(h.w));
        ((ushort4*)hi)[i] = h;
        ((ushort4*)lo)[i] = l;
    }
}

// =====================================================================
extern "C" void kernel_launch(void* const* d_in, const int* in_sizes, int n_in,
                              void* d_out, int out_size, void* d_ws, size_t ws_size,
                              hipStream_t stream)
{
    const float* x     = (const float*)d_in[0];
    const float* Wproj = (const float*)d_in[1];
    const float* Wx0   = (const float*)d_in[2];
    const float* Wh0   = (const float*)d_in[3];
    const float* b0    = (const float*)d_in[4];
    const float* Wx1   = (const float*)d_in[5];
    const float* Wh1   = (const float*)d_in[6];
    const float* b1    = (const float*)d_in[7];
    const float* lnc_g = (const float*)d_in[8];
    const float* lnc_b = (const float*)d_in[9];
    const float* lnh_g = (const float*)d_in[10];
    const float* lnh_b = (const float*)d_in[11];
    const float* lno_g = (const float*)d_in[12];
    const float* lno_b = (const float*)d_in[13];
    float* out = (float*)d_out;

    // ---- ws layout (~122 MB; R10's 126 MB passed the guard) ----
    char* base = (char*)d_ws;
    size_t o = 0;
    u16* x_hi  = (u16*)(base + o); o += (size_t)TSTEPS * BSZ * INDIM * 2;
    u16* x_lo  = (u16*)(base + o); o += (size_t)TSTEPS * BSZ * INDIM * 2;
    u16* Whthi = (u16*)(base + o); o += (size_t)G4 * HDIM * 2;
    u16* Whtlo = (u16*)(base + o); o += (size_t)G4 * HDIM * 2;
    u16* Wxthi = (u16*)(base + o); o += (size_t)NX * INDIM * 2;
    u16* Wxtlo = (u16*)(base + o); o += (size_t)NX * INDIM * 2;
    u16* W1thi = (u16*)(base + o); o += (size_t)G4 * 2048 * 2;
    u16* W1tlo = (u16*)(base + o); o += (size_t)G4 * 2048 * 2;
    float* xg     = (float*)(base + o); o += (size_t)2 * CROWS * NX * 4;
    float* parts0 = (float*)(base + o); o += (size_t)2 * BSZ * G4 * 4;
    float* parts1 = (float*)(base + o); o += (size_t)2 * BSZ * G4 * 4;
    u16* h0hi = (u16*)(base + o); o += (size_t)HRING * HSLOT * 2;
    u16* h0lo = (u16*)(base + o); o += (size_t)HRING * HSLOT * 2;
    u16* h1hi = (u16*)(base + o); o += (size_t)HRING * HSLOT * 2;
    u16* h1lo = (u16*)(base + o); o += (size_t)HRING * HSLOT * 2;
    int* bar  = (int*)(base + o); o += 40960;
    if (ws_size < o) return;   // fail loudly (poisoned out) if ws too small

    // ---- prep ----
    conv_split<<<dim3(8192), 256, 0, stream>>>(x, x_hi, x_lo, 2097152);
    transpose_split<<<dim3(128, 32), 256, 0, stream>>>(Wh0, G4, Whthi, Whtlo, HDIM, 0, 0);
    transpose_split<<<dim3(128, 8),  256, 0, stream>>>(Wx0,   G4,   Wxthi, Wxtlo, INDIM, 0,    0);
    transpose_split<<<dim3(32, 8),   256, 0, stream>>>(Wproj, HDIM, Wxthi, Wxtlo, INDIM, 4096, 0);
    transpose_split<<<dim3(128, 32), 256, 0, stream>>>(Wx1, G4, W1thi, W1tlo, 2048, 0, 0);
    transpose_split<<<dim3(128, 32), 256, 0, stream>>>(Wh1, G4, W1thi, W1tlo, 2048, 0, 1024);
    // zero: parts0 (h0(-1)=0), h rings (first reads must be 0), barrier block
    hipMemsetAsync(parts0, 0, (size_t)2 * BSZ * G4 * 4, stream);
    hipMemsetAsync(h0hi, 0, (size_t)4 * HRING * HSLOT * 2, stream);  // h0hi..h1lo contiguous
    hipMemsetAsync(bar, 0, 40960, stream);

    // ---- the whole recurrence: one persistent kernel ----
    persistent<<<dim3(NBLK), dim3(NTHR), LDS_BYTES, stream>>>(
        x_hi, x_lo, Whthi, Whtlo, Wxthi, Wxtlo, W1thi, W1tlo, b0, b1,
        lnc_g, lnc_b, lnh_g, lnh_b, lno_g, lno_b,
        xg, parts0, parts1,
        h0hi, h0lo, h1hi, h1lo, out, bar);
}

// Round 12
// 25687.262 us; speedup vs baseline: 2.1129x; 1.0680x over previous
//
#include <hip/hip_runtime.h>
#include <math.h>

// Problem dims
#define TSTEPS 512
#define BSZ    64
#define INDIM  256
#define HDIM   1024
#define G4     4096
#define NX     5120   // xg cols: 4096 gate + 1024 proj
#define LN_EPS 1e-5f

#define NBLK   256
#define NTHR   1024
#define CHUNK  8
#define CROWS  (CHUNK * BSZ)
#define NCHUNK (TSTEPS / CHUNK)
#define HRING  16            // h ring slots; acquire fence every 8 steps
#define HSLOT  65536         // u16 per slot (64 x 1024)

// LDS: W1 strip [16 cols][2054] hi then lo (stride == 3 mod 32 dwords: conflict-free)
#define LDS_LDK    2054
#define LDS_LO_OFF (16 * LDS_LDK)
#define LDS_W_BYTES (2 * 16 * LDS_LDK * 2)
#define LDS_STG_OFF LDS_W_BYTES
#define LDS_RED_OFF (LDS_W_BYTES + 4096)
#define LDS_BYTES   (LDS_W_BYTES + 4096 + 256)

typedef short          s8v __attribute__((ext_vector_type(8)));
typedef float          f4v __attribute__((ext_vector_type(4)));
typedef unsigned short u16;

#define MFMA __builtin_amdgcn_mfma_f32_16x16x32_bf16

__device__ __forceinline__ u16 f2bf(float f) {
    unsigned u = __float_as_uint(f);
    u += 0x7FFFu + ((u >> 16) & 1u);
    return (u16)(u >> 16);
}
__device__ __forceinline__ float bf2f(u16 h) {
    return __uint_as_float(((unsigned)h) << 16);
}
__device__ __forceinline__ float sigm(float x) { return 1.f / (1.f + expf(-x)); }

// ---- sc1 (L2-bypass, always-fresh) accessors for read-once mutable data ----
__device__ __forceinline__ float aldf(const float* p) {
    unsigned v = __hip_atomic_load((unsigned*)p, __ATOMIC_RELAXED,
                                   __HIP_MEMORY_SCOPE_AGENT);
    return __uint_as_float(v);
}
__device__ __forceinline__ void astf(float* p, float v) {
    __hip_atomic_store((unsigned*)p, __float_as_uint(v), __ATOMIC_RELAXED,
                       __HIP_MEMORY_SCOPE_AGENT);
}
// 16B sc1 store (write-through to L3; drained by barrier's vmcnt(0))
__device__ __forceinline__ void ast16B(u16* p, s8v v) {
    asm volatile("global_store_dwordx4 %0, %1, off sc1"
                 :: "v"(p), "v"(v) : "memory");
}

// ---------------- tree grid barrier ---------------------------------------
// R4-R11 lessons baked in: tree arrivals (16 groups x 16, 2KB-strided lines),
// busy-spin relaxed load polls, sc1/ring data plane, acquire fence only every
// 8th step (bounds ring-slot cache lifetime; weights stay L2-warm 7/8 steps).
#define GSTRIDE 512
__device__ __forceinline__ void grid_barrier(int* bar, int nbar, bool fence)
{
    asm volatile("s_waitcnt vmcnt(0)" ::: "memory");
    __syncthreads();
    if (threadIdx.x == 0) {
        const int blk = blockIdx.x;
        const int g   = blk & 15;
        int* gctr = bar + g * GSTRIDE;
        int* ggo  = gctr + 32;
        int* root = bar + 16 * GSTRIDE;
        int v = __hip_atomic_fetch_add(gctr, 1, __ATOMIC_RELAXED,
                                       __HIP_MEMORY_SCOPE_AGENT);
        if (v == nbar * 16 - 1)
            __hip_atomic_fetch_add(root, 1, __ATOMIC_RELAXED,
                                   __HIP_MEMORY_SCOPE_AGENT);
        if (blk < 16) {
            while (__hip_atomic_load(root, __ATOMIC_RELAXED,
                                     __HIP_MEMORY_SCOPE_AGENT) < nbar * 16) {}
            __hip_atomic_store(ggo, nbar, __ATOMIC_RELAXED,
                               __HIP_MEMORY_SCOPE_AGENT);
        } else {
            while (__hip_atomic_load(ggo, __ATOMIC_RELAXED,
                                     __HIP_MEMORY_SCOPE_AGENT) < nbar) {}
        }
        if (fence)
            __builtin_amdgcn_fence(__ATOMIC_ACQUIRE, "agent");  // inv L1/L2
        asm volatile("" ::: "memory");
    }
    __syncthreads();
}

// ---------------- taskA: gates0 h-part. g in [0,2048) ---------------------
// R12: depth-2 software prefetch on all four operand streams (VGPR cap is
// 128 at this occupancy; R11's source let the allocator squeeze to 64,
// serializing every iteration on L2/L3 load latency).
__device__ __forceinline__ void taskA(int g, int lane,
    const u16* __restrict__ h0hi_s, const u16* __restrict__ h0lo_s,
    const u16* __restrict__ Whthi, const u16* __restrict__ Whtlo,
    float* __restrict__ parts0)
{
    const int ks = g & 1, tile = g >> 1;
    const int rt = tile & 3, ct = tile >> 2;
    const int row = lane & 15, kg = lane >> 4;
    const int m = rt * 16 + row;
    const u16* wh = Whthi + (size_t)(ct * 16 + row) * HDIM + ks * 512 + kg * 8;
    const u16* wl = Whtlo + (size_t)(ct * 16 + row) * HDIM + ks * 512 + kg * 8;
    const u16* ah = h0hi_s + (size_t)m * HDIM + ks * 512 + kg * 8;
    const u16* al = h0lo_s + (size_t)m * HDIM + ks * 512 + kg * 8;
    f4v acc = {0.f, 0.f, 0.f, 0.f};
    s8v Ah = *(const s8v*)(ah);
    s8v Al = *(const s8v*)(al);
    s8v Bh = *(const s8v*)(wh);
    s8v Bl = *(const s8v*)(wl);
#pragma unroll
    for (int i = 0; i < 16; ++i) {
        s8v nAh, nAl, nBh, nBl;
        if (i + 1 < 16) {
            const int kn = (i + 1) * 32;
            nAh = *(const s8v*)(ah + kn);
            nAl = *(const s8v*)(al + kn);
            nBh = *(const s8v*)(wh + kn);
            nBl = *(const s8v*)(wl + kn);
        }
        acc = MFMA(Ah, Bh, acc, 0, 0, 0);
        acc = MFMA(Ah, Bl, acc, 0, 0, 0);
        acc = MFMA(Al, Bh, acc, 0, 0, 0);
        Ah = nAh; Al = nAl; Bh = nBh; Bl = nBl;
    }
    float* Cp = parts0 + (size_t)ks * BSZ * G4;
#pragma unroll
    for (int r = 0; r < 4; ++r)
        astf(&Cp[(size_t)(rt * 16 + kg * 4 + r) * G4 + ct * 16 + row], acc[r]);
}

// ---------------- taskX: xg chunk GEMM, one 16x16 tile, K=256 -------------
__device__ __forceinline__ void taskX(int task, int c, int lane,
    const u16* __restrict__ xhi, const u16* __restrict__ xlo,
    const u16* __restrict__ Wxthi, const u16* __restrict__ Wxtlo,
    float* __restrict__ xgbuf)
{
    const int mt = task & 31, ct = task >> 5;
    const int row = lane & 15, kg = lane >> 4;
    const int mr = mt * 16 + row;
    const u16* ah = xhi + ((size_t)c * CROWS + mr) * INDIM + kg * 8;
    const u16* al = xlo + ((size_t)c * CROWS + mr) * INDIM + kg * 8;
    const u16* wh = Wxthi + (size_t)(ct * 16 + row) * INDIM + kg * 8;
    const u16* wl = Wxtlo + (size_t)(ct * 16 + row) * INDIM + kg * 8;
    f4v acc = {0.f, 0.f, 0.f, 0.f};
    s8v Ah = *(const s8v*)(ah);
    s8v Al = *(const s8v*)(al);
    s8v Bh = *(const s8v*)(wh);
    s8v Bl = *(const s8v*)(wl);
#pragma unroll
    for (int i = 0; i < 8; ++i) {
        s8v nAh, nAl, nBh, nBl;
        if (i + 1 < 8) {
            const int kn = (i + 1) * 32;
            nAh = *(const s8v*)(ah + kn);
            nAl = *(const s8v*)(al + kn);
            nBh = *(const s8v*)(wh + kn);
            nBl = *(const s8v*)(wl + kn);
        }
        acc = MFMA(Ah, Bh, acc, 0, 0, 0);
        acc = MFMA(Ah, Bl, acc, 0, 0, 0);
        acc = MFMA(Al, Bh, acc, 0, 0, 0);
        Ah = nAh; Al = nAl; Bh = nBh; Bl = nBl;
    }
#pragma unroll
    for (int r = 0; r < 4; ++r)
        astf(&xgbuf[(size_t)(mt * 16 + kg * 4 + r) * NX + ct * 16 + row], acc[r]);
}

// ---------------- taskC: GEMM1, block owns 16 cols (LDS strip) ------------
// wv in 0..7: rt=wv&3, hs=wv>>2. Depth-2 prefetch on global A streams;
// LDS B reads stay in-loop (compiler's lgkmcnt scheduling is fine).
__device__ __forceinline__ void taskC(int blk, int wv, int lane,
    const u16* __restrict__ shW,
    const u16* __restrict__ h0hi_s, const u16* __restrict__ h0lo_s,
    const u16* __restrict__ h1hi_s, const u16* __restrict__ h1lo_s,
    float* __restrict__ parts1)
{
    const int rt = wv & 3, hs = wv >> 2;
    const int row = lane & 15, kg = lane >> 4;
    const int m = rt * 16 + row;
    const u16* ah0 = (hs ? h1hi_s : h0hi_s) + (size_t)m * HDIM + kg * 8;
    const u16* al0 = (hs ? h1lo_s : h0lo_s) + (size_t)m * HDIM + kg * 8;
    const u16* sh  = shW + row * LDS_LDK + hs * 1024 + kg * 8;
    const u16* sl  = shW + LDS_LO_OFF + row * LDS_LDK + hs * 1024 + kg * 8;
    f4v acc = {0.f, 0.f, 0.f, 0.f};
    s8v Ah = *(const s8v*)(ah0);
    s8v Al = *(const s8v*)(al0);
#pragma unroll
    for (int i = 0; i < 32; ++i) {
        s8v nAh, nAl;
        if (i + 1 < 32) {
            nAh = *(const s8v*)(ah0 + (i + 1) * 32);
            nAl = *(const s8v*)(al0 + (i + 1) * 32);
        }
        const int kloc = i * 32;
        s8v Bh = *(const s8v*)(sh + kloc);
        s8v Bl = *(const s8v*)(sl + kloc);
        acc = MFMA(Ah, Bh, acc, 0, 0, 0);
        acc = MFMA(Ah, Bl, acc, 0, 0, 0);
        acc = MFMA(Al, Bh, acc, 0, 0, 0);
        Ah = nAh; Al = nAl;
    }
    float* Cp = parts1 + (size_t)hs * BSZ * G4;
#pragma unroll
    for (int r = 0; r < 4; ++r)
        astf(&Cp[(size_t)(rt * 16 + kg * 4 + r) * G4 + blk * 16 + row], acc[r]);
}

// ---------------- block reduction + LN helpers ----------------------------
__device__ __forceinline__ float2 blk_sum2(float s, float q, float* red, int tid)
{
#pragma unroll
    for (int off = 32; off; off >>= 1) {
        s += __shfl_down(s, off);
        q += __shfl_down(q, off);
    }
    if ((tid & 63) == 0) { red[(tid >> 6) * 2] = s; red[(tid >> 6) * 2 + 1] = q; }
    __syncthreads();
    float ts = 0.f, tq = 0.f;
#pragma unroll
    for (int i = 0; i < 16; ++i) { ts += red[2 * i]; tq += red[2 * i + 1]; }
    __syncthreads();
    return make_float2(ts, tq);
}

__device__ __forceinline__ float lnorm(float v, float2 sq, float g, float b)
{
    float mean = sq.x * (1.f / 1024.f);
    float var  = sq.y * (1.f / 1024.f) - mean * mean;
    return (v - mean) * rsqrtf(var + LN_EPS) * g + b;
}

// stage h (hi,lo per-thread u16) through LDS -> 16B sc1 stores
__device__ __forceinline__ void store_h_16B(u16* stg, int tid,
                                            u16 hi, u16 lo,
                                            u16* dhi, u16* dlo, int base)
{
    stg[tid] = hi;
    stg[1024 + tid] = lo;
    __syncthreads();
    if (tid < 256) {
        const u16* src = stg + (tid >> 7) * 1024 + (tid & 127) * 8;
        s8v v = *(const s8v*)src;
        u16* dst = ((tid >> 7) == 0 ? dhi : dlo) + base + (tid & 127) * 8;
        ast16B(dst, v);
    }
    __syncthreads();
}

// =====================================================================
__global__ __launch_bounds__(NTHR, 4) void persistent(
    const u16* __restrict__ xhi,  const u16* __restrict__ xlo,
    const u16* __restrict__ Whthi, const u16* __restrict__ Whtlo,
    const u16* __restrict__ Wxthi, const u16* __restrict__ Wxtlo,
    const u16* __restrict__ W1thi, const u16* __restrict__ W1tlo,
    const float* __restrict__ b0, const float* __restrict__ b1,
    const float* __restrict__ lncg, const float* __restrict__ lncb,
    const float* __restrict__ lnhg, const float* __restrict__ lnhb,
    const float* __restrict__ lnog, const float* __restrict__ lnob,
    float* __restrict__ xg,                        // [2][512][5120]  (sc1)
    float* __restrict__ parts0,                    // [2][64][4096]   (sc1)
    float* __restrict__ parts1,                    // [2][64][4096]   (sc1)
    u16* __restrict__ h0hi, u16* __restrict__ h0lo,// [HRING][64][1024]
    u16* __restrict__ h1hi, u16* __restrict__ h1lo,// [HRING][64][1024]
    float* __restrict__ out, int* bar)
{
    extern __shared__ char smem[];
    u16*   shW = (u16*)smem;
    u16*   stg = (u16*)(smem + LDS_STG_OFF);
    float* red = (float*)(smem + LDS_RED_OFF);

    const int blk  = blockIdx.x;
    const int tid  = threadIdx.x;
    const int wv   = tid >> 6;
    const int lane = tid & 63;
    int nbar = 0;

    // recurrent per-thread state:
    //   blocks 0..63: c0,h0 of batch row blk; blocks 64..127: c1,h1 of row blk-64
    float c0reg = 0.f, h0reg = 0.f, c1reg = 0.f, h1reg = 0.f;

    // ---- prologue: LDS W1 strip (cols blk*16..+16, K=2048) ----
    {
        const size_t gcol = (size_t)(blk * 16 + wv) * 2048;
        for (int j = lane * 8; j < 2048; j += 512) {
            *(s8v*)(shW + wv * LDS_LDK + j)              = *(const s8v*)(W1thi + gcol + j);
            *(s8v*)(shW + LDS_LO_OFF + wv * LDS_LDK + j) = *(const s8v*)(W1tlo + gcol + j);
        }
    }
    grid_barrier(bar, ++nbar, false);

    // ---- prologue: xg chunk 0 (all blocks; 10240 tasks / 4096 waves) ----
    {
        const int g = blk * 16 + wv;
        for (int task = g; task < 10240; task += 4096)
            taskX(task, 0, lane, xhi, xlo, Wxthi, Wxtlo, xg);
    }
    grid_barrier(bar, ++nbar, false);
    // parts0 zeroed host-side (h0(-1)=0); h rings zeroed host-side.

    for (int t = 0; t < TSTEPS; ++t) {
        const int s0  = t & (HRING - 1);            // h0(t) slot
        const int s0p = (t - 1) & (HRING - 1);      // h0(t-1) slot
        const int s1p = (t - 1) & (HRING - 1);      // h1(t-1) slot
        const bool fence = ((t & 7) == 7);

        // ================= phase 1: cells (+ xg chunk on idle blocks) =====
        if (blk < 64) {
            // ---- cell0(t): row b = blk ----
            const int b = blk, n = tid;
            const float* XG = xg + (size_t)((t >> 3) & 1) * CROWS * NX
                                 + (size_t)((t & 7) * BSZ + b) * NX;
            const float* P0 = parts0 + (size_t)b * G4;
            const float* P1 = parts0 + (size_t)(BSZ + b) * G4;
            float gi = aldf(&XG[n])        + aldf(&P0[n])        + aldf(&P1[n])        + b0[n];
            float gf = aldf(&XG[1024 + n]) + aldf(&P0[1024 + n]) + aldf(&P1[1024 + n]) + b0[1024 + n];
            float gg = aldf(&XG[2048 + n]) + aldf(&P0[2048 + n]) + aldf(&P1[2048 + n]) + b0[2048 + n];
            float go = aldf(&XG[3072 + n]) + aldf(&P0[3072 + n]) + aldf(&P1[3072 + n]) + b0[3072 + n];
            float xp = aldf(&XG[4096 + n]);
            float cv = sigm(gf) * c0reg + expf(gi) * tanhf(gg);
            float2 r = blk_sum2(cv, cv * cv, red, tid);
            float cl = lnorm(cv, r, lncg[n], lncb[n]);
            c0reg = cl;
            float hv = sigm(go) * tanhf(cl);
            r = blk_sum2(hv, hv * hv, red, tid);
            float hl = lnorm(hv, r, lnhg[n], lnhb[n]) + xp;
            r = blk_sum2(hl, hl * hl, red, tid);
            float hn = lnorm(hl, r, lnog[n], lnob[n]);
            h0reg = hn;
            u16 hi = f2bf(hn);
            store_h_16B(stg, tid, hi, f2bf(hn - bf2f(hi)),
                        h0hi + (size_t)s0 * HSLOT, h0lo + (size_t)s0 * HSLOT,
                        b * HDIM);
        } else if (blk < 128) {
            if (t > 0) {
                // ---- cell1(t-1): row b = blk-64 ----
                const int b = blk - 64, n = tid;
                const float* P0 = parts1 + (size_t)b * G4;
                const float* P1 = parts1 + (size_t)(BSZ + b) * G4;
                float gi = aldf(&P0[n])        + aldf(&P1[n])        + b1[n];
                float gf = aldf(&P0[1024 + n]) + aldf(&P1[1024 + n]) + b1[1024 + n];
                float gg = aldf(&P0[2048 + n]) + aldf(&P1[2048 + n]) + b1[2048 + n];
                float go = aldf(&P0[3072 + n]) + aldf(&P1[3072 + n]) + b1[3072 + n];
                float cv = sigm(gf) * c1reg + expf(gi) * tanhf(gg);
                float2 r = blk_sum2(cv, cv * cv, red, tid);
                float cl = lnorm(cv, r, lncg[HDIM + n], lncb[HDIM + n]);
                c1reg = cl;
                float hv = sigm(go) * tanhf(cl);
                r = blk_sum2(hv, hv * hv, red, tid);
                // residual h0(t-1): cached ring read (hi+lo ~ fp32)
                float h0v = bf2f(h0hi[(size_t)s0p * HSLOT + b * HDIM + n])
                          + bf2f(h0lo[(size_t)s0p * HSLOT + b * HDIM + n]);
                float hl = lnorm(hv, r, lnhg[HDIM + n], lnhb[HDIM + n]) + h0v;
                r = blk_sum2(hl, hl * hl, red, tid);
                float hn = lnorm(hl, r, lnog[HDIM + n], lnob[HDIM + n]);
                h1reg = hn;
                u16 hi = f2bf(hn);
                out[(size_t)(t - 1) * BSZ * HDIM + b * HDIM + n] = hn;
                store_h_16B(stg, tid, hi, f2bf(hn - bf2f(hi)),
                            h1hi + (size_t)s1p * HSLOT, h1lo + (size_t)s1p * HSLOT,
                            b * HDIM);
            }
        } else if ((t & 7) == 7 && (t >> 3) + 1 < NCHUNK) {
            // xg chunk (t>>3)+1 on blocks 128..255 (10240 tasks / 2048 waves)
            const int c = (t >> 3) + 1;
            float* xgbuf = xg + (size_t)(c & 1) * CROWS * NX;
            const int g = (blk - 128) * 16 + wv;
            for (int i = 0; i < 5; ++i)
                taskX(g + 2048 * i, c, lane, xhi, xlo, Wxthi, Wxtlo, xgbuf);
        }
        grid_barrier(bar, ++nbar, false);

        // ================= phase 2: GEMMs (all blocks) ====================
        // wv 0-7: taskC(t) reads h0(t) slot s0, h1(t-1) slot s1p
        // wv 8-15: taskA(t+1) reads h0(t) slot s0
        if (wv < 8) {
            taskC(blk, wv, lane, shW,
                  h0hi + (size_t)s0 * HSLOT,  h0lo + (size_t)s0 * HSLOT,
                  h1hi + (size_t)s1p * HSLOT, h1lo + (size_t)s1p * HSLOT,
                  parts1);
        } else if (t + 1 < TSTEPS) {
            taskA(blk * 8 + (wv - 8), lane,
                  h0hi + (size_t)s0 * HSLOT, h0lo + (size_t)s0 * HSLOT,
                  Whthi, Whtlo, parts0);
        }
        grid_barrier(bar, ++nbar, fence);
    }

    // ---- epilogue: cell1(511) ----
    if (blk >= 64 && blk < 128) {
        const int b = blk - 64, n = tid;
        const int tp = TSTEPS - 1;
        const int sp = tp & (HRING - 1);
        const float* P0 = parts1 + (size_t)b * G4;
        const float* P1 = parts1 + (size_t)(BSZ + b) * G4;
        float gi = aldf(&P0[n])        + aldf(&P1[n])        + b1[n];
        float gf = aldf(&P0[1024 + n]) + aldf(&P1[1024 + n]) + b1[1024 + n];
        float gg = aldf(&P0[2048 + n]) + aldf(&P1[2048 + n]) + b1[2048 + n];
        float go = aldf(&P0[3072 + n]) + aldf(&P1[3072 + n]) + b1[3072 + n];
        float cv = sigm(gf) * c1reg + expf(gi) * tanhf(gg);
        float2 r = blk_sum2(cv, cv * cv, red, tid);
        float cl = lnorm(cv, r, lncg[HDIM + n], lncb[HDIM + n]);
        c1reg = cl;
        float hv = sigm(go) * tanhf(cl);
        r = blk_sum2(hv, hv * hv, red, tid);
        float h0v = bf2f(h0hi[(size_t)sp * HSLOT + b * HDIM + n])
                  + bf2f(h0lo[(size_t)sp * HSLOT + b * HDIM + n]);
        float hl = lnorm(hv, r, lnhg[HDIM + n], lnhb[HDIM + n]) + h0v;
        r = blk_sum2(hl, hl * hl, red, tid);
        float hn = lnorm(hl, r, lnog[HDIM + n], lnob[HDIM + n]);
        h1reg = hn;
        out[(size_t)tp * BSZ * HDIM + b * HDIM + n] = hn;
    }

    // ---- final states: h0, h1, c0, c1 ----
    {
        const size_t F = (size_t)TSTEPS * BSZ * HDIM;
        if (blk < 64) {
            out[F +          blk * HDIM + tid] = h0reg;
            out[F + 131072 + blk * HDIM + tid] = c0reg;
        } else if (blk < 128) {
            const int b = blk - 64;
            out[F +  65536 + b * HDIM + tid] = h1reg;
            out[F + 196608 + b * HDIM + tid] = c1reg;
        }
    }
}

// =====================================================================
// prep kernels
// =====================================================================
__global__ __launch_bounds__(256) void transpose_split(
    const float* __restrict__ src, int N,
    u16* __restrict__ dsthi, u16* __restrict__ dstlo,
    int ldd, int noff, int koff)
{
    __shared__ float tile[32][33];
    const int n0 = blockIdx.x * 32, k0 = blockIdx.y * 32;
    const int tx = threadIdx.x & 31, ty = threadIdx.x >> 5;
#pragma unroll
    for (int i = 0; i < 4; ++i)
        tile[ty + i * 8][tx] = src[(size_t)(k0 + ty + i * 8) * N + n0 + tx];
    __syncthreads();
#pragma unroll
    for (int i = 0; i < 4; ++i) {
        float v = tile[tx][ty + i * 8];
        u16 hi = f2bf(v);
        u16 lo = f2bf(v - bf2f(hi));
        size_t idx = (size_t)(n0 + ty + i * 8 + noff) * ldd + k0 + koff + tx;
        dsthi[idx] = hi;
        dstlo[idx] = lo;
    }
}

__global__ void conv_split(const float* __restrict__ src,
                           u16* __restrict__ hi, u16* __restrict__ lo, int n4)
{
    int i = blockIdx.x * 256 + threadIdx.x;
    if (i < n4) {
        float4 v = ((const float4*)src)[i];
        ushort4 h, l;
        h.x = f2bf(v.x); l.x = f2bf(v.x - bf2f(h.x));
        h.y = f2bf(v.y); l.y = f2bf(v.y - bf2f(h.y));
        h.z = f2bf(v.z); l.z = f2bf(v.z - bf2f(h.z));
        h.w = f2bf(v.w); l.w = f2bf(v.w - bf2f(h.w));
        ((ushort4*)hi)[i] = h;
        ((ushort4*)lo)[i] = l;
    }
}

// =====================================================================
extern "C" void kernel_launch(void* const* d_in, const int* in_sizes, int n_in,
                              void* d_out, int out_size, void* d_ws, size_t ws_size,
                              hipStream_t stream)
{
    const float* x     = (const float*)d_in[0];
    const float* Wproj = (const float*)d_in[1];
    const float* Wx0   = (const float*)d_in[2];
    const float* Wh0   = (const float*)d_in[3];
    const float* b0    = (const float*)d_in[4];
    const float* Wx1   = (const float*)d_in[5];
    const float* Wh1   = (const float*)d_in[6];
    const float* b1    = (const float*)d_in[7];
    const float* lnc_g = (const float*)d_in[8];
    const float* lnc_b = (const float*)d_in[9];
    const float* lnh_g = (const float*)d_in[10];
    const float* lnh_b = (const float*)d_in[11];
    const float* lno_g = (const float*)d_in[12];
    const float* lno_b = (const float*)d_in[13];
    float* out = (float*)d_out;

    // ---- ws layout (~122 MB) ----
    char* base = (char*)d_ws;
    size_t o = 0;
    u16* x_hi  = (u16*)(base + o); o += (size_t)TSTEPS * BSZ * INDIM * 2;
    u16* x_lo  = (u16*)(base + o); o += (size_t)TSTEPS * BSZ * INDIM * 2;
    u16* Whthi = (u16*)(base + o); o += (size_t)G4 * HDIM * 2;
    u16* Whtlo = (u16*)(base + o); o += (size_t)G4 * HDIM * 2;
    u16* Wxthi = (u16*)(base + o); o += (size_t)NX * INDIM * 2;
    u16* Wxtlo = (u16*)(base + o); o += (size_t)NX * INDIM * 2;
    u16* W1thi = (u16*)(base + o); o += (size_t)G4 * 2048 * 2;
    u16* W1tlo = (u16*)(base + o); o += (size_t)G4 * 2048 * 2;
    float* xg     = (float*)(base + o); o += (size_t)2 * CROWS * NX * 4;
    float* parts0 = (float*)(base + o); o += (size_t)2 * BSZ * G4 * 4;
    float* parts1 = (float*)(base + o); o += (size_t)2 * BSZ * G4 * 4;
    u16* h0hi = (u16*)(base + o); o += (size_t)HRING * HSLOT * 2;
    u16* h0lo = (u16*)(base + o); o += (size_t)HRING * HSLOT * 2;
    u16* h1hi = (u16*)(base + o); o += (size_t)HRING * HSLOT * 2;
    u16* h1lo = (u16*)(base + o); o += (size_t)HRING * HSLOT * 2;
    int* bar  = (int*)(base + o); o += 40960;
    if (ws_size < o) return;   // fail loudly (poisoned out) if ws too small

    // ---- prep ----
    conv_split<<<dim3(8192), 256, 0, stream>>>(x, x_hi, x_lo, 2097152);
    transpose_split<<<dim3(128, 32), 256, 0, stream>>>(Wh0, G4, Whthi, Whtlo, HDIM, 0, 0);
    transpose_split<<<dim3(128, 8),  256, 0, stream>>>(Wx0,   G4,   Wxthi, Wxtlo, INDIM, 0,    0);
    transpose_split<<<dim3(32, 8),   256, 0, stream>>>(Wproj, HDIM, Wxthi, Wxtlo, INDIM, 4096, 0);
    transpose_split<<<dim3(128, 32), 256, 0, stream>>>(Wx1, G4, W1thi, W1tlo, 2048, 0, 0);
    transpose_split<<<dim3(128, 32), 256, 0, stream>>>(Wh1, G4, W1thi, W1tlo, 2048, 0, 1024);
    // zero: parts0 (h0(-1)=0), h rings (first reads must be 0), barrier block
    hipMemsetAsync(parts0, 0, (size_t)2 * BSZ * G4 * 4, stream);
    hipMemsetAsync(h0hi, 0, (size_t)4 * HRING * HSLOT * 2, stream);  // h0hi..h1lo contiguous
    hipMemsetAsync(bar, 0, 40960, stream);

    // ---- the whole recurrence: one persistent kernel ----
    persistent<<<dim3(NBLK), dim3(NTHR), LDS_BYTES, stream>>>(
        x_hi, x_lo, Whthi, Whtlo, Wxthi, Wxtlo, W1thi, W1tlo, b0, b1,
        lnc_g, lnc_b, lnh_g, lnh_b, lno_g, lno_b,
        xg, parts0, parts1,
        h0hi, h0lo, h1hi, h1lo, out, bar);
}

// Round 13
// 25353.888 us; speedup vs baseline: 2.1407x; 1.0131x over previous
//
#include <hip/hip_runtime.h>
#include <math.h>

// Problem dims
#define TSTEPS 512
#define BSZ    64
#define INDIM  256
#define HDIM   1024
#define G4     4096
#define NX     5120   // xg cols: 4096 gate + 1024 proj
#define LN_EPS 1e-5f

#define NBLK   256
#define NTHR   1024
#define CHUNK  8
#define CROWS  (CHUNK * BSZ)
#define NCHUNK (TSTEPS / CHUNK)
#define HRING  16            // h ring slots; acquire fence every 8 steps
#define HSLOT  65536         // u16 per slot (64 x 1024)

// LDS: W1 strip [16 cols][2054] hi then lo (stride == 3 mod 32 dwords: conflict-free)
#define LDS_LDK    2054
#define LDS_LO_OFF (16 * LDS_LDK)
#define LDS_W_BYTES (2 * 16 * LDS_LDK * 2)          // 131,456
#define LDS_STG_OFF LDS_W_BYTES                     // u16 stg_h[2048] = 4 KB
#define LDS_RED_OFF (LDS_W_BYTES + 4096)            // float red[16] (+pad 256B)
#define LDS_GST_OFF (LDS_RED_OFF + 256)             // float stg_g[16][256] = 16 KB
#define LDS_BYTES   (LDS_GST_OFF + 16384)           // 152,192 < 160 KB

typedef short          s8v __attribute__((ext_vector_type(8)));
typedef float          f4v __attribute__((ext_vector_type(4)));
typedef unsigned short u16;

#define MFMA __builtin_amdgcn_mfma_f32_16x16x32_bf16

__device__ __forceinline__ u16 f2bf(float f) {
    unsigned u = __float_as_uint(f);
    u += 0x7FFFu + ((u >> 16) & 1u);
    return (u16)(u >> 16);
}
__device__ __forceinline__ float bf2f(u16 h) {
    return __uint_as_float(((unsigned)h) << 16);
}
__device__ __forceinline__ float sigm(float x) { return 1.f / (1.f + expf(-x)); }

// ---- sc1 (L2-bypass, always-fresh) accessors for read-once mutable data ----
__device__ __forceinline__ float aldf(const float* p) {
    unsigned v = __hip_atomic_load((unsigned*)p, __ATOMIC_RELAXED,
                                   __HIP_MEMORY_SCOPE_AGENT);
    return __uint_as_float(v);
}
// 16B sc1 stores (write-through; drained by barrier's vmcnt(0))
__device__ __forceinline__ void ast16B(u16* p, s8v v) {
    asm volatile("global_store_dwordx4 %0, %1, off sc1"
                 :: "v"(p), "v"(v) : "memory");
}
__device__ __forceinline__ void ast16Bf(float* p, f4v v) {
    asm volatile("global_store_dwordx4 %0, %1, off sc1"
                 :: "v"(p), "v"(v) : "memory");
}

// ---- GEMM C-write: per-wave LDS stage -> one contiguous 16B/lane sc1 store.
// acc[r] of lane (col=lane&15, kg=lane>>4) is C[kg*4+r][col] of a 16x16 tile.
// Stage row-major then each lane stores 16B of one row: 1KB full-line write
// per instr (R12 did 4 scattered 4B sc1 stores -> partial-line traffic).
__device__ __forceinline__ void store_c_16B(float* stgw, int lane, f4v acc,
                                            float* dst, int ld)
{
    const int row = lane & 15, kg = lane >> 4;
#pragma unroll
    for (int r = 0; r < 4; ++r)
        stgw[(kg * 4 + r) * 16 + row] = acc[r];     // 4-way bank alias: cheap
    f4v v = *(f4v*)(stgw + lane * 4);               // compiler inserts lgkmcnt
    ast16Bf(dst + (lane >> 2) * ld + (lane & 3) * 4, v);
}

// ---------------- tree grid barrier ---------------------------------------
// R13: root closer broadcasts all 16 go words directly (removes the
// leader-poll hop: chain = leaf RMW -> root RMW -> go stores -> member poll).
// Arrivals pipeline at the memory-side atomic ALU (R8-proven); polls are
// relaxed loads (non-invalidating); acquire fence only every 8th step.
#define GSTRIDE 512
__device__ __forceinline__ void grid_barrier(int* bar, int nbar, bool fence)
{
    asm volatile("s_waitcnt vmcnt(0)" ::: "memory");
    __syncthreads();
    if (threadIdx.x == 0) {
        const int g = blockIdx.x & 15;
        int* gctr = bar + g * GSTRIDE;
        int* ggo  = gctr + 32;
        int* root = bar + 16 * GSTRIDE;
        int v = __hip_atomic_fetch_add(gctr, 1, __ATOMIC_RELAXED,
                                       __HIP_MEMORY_SCOPE_AGENT);
        if (v == nbar * 16 - 1) {                    // group closer
            int rv = __hip_atomic_fetch_add(root, 1, __ATOMIC_RELAXED,
                                            __HIP_MEMORY_SCOPE_AGENT);
            if (rv == nbar * 16 - 1) {               // last group: broadcast
#pragma unroll
                for (int g2 = 0; g2 < 16; ++g2)
                    __hip_atomic_store(bar + g2 * GSTRIDE + 32, nbar,
                                       __ATOMIC_RELAXED, __HIP_MEMORY_SCOPE_AGENT);
            }
        }
        while (__hip_atomic_load(ggo, __ATOMIC_RELAXED,
                                 __HIP_MEMORY_SCOPE_AGENT) < nbar) {}
        if (fence)
            __builtin_amdgcn_fence(__ATOMIC_ACQUIRE, "agent");  // inv L1/L2
        asm volatile("" ::: "memory");
    }
    __syncthreads();
}

// ---------------- taskA: gates0 h-part. g in [0,2048) ---------------------
__device__ __forceinline__ void taskA(int g, int lane, float* stgw,
    const u16* __restrict__ h0hi_s, const u16* __restrict__ h0lo_s,
    const u16* __restrict__ Whthi, const u16* __restrict__ Whtlo,
    float* __restrict__ parts0)
{
    const int ks = g & 1, tile = g >> 1;
    const int rt = tile & 3, ct = tile >> 2;
    const int row = lane & 15, kg = lane >> 4;
    const int m = rt * 16 + row;
    const u16* wh = Whthi + (size_t)(ct * 16 + row) * HDIM + ks * 512 + kg * 8;
    const u16* wl = Whtlo + (size_t)(ct * 16 + row) * HDIM + ks * 512 + kg * 8;
    const u16* ah = h0hi_s + (size_t)m * HDIM + ks * 512 + kg * 8;
    const u16* al = h0lo_s + (size_t)m * HDIM + ks * 512 + kg * 8;
    f4v acc = {0.f, 0.f, 0.f, 0.f};
    s8v Ah = *(const s8v*)(ah);
    s8v Al = *(const s8v*)(al);
    s8v Bh = *(const s8v*)(wh);
    s8v Bl = *(const s8v*)(wl);
#pragma unroll
    for (int i = 0; i < 16; ++i) {
        s8v nAh, nAl, nBh, nBl;
        if (i + 1 < 16) {
            const int kn = (i + 1) * 32;
            nAh = *(const s8v*)(ah + kn);
            nAl = *(const s8v*)(al + kn);
            nBh = *(const s8v*)(wh + kn);
            nBl = *(const s8v*)(wl + kn);
        }
        acc = MFMA(Ah, Bh, acc, 0, 0, 0);
        acc = MFMA(Ah, Bl, acc, 0, 0, 0);
        acc = MFMA(Al, Bh, acc, 0, 0, 0);
        Ah = nAh; Al = nAl; Bh = nBh; Bl = nBl;
    }
    store_c_16B(stgw, lane, acc,
                parts0 + (size_t)ks * BSZ * G4 + (size_t)(rt * 16) * G4 + ct * 16,
                G4);
}

// ---------------- taskX: xg chunk GEMM, one 16x16 tile, K=256 -------------
__device__ __forceinline__ void taskX(int task, int c, int lane, float* stgw,
    const u16* __restrict__ xhi, const u16* __restrict__ xlo,
    const u16* __restrict__ Wxthi, const u16* __restrict__ Wxtlo,
    float* __restrict__ xgbuf)
{
    const int mt = task & 31, ct = task >> 5;
    const int row = lane & 15, kg = lane >> 4;
    const int mr = mt * 16 + row;
    const u16* ah = xhi + ((size_t)c * CROWS + mr) * INDIM + kg * 8;
    const u16* al = xlo + ((size_t)c * CROWS + mr) * INDIM + kg * 8;
    const u16* wh = Wxthi + (size_t)(ct * 16 + row) * INDIM + kg * 8;
    const u16* wl = Wxtlo + (size_t)(ct * 16 + row) * INDIM + kg * 8;
    f4v acc = {0.f, 0.f, 0.f, 0.f};
    s8v Ah = *(const s8v*)(ah);
    s8v Al = *(const s8v*)(al);
    s8v Bh = *(const s8v*)(wh);
    s8v Bl = *(const s8v*)(wl);
#pragma unroll
    for (int i = 0; i < 8; ++i) {
        s8v nAh, nAl, nBh, nBl;
        if (i + 1 < 8) {
            const int kn = (i + 1) * 32;
            nAh = *(const s8v*)(ah + kn);
            nAl = *(const s8v*)(al + kn);
            nBh = *(const s8v*)(wh + kn);
            nBl = *(const s8v*)(wl + kn);
        }
        acc = MFMA(Ah, Bh, acc, 0, 0, 0);
        acc = MFMA(Ah, Bl, acc, 0, 0, 0);
        acc = MFMA(Al, Bh, acc, 0, 0, 0);
        Ah = nAh; Al = nAl; Bh = nBh; Bl = nBl;
    }
    store_c_16B(stgw, lane, acc,
                xgbuf + (size_t)(mt * 16) * NX + ct * 16, NX);
}

// ---------------- taskC: GEMM1, block owns 16 cols (LDS strip) ------------
__device__ __forceinline__ void taskC(int blk, int wv, int lane, float* stgw,
    const u16* __restrict__ shW,
    const u16* __restrict__ h0hi_s, const u16* __restrict__ h0lo_s,
    const u16* __restrict__ h1hi_s, const u16* __restrict__ h1lo_s,
    float* __restrict__ parts1)
{
    const int rt = wv & 3, hs = wv >> 2;
    const int row = lane & 15, kg = lane >> 4;
    const int m = rt * 16 + row;
    const u16* ah0 = (hs ? h1hi_s : h0hi_s) + (size_t)m * HDIM + kg * 8;
    const u16* al0 = (hs ? h1lo_s : h0lo_s) + (size_t)m * HDIM + kg * 8;
    const u16* sh  = shW + row * LDS_LDK + hs * 1024 + kg * 8;
    const u16* sl  = shW + LDS_LO_OFF + row * LDS_LDK + hs * 1024 + kg * 8;
    f4v acc = {0.f, 0.f, 0.f, 0.f};
    s8v Ah = *(const s8v*)(ah0);
    s8v Al = *(const s8v*)(al0);
#pragma unroll
    for (int i = 0; i < 32; ++i) {
        s8v nAh, nAl;
        if (i + 1 < 32) {
            nAh = *(const s8v*)(ah0 + (i + 1) * 32);
            nAl = *(const s8v*)(al0 + (i + 1) * 32);
        }
        const int kloc = i * 32;
        s8v Bh = *(const s8v*)(sh + kloc);
        s8v Bl = *(const s8v*)(sl + kloc);
        acc = MFMA(Ah, Bh, acc, 0, 0, 0);
        acc = MFMA(Ah, Bl, acc, 0, 0, 0);
        acc = MFMA(Al, Bh, acc, 0, 0, 0);
        Ah = nAh; Al = nAl;
    }
    store_c_16B(stgw, lane, acc,
                parts1 + (size_t)hs * BSZ * G4 + (size_t)(rt * 16) * G4 + blk * 16,
                G4);
}

// ---------------- block reduction + LN helpers ----------------------------
__device__ __forceinline__ float2 blk_sum2(float s, float q, float* red, int tid)
{
#pragma unroll
    for (int off = 32; off; off >>= 1) {
        s += __shfl_down(s, off);
        q += __shfl_down(q, off);
    }
    if ((tid & 63) == 0) { red[(tid >> 6) * 2] = s; red[(tid >> 6) * 2 + 1] = q; }
    __syncthreads();
    float ts = 0.f, tq = 0.f;
#pragma unroll
    for (int i = 0; i < 16; ++i) { ts += red[2 * i]; tq += red[2 * i + 1]; }
    __syncthreads();
    return make_float2(ts, tq);
}

__device__ __forceinline__ float lnorm(float v, float2 sq, float g, float b)
{
    float mean = sq.x * (1.f / 1024.f);
    float var  = sq.y * (1.f / 1024.f) - mean * mean;
    return (v - mean) * rsqrtf(var + LN_EPS) * g + b;
}

// stage h (hi,lo per-thread u16) through LDS -> 16B sc1 stores
__device__ __forceinline__ void store_h_16B(u16* stg, int tid,
                                            u16 hi, u16 lo,
                                            u16* dhi, u16* dlo, int base)
{
    stg[tid] = hi;
    stg[1024 + tid] = lo;
    __syncthreads();
    if (tid < 256) {
        const u16* src = stg + (tid >> 7) * 1024 + (tid & 127) * 8;
        s8v v = *(const s8v*)src;
        u16* dst = ((tid >> 7) == 0 ? dhi : dlo) + base + (tid & 127) * 8;
        ast16B(dst, v);
    }
    __syncthreads();
}

// =====================================================================
__global__ __launch_bounds__(NTHR, 4) void persistent(
    const u16* __restrict__ xhi,  const u16* __restrict__ xlo,
    const u16* __restrict__ Whthi, const u16* __restrict__ Whtlo,
    const u16* __restrict__ Wxthi, const u16* __restrict__ Wxtlo,
    const u16* __restrict__ W1thi, const u16* __restrict__ W1tlo,
    const float* __restrict__ b0, const float* __restrict__ b1,
    const float* __restrict__ lncg, const float* __restrict__ lncb,
    const float* __restrict__ lnhg, const float* __restrict__ lnhb,
    const float* __restrict__ lnog, const float* __restrict__ lnob,
    float* __restrict__ xg,                        // [2][512][5120]  (sc1)
    float* __restrict__ parts0,                    // [2][64][4096]   (sc1)
    float* __restrict__ parts1,                    // [2][64][4096]   (sc1)
    u16* __restrict__ h0hi, u16* __restrict__ h0lo,// [HRING][64][1024]
    u16* __restrict__ h1hi, u16* __restrict__ h1lo,// [HRING][64][1024]
    float* __restrict__ out, int* bar)
{
    extern __shared__ char smem[];
    u16*   shW   = (u16*)smem;
    u16*   stg   = (u16*)(smem + LDS_STG_OFF);
    float* red   = (float*)(smem + LDS_RED_OFF);
    float* stg_g = (float*)(smem + LDS_GST_OFF);

    const int blk  = blockIdx.x;
    const int tid  = threadIdx.x;
    const int wv   = tid >> 6;
    const int lane = tid & 63;
    float* stgw = stg_g + wv * 256;
    int nbar = 0;

    // recurrent per-thread state:
    //   blocks 0..63: c0,h0 of batch row blk; blocks 64..127: c1,h1 of row blk-64
    float c0reg = 0.f, h0reg = 0.f, c1reg = 0.f, h1reg = 0.f;

    // ---- prologue: LDS W1 strip (cols blk*16..+16, K=2048) ----
    {
        const size_t gcol = (size_t)(blk * 16 + wv) * 2048;
        for (int j = lane * 8; j < 2048; j += 512) {
            *(s8v*)(shW + wv * LDS_LDK + j)              = *(const s8v*)(W1thi + gcol + j);
            *(s8v*)(shW + LDS_LO_OFF + wv * LDS_LDK + j) = *(const s8v*)(W1tlo + gcol + j);
        }
    }
    grid_barrier(bar, ++nbar, false);

    // ---- prologue: xg chunk 0 (all blocks; 10240 tasks / 4096 waves) ----
    {
        const int g = blk * 16 + wv;
        for (int task = g; task < 10240; task += 4096)
            taskX(task, 0, lane, stgw, xhi, xlo, Wxthi, Wxtlo, xg);
    }
    grid_barrier(bar, ++nbar, false);
    // parts0 zeroed host-side (h0(-1)=0); h rings zeroed host-side.

    for (int t = 0; t < TSTEPS; ++t) {
        const int s0  = t & (HRING - 1);            // h0(t) slot
        const int s0p = (t - 1) & (HRING - 1);      // h0(t-1) slot
        const int s1p = (t - 1) & (HRING - 1);      // h1(t-1) slot
        const bool fence = ((t & 7) == 7);

        // ================= phase 1: cells + spread xg prefetch ============
        if (blk < 64) {
            // ---- cell0(t): row b = blk ----
            const int b = blk, n = tid;
            const float* XG = xg + (size_t)((t >> 3) & 1) * CROWS * NX
                                 + (size_t)((t & 7) * BSZ + b) * NX;
            const float* P0 = parts0 + (size_t)b * G4;
            const float* P1 = parts0 + (size_t)(BSZ + b) * G4;
            float gi = aldf(&XG[n])        + aldf(&P0[n])        + aldf(&P1[n])        + b0[n];
            float gf = aldf(&XG[1024 + n]) + aldf(&P0[1024 + n]) + aldf(&P1[1024 + n]) + b0[1024 + n];
            float gg = aldf(&XG[2048 + n]) + aldf(&P0[2048 + n]) + aldf(&P1[2048 + n]) + b0[2048 + n];
            float go = aldf(&XG[3072 + n]) + aldf(&P0[3072 + n]) + aldf(&P1[3072 + n]) + b0[3072 + n];
            float xp = aldf(&XG[4096 + n]);
            float cv = sigm(gf) * c0reg + expf(gi) * tanhf(gg);
            float2 r = blk_sum2(cv, cv * cv, red, tid);
            float cl = lnorm(cv, r, lncg[n], lncb[n]);
            c0reg = cl;
            float hv = sigm(go) * tanhf(cl);
            r = blk_sum2(hv, hv * hv, red, tid);
            float hl = lnorm(hv, r, lnhg[n], lnhb[n]) + xp;
            r = blk_sum2(hl, hl * hl, red, tid);
            float hn = lnorm(hl, r, lnog[n], lnob[n]);
            h0reg = hn;
            u16 hi = f2bf(hn);
            store_h_16B(stg, tid, hi, f2bf(hn - bf2f(hi)),
                        h0hi + (size_t)s0 * HSLOT, h0lo + (size_t)s0 * HSLOT,
                        b * HDIM);
        } else if (blk < 128) {
            if (t > 0) {
                // ---- cell1(t-1): row b = blk-64 ----
                const int b = blk - 64, n = tid;
                const float* P0 = parts1 + (size_t)b * G4;
                const float* P1 = parts1 + (size_t)(BSZ + b) * G4;
                float gi = aldf(&P0[n])        + aldf(&P1[n])        + b1[n];
                float gf = aldf(&P0[1024 + n]) + aldf(&P1[1024 + n]) + b1[1024 + n];
                float gg = aldf(&P0[2048 + n]) + aldf(&P1[2048 + n]) + b1[2048 + n];
                float go = aldf(&P0[3072 + n]) + aldf(&P1[3072 + n]) + b1[3072 + n];
                float cv = sigm(gf) * c1reg + expf(gi) * tanhf(gg);
                float2 r = blk_sum2(cv, cv * cv, red, tid);
                float cl = lnorm(cv, r, lncg[HDIM + n], lncb[HDIM + n]);
                c1reg = cl;
                float hv = sigm(go) * tanhf(cl);
                r = blk_sum2(hv, hv * hv, red, tid);
                // residual h0(t-1): cached ring read (hi+lo ~ fp32)
                float h0v = bf2f(h0hi[(size_t)s0p * HSLOT + b * HDIM + n])
                          + bf2f(h0lo[(size_t)s0p * HSLOT + b * HDIM + n]);
                float hl = lnorm(hv, r, lnhg[HDIM + n], lnhb[HDIM + n]) + h0v;
                r = blk_sum2(hl, hl * hl, red, tid);
                float hn = lnorm(hl, r, lnog[HDIM + n], lnob[HDIM + n]);
                h1reg = hn;
                u16 hi = f2bf(hn);
                out[(size_t)(t - 1) * BSZ * HDIM + b * HDIM + n] = hn;
                store_h_16B(stg, tid, hi, f2bf(hn - bf2f(hi)),
                            h1hi + (size_t)s1p * HSLOT, h1lo + (size_t)s1p * HSLOT,
                            b * HDIM);
            }
        } else {
            // ---- spread xg prefetch: chunk (t>>3)+1, 1280 tasks/step over
            // 2048 idle waves (R12 ran all 10240 on one step: 5-task pole) ----
            const int c = (t >> 3) + 1;
            if (c < NCHUNK) {
                float* xgbuf = xg + (size_t)(c & 1) * CROWS * NX;
                const int widx = (blk - 128) * 16 + wv;        // 0..2047
                if (widx < 1280)
                    taskX((t & 7) * 1280 + widx, c, lane, stgw,
                          xhi, xlo, Wxthi, Wxtlo, xgbuf);
            }
        }
        grid_barrier(bar, ++nbar, false);

        // ================= phase 2: GEMMs (all blocks) ====================
        // wv 0-7: taskC(t) reads h0(t) slot s0, h1(t-1) slot s1p
        // wv 8-15: taskA(t+1) reads h0(t) slot s0
        if (wv < 8) {
            taskC(blk, wv, lane, stgw, shW,
                  h0hi + (size_t)s0 * HSLOT,  h0lo + (size_t)s0 * HSLOT,
                  h1hi + (size_t)s1p * HSLOT, h1lo + (size_t)s1p * HSLOT,
                  parts1);
        } else if (t + 1 < TSTEPS) {
            taskA(blk * 8 + (wv - 8), lane, stgw,
                  h0hi + (size_t)s0 * HSLOT, h0lo + (size_t)s0 * HSLOT,
                  Whthi, Whtlo, parts0);
        }
        grid_barrier(bar, ++nbar, fence);
    }

    // ---- epilogue: cell1(511) ----
    if (blk >= 64 && blk < 128) {
        const int b = blk - 64, n = tid;
        const int tp = TSTEPS - 1;
        const int sp = tp & (HRING - 1);
        const float* P0 = parts1 + (size_t)b * G4;
        const float* P1 = parts1 + (size_t)(BSZ + b) * G4;
        float gi = aldf(&P0[n])        + aldf(&P1[n])        + b1[n];
        float gf = aldf(&P0[1024 + n]) + aldf(&P1[1024 + n]) + b1[1024 + n];
        float gg = aldf(&P0[2048 + n]) + aldf(&P1[2048 + n]) + b1[2048 + n];
        float go = aldf(&P0[3072 + n]) + aldf(&P1[3072 + n]) + b1[3072 + n];
        float cv = sigm(gf) * c1reg + expf(gi) * tanhf(gg);
        float2 r = blk_sum2(cv, cv * cv, red, tid);
        float cl = lnorm(cv, r, lncg[HDIM + n], lncb[HDIM + n]);
        c1reg = cl;
        float hv = sigm(go) * tanhf(cl);
        r = blk_sum2(hv, hv * hv, red, tid);
        float h0v = bf2f(h0hi[(size_t)sp * HSLOT + b * HDIM + n])
                  + bf2f(h0lo[(size_t)sp * HSLOT + b * HDIM + n]);
        float hl = lnorm(hv, r, lnhg[HDIM + n], lnhb[HDIM + n]) + h0v;
        r = blk_sum2(hl, hl * hl, red, tid);
        float hn = lnorm(hl, r, lnog[HDIM + n], lnob[HDIM + n]);
        h1reg = hn;
        out[(size_t)tp * BSZ * HDIM + b * HDIM + n] = hn;
    }

    // ---- final states: h0, h1, c0, c1 ----
    {
        const size_t F = (size_t)TSTEPS * BSZ * HDIM;
        if (blk < 64) {
            out[F +          blk * HDIM + tid] = h0reg;
            out[F + 131072 + blk * HDIM + tid] = c0reg;
        } else if (blk < 128) {
            const int b = blk - 64;
            out[F +  65536 + b * HDIM + tid] = h1reg;
            out[F + 196608 + b * HDIM + tid] = c1reg;
        }
    }
}

// =====================================================================
// prep kernels
// =====================================================================
__global__ __launch_bounds__(256) void transpose_split(
    const float* __restrict__ src, int N,
    u16* __restrict__ dsthi, u16* __restrict__ dstlo,
    int ldd, int noff, int koff)
{
    __shared__ float tile[32][33];
    const int n0 = blockIdx.x * 32, k0 = blockIdx.y * 32;
    const int tx = threadIdx.x & 31, ty = threadIdx.x >> 5;
#pragma unroll
    for (int i = 0; i < 4; ++i)
        tile[ty + i * 8][tx] = src[(size_t)(k0 + ty + i * 8) * N + n0 + tx];
    __syncthreads();
#pragma unroll
    for (int i = 0; i < 4; ++i) {
        float v = tile[tx][ty + i * 8];
        u16 hi = f2bf(v);
        u16 lo = f2bf(v - bf2f(hi));
        size_t idx = (size_t)(n0 + ty + i * 8 + noff) * ldd + k0 + koff + tx;
        dsthi[idx] = hi;
        dstlo[idx] = lo;
    }
}

__global__ void conv_split(const float* __restrict__ src,
                           u16* __restrict__ hi, u16* __restrict__ lo, int n4)
{
    int i = blockIdx.x * 256 + threadIdx.x;
    if (i < n4) {
        float4 v = ((const float4*)src)[i];
        ushort4 h, l;
        h.x = f2bf(v.x); l.x = f2bf(v.x - bf2f(h.x));
        h.y = f2bf(v.y); l.y = f2bf(v.y - bf2f(h.y));
        h.z = f2bf(v.z); l.z = f2bf(v.z - bf2f(h.z));
        h.w = f2bf(v.w); l.w = f2bf(v.w - bf2f(h.w));
        ((ushort4*)hi)[i] = h;
        ((ushort4*)lo)[i] = l;
    }
}

// =====================================================================
extern "C" void kernel_launch(void* const* d_in, const int* in_sizes, int n_in,
                              void* d_out, int out_size, void* d_ws, size_t ws_size,
                              hipStream_t stream)
{
    const float* x     = (const float*)d_in[0];
    const float* Wproj = (const float*)d_in[1];
    const float* Wx0   = (const float*)d_in[2];
    const float* Wh0   = (const float*)d_in[3];
    const float* b0    = (const float*)d_in[4];
    const float* Wx1   = (const float*)d_in[5];
    const float* Wh1   = (const float*)d_in[6];
    const float* b1    = (const float*)d_in[7];
    const float* lnc_g = (const float*)d_in[8];
    const float* lnc_b = (const float*)d_in[9];
    const float* lnh_g = (const float*)d_in[10];
    const float* lnh_b = (const float*)d_in[11];
    const float* lno_g = (const float*)d_in[12];
    const float* lno_b = (const float*)d_in[13];
    float* out = (float*)d_out;

    // ---- ws layout (~122 MB) ----
    char* base = (char*)d_ws;
    size_t o = 0;
    u16* x_hi  = (u16*)(base + o); o += (size_t)TSTEPS * BSZ * INDIM * 2;
    u16* x_lo  = (u16*)(base + o); o += (size_t)TSTEPS * BSZ * INDIM * 2;
    u16* Whthi = (u16*)(base + o); o += (size_t)G4 * HDIM * 2;
    u16* Whtlo = (u16*)(base + o); o += (size_t)G4 * HDIM * 2;
    u16* Wxthi = (u16*)(base + o); o += (size_t)NX * INDIM * 2;
    u16* Wxtlo = (u16*)(base + o); o += (size_t)NX * INDIM * 2;
    u16* W1thi = (u16*)(base + o); o += (size_t)G4 * 2048 * 2;
    u16* W1tlo = (u16*)(base + o); o += (size_t)G4 * 2048 * 2;
    float* xg     = (float*)(base + o); o += (size_t)2 * CROWS * NX * 4;
    float* parts0 = (float*)(base + o); o += (size_t)2 * BSZ * G4 * 4;
    float* parts1 = (float*)(base + o); o += (size_t)2 * BSZ * G4 * 4;
    u16* h0hi = (u16*)(base + o); o += (size_t)HRING * HSLOT * 2;
    u16* h0lo = (u16*)(base + o); o += (size_t)HRING * HSLOT * 2;
    u16* h1hi = (u16*)(base + o); o += (size_t)HRING * HSLOT * 2;
    u16* h1lo = (u16*)(base + o); o += (size_t)HRING * HSLOT * 2;
    int* bar  = (int*)(base + o); o += 40960;
    if (ws_size < o) return;   // fail loudly (poisoned out) if ws too small

    // ---- prep ----
    conv_split<<<dim3(8192), 256, 0, stream>>>(x, x_hi, x_lo, 2097152);
    transpose_split<<<dim3(128, 32), 256, 0, stream>>>(Wh0, G4, Whthi, Whtlo, HDIM, 0, 0);
    transpose_split<<<dim3(128, 8),  256, 0, stream>>>(Wx0,   G4,   Wxthi, Wxtlo, INDIM, 0,    0);
    transpose_split<<<dim3(32, 8),   256, 0, stream>>>(Wproj, HDIM, Wxthi, Wxtlo, INDIM, 4096, 0);
    transpose_split<<<dim3(128, 32), 256, 0, stream>>>(Wx1, G4, W1thi, W1tlo, 2048, 0, 0);
    transpose_split<<<dim3(128, 32), 256, 0, stream>>>(Wh1, G4, W1thi, W1tlo, 2048, 0, 1024);
    // zero: parts0 (h0(-1)=0), h rings (first reads must be 0), barrier block
    hipMemsetAsync(parts0, 0, (size_t)2 * BSZ * G4 * 4, stream);
    hipMemsetAsync(h0hi, 0, (size_t)4 * HRING * HSLOT * 2, stream);  // contiguous
    hipMemsetAsync(bar, 0, 40960, stream);

    // ---- the whole recurrence: one persistent kernel ----
    persistent<<<dim3(NBLK), dim3(NTHR), LDS_BYTES, stream>>>(
        x_hi, x_lo, Whthi, Whtlo, Wxthi, Wxtlo, W1thi, W1tlo, b0, b1,
        lnc_g, lnc_b, lnh_g, lnh_b, lno_g, lno_b,
        xg, parts0, parts1,
        h0hi, h0lo, h1hi, h1lo, out, bar);
}

// Round 14
// 24336.292 us; speedup vs baseline: 2.2302x; 1.0418x over previous
//
#include <hip/hip_runtime.h>
#include <math.h>

// Problem dims
#define TSTEPS 512
#define BSZ    64
#define INDIM  256
#define HDIM   1024
#define G4     4096
#define NX     5120   // xg cols: 4096 gate + 1024 proj
#define LN_EPS 1e-5f

#define NBLK   256
#define NTHR   1024
#define CHUNK  8
#define CROWS  (CHUNK * BSZ)
#define NCHUNK (TSTEPS / CHUNK)
#define HRING  16            // h ring slots; acquire fence every 16 steps
#define HSLOT  65536         // u16 per slot (64 x 1024)

// LDS: W1 strip [16 cols][2054] hi then lo (stride == 3 mod 32 dwords: conflict-free)
#define LDS_LDK    2054
#define LDS_LO_OFF (16 * LDS_LDK)
#define LDS_W_BYTES (2 * 16 * LDS_LDK * 2)          // 131,456
#define LDS_STG_OFF LDS_W_BYTES                     // u16 stg_h[2048] = 4 KB
#define LDS_RED_OFF (LDS_W_BYTES + 4096)            // float red[16] (+pad 256B)
#define LDS_GST_OFF (LDS_RED_OFF + 256)             // float stg_g[16][256] = 16 KB
#define LDS_BYTES   (LDS_GST_OFF + 16384)           // 152,192 < 160 KB

typedef short          s8v __attribute__((ext_vector_type(8)));
typedef float          f4v __attribute__((ext_vector_type(4)));
typedef unsigned short u16;

#define MFMA __builtin_amdgcn_mfma_f32_16x16x32_bf16

__device__ __forceinline__ u16 f2bf(float f) {
    unsigned u = __float_as_uint(f);
    u += 0x7FFFu + ((u >> 16) & 1u);
    return (u16)(u >> 16);
}
__device__ __forceinline__ float bf2f(u16 h) {
    return __uint_as_float(((unsigned)h) << 16);
}
__device__ __forceinline__ float sigm(float x) { return 1.f / (1.f + expf(-x)); }

// ---- sc1 (L2-bypass, always-fresh) accessors for read-once mutable data ----
__device__ __forceinline__ float aldf(const float* p) {
    unsigned v = __hip_atomic_load((unsigned*)p, __ATOMIC_RELAXED,
                                   __HIP_MEMORY_SCOPE_AGENT);
    return __uint_as_float(v);
}
// 16B sc1 stores (write-through; drained by barrier's vmcnt(0))
__device__ __forceinline__ void ast16B(u16* p, s8v v) {
    asm volatile("global_store_dwordx4 %0, %1, off sc1"
                 :: "v"(p), "v"(v) : "memory");
}
__device__ __forceinline__ void ast16Bf(float* p, f4v v) {
    asm volatile("global_store_dwordx4 %0, %1, off sc1"
                 :: "v"(p), "v"(v) : "memory");
}

// ---- GEMM C-write: per-wave LDS stage -> one contiguous 16B/lane sc1 store.
__device__ __forceinline__ void store_c_16B(float* stgw, int lane, f4v acc,
                                            float* dst, int ld)
{
    const int row = lane & 15, kg = lane >> 4;
#pragma unroll
    for (int r = 0; r < 4; ++r)
        stgw[(kg * 4 + r) * 16 + row] = acc[r];
    f4v v = *(f4v*)(stgw + lane * 4);
    ast16Bf(dst + (lane >> 2) * ld + (lane & 3) * 4, v);
}

// ---------------- tree grid barrier ---------------------------------------
// Tree arrivals (16 groups x 16, 2KB-strided lines), root closer broadcasts
// go words, busy-spin relaxed load polls. Acquire fence every 16th step only
// (R14: ring-16 staleness window spans exactly one fence; weight refetch
// halves vs fence-8).
#define GSTRIDE 512
__device__ __forceinline__ void grid_barrier(int* bar, int nbar, bool fence)
{
    asm volatile("s_waitcnt vmcnt(0)" ::: "memory");
    __syncthreads();
    if (threadIdx.x == 0) {
        const int g = blockIdx.x & 15;
        int* gctr = bar + g * GSTRIDE;
        int* ggo  = gctr + 32;
        int* root = bar + 16 * GSTRIDE;
        int v = __hip_atomic_fetch_add(gctr, 1, __ATOMIC_RELAXED,
                                       __HIP_MEMORY_SCOPE_AGENT);
        if (v == nbar * 16 - 1) {
            int rv = __hip_atomic_fetch_add(root, 1, __ATOMIC_RELAXED,
                                            __HIP_MEMORY_SCOPE_AGENT);
            if (rv == nbar * 16 - 1) {
#pragma unroll
                for (int g2 = 0; g2 < 16; ++g2)
                    __hip_atomic_store(bar + g2 * GSTRIDE + 32, nbar,
                                       __ATOMIC_RELAXED, __HIP_MEMORY_SCOPE_AGENT);
            }
        }
        while (__hip_atomic_load(ggo, __ATOMIC_RELAXED,
                                 __HIP_MEMORY_SCOPE_AGENT) < nbar) {}
        if (fence)
            __builtin_amdgcn_fence(__ATOMIC_ACQUIRE, "agent");  // inv L1/L2
        asm volatile("" ::: "memory");
    }
    __syncthreads();
}

// ---------------- taskA: gates0 h-part, K=1024 merged (R14) ---------------
// Block blk owns col-tile ct=blk (cols blk*16..+16); rt in 0..3 per wave.
__device__ __forceinline__ void taskA(int blk, int rt, int lane, float* stgw,
    const u16* __restrict__ h0hi_s, const u16* __restrict__ h0lo_s,
    const u16* __restrict__ Whthi, const u16* __restrict__ Whtlo,
    float* __restrict__ parts0)
{
    const int row = lane & 15, kg = lane >> 4;
    const int m = rt * 16 + row;
    const u16* wh = Whthi + (size_t)(blk * 16 + row) * HDIM + kg * 8;
    const u16* wl = Whtlo + (size_t)(blk * 16 + row) * HDIM + kg * 8;
    const u16* ah = h0hi_s + (size_t)m * HDIM + kg * 8;
    const u16* al = h0lo_s + (size_t)m * HDIM + kg * 8;
    f4v acc = {0.f, 0.f, 0.f, 0.f};
    s8v Ah = *(const s8v*)(ah);
    s8v Al = *(const s8v*)(al);
    s8v Bh = *(const s8v*)(wh);
    s8v Bl = *(const s8v*)(wl);
#pragma unroll
    for (int i = 0; i < 32; ++i) {
        s8v nAh, nAl, nBh, nBl;
        if (i + 1 < 32) {
            const int kn = (i + 1) * 32;
            nAh = *(const s8v*)(ah + kn);
            nAl = *(const s8v*)(al + kn);
            nBh = *(const s8v*)(wh + kn);
            nBl = *(const s8v*)(wl + kn);
        }
        acc = MFMA(Ah, Bh, acc, 0, 0, 0);
        acc = MFMA(Ah, Bl, acc, 0, 0, 0);
        acc = MFMA(Al, Bh, acc, 0, 0, 0);
        Ah = nAh; Al = nAl; Bh = nBh; Bl = nBl;
    }
    store_c_16B(stgw, lane, acc,
                parts0 + (size_t)(rt * 16) * G4 + blk * 16, G4);
}

// ---------------- taskX: xg chunk GEMM, one 16x16 tile, K=256 -------------
__device__ __forceinline__ void taskX(int task, int c, int lane, float* stgw,
    const u16* __restrict__ xhi, const u16* __restrict__ xlo,
    const u16* __restrict__ Wxthi, const u16* __restrict__ Wxtlo,
    float* __restrict__ xgbuf)
{
    const int mt = task & 31, ct = task >> 5;
    const int row = lane & 15, kg = lane >> 4;
    const int mr = mt * 16 + row;
    const u16* ah = xhi + ((size_t)c * CROWS + mr) * INDIM + kg * 8;
    const u16* al = xlo + ((size_t)c * CROWS + mr) * INDIM + kg * 8;
    const u16* wh = Wxthi + (size_t)(ct * 16 + row) * INDIM + kg * 8;
    const u16* wl = Wxtlo + (size_t)(ct * 16 + row) * INDIM + kg * 8;
    f4v acc = {0.f, 0.f, 0.f, 0.f};
    s8v Ah = *(const s8v*)(ah);
    s8v Al = *(const s8v*)(al);
    s8v Bh = *(const s8v*)(wh);
    s8v Bl = *(const s8v*)(wl);
#pragma unroll
    for (int i = 0; i < 8; ++i) {
        s8v nAh, nAl, nBh, nBl;
        if (i + 1 < 8) {
            const int kn = (i + 1) * 32;
            nAh = *(const s8v*)(ah + kn);
            nAl = *(const s8v*)(al + kn);
            nBh = *(const s8v*)(wh + kn);
            nBl = *(const s8v*)(wl + kn);
        }
        acc = MFMA(Ah, Bh, acc, 0, 0, 0);
        acc = MFMA(Ah, Bl, acc, 0, 0, 0);
        acc = MFMA(Al, Bh, acc, 0, 0, 0);
        Ah = nAh; Al = nAl; Bh = nBh; Bl = nBl;
    }
    store_c_16B(stgw, lane, acc,
                xgbuf + (size_t)(mt * 16) * NX + ct * 16, NX);
}

// ---------------- taskC: GEMM1 K=2048 merged (R14); rt = wave 0..3 --------
__device__ __forceinline__ void taskC(int blk, int rt, int lane, float* stgw,
    const u16* __restrict__ shW,
    const u16* __restrict__ h0hi_s, const u16* __restrict__ h0lo_s,
    const u16* __restrict__ h1hi_s, const u16* __restrict__ h1lo_s,
    float* __restrict__ parts1)
{
    const int row = lane & 15, kg = lane >> 4;
    const int m = rt * 16 + row;
    f4v acc = {0.f, 0.f, 0.f, 0.f};
#pragma unroll
    for (int hs = 0; hs < 2; ++hs) {
        const u16* ah0 = (hs ? h1hi_s : h0hi_s) + (size_t)m * HDIM + kg * 8;
        const u16* al0 = (hs ? h1lo_s : h0lo_s) + (size_t)m * HDIM + kg * 8;
        const u16* sh  = shW + row * LDS_LDK + hs * 1024 + kg * 8;
        const u16* sl  = shW + LDS_LO_OFF + row * LDS_LDK + hs * 1024 + kg * 8;
        s8v Ah = *(const s8v*)(ah0);
        s8v Al = *(const s8v*)(al0);
#pragma unroll
        for (int i = 0; i < 32; ++i) {
            s8v nAh, nAl;
            if (i + 1 < 32) {
                nAh = *(const s8v*)(ah0 + (i + 1) * 32);
                nAl = *(const s8v*)(al0 + (i + 1) * 32);
            }
            const int kloc = i * 32;
            s8v Bh = *(const s8v*)(sh + kloc);
            s8v Bl = *(const s8v*)(sl + kloc);
            acc = MFMA(Ah, Bh, acc, 0, 0, 0);
            acc = MFMA(Ah, Bl, acc, 0, 0, 0);
            acc = MFMA(Al, Bh, acc, 0, 0, 0);
            Ah = nAh; Al = nAl;
        }
    }
    store_c_16B(stgw, lane, acc,
                parts1 + (size_t)(rt * 16) * G4 + blk * 16, G4);
}

// ---------------- block reduction + LN helpers ----------------------------
__device__ __forceinline__ float2 blk_sum2(float s, float q, float* red, int tid)
{
#pragma unroll
    for (int off = 32; off; off >>= 1) {
        s += __shfl_down(s, off);
        q += __shfl_down(q, off);
    }
    if ((tid & 63) == 0) { red[(tid >> 6) * 2] = s; red[(tid >> 6) * 2 + 1] = q; }
    __syncthreads();
    float ts = 0.f, tq = 0.f;
#pragma unroll
    for (int i = 0; i < 16; ++i) { ts += red[2 * i]; tq += red[2 * i + 1]; }
    __syncthreads();
    return make_float2(ts, tq);
}

__device__ __forceinline__ float lnorm(float v, float2 sq, float g, float b)
{
    float mean = sq.x * (1.f / 1024.f);
    float var  = sq.y * (1.f / 1024.f) - mean * mean;
    return (v - mean) * rsqrtf(var + LN_EPS) * g + b;
}

// stage h (hi,lo per-thread u16) through LDS -> 16B sc1 stores
__device__ __forceinline__ void store_h_16B(u16* stg, int tid,
                                            u16 hi, u16 lo,
                                            u16* dhi, u16* dlo, int base)
{
    stg[tid] = hi;
    stg[1024 + tid] = lo;
    __syncthreads();
    if (tid < 256) {
        const u16* src = stg + (tid >> 7) * 1024 + (tid & 127) * 8;
        s8v v = *(const s8v*)src;
        u16* dst = ((tid >> 7) == 0 ? dhi : dlo) + base + (tid & 127) * 8;
        ast16B(dst, v);
    }
    __syncthreads();
}

// =====================================================================
__global__ __launch_bounds__(NTHR, 4) void persistent(
    const u16* __restrict__ xhi,  const u16* __restrict__ xlo,
    const u16* __restrict__ Whthi, const u16* __restrict__ Whtlo,
    const u16* __restrict__ Wxthi, const u16* __restrict__ Wxtlo,
    const u16* __restrict__ W1thi, const u16* __restrict__ W1tlo,
    const float* __restrict__ b0, const float* __restrict__ b1,
    const float* __restrict__ lncg, const float* __restrict__ lncb,
    const float* __restrict__ lnhg, const float* __restrict__ lnhb,
    const float* __restrict__ lnog, const float* __restrict__ lnob,
    float* __restrict__ xg,                        // [2][512][5120]  (sc1)
    float* __restrict__ parts0,                    // [64][4096]      (sc1)
    float* __restrict__ parts1,                    // [64][4096]      (sc1)
    u16* __restrict__ h0hi, u16* __restrict__ h0lo,// [HRING][64][1024]
    u16* __restrict__ h1hi, u16* __restrict__ h1lo,// [HRING][64][1024]
    float* __restrict__ out, int* bar)
{
    extern __shared__ char smem[];
    u16*   shW   = (u16*)smem;
    u16*   stg   = (u16*)(smem + LDS_STG_OFF);
    float* red   = (float*)(smem + LDS_RED_OFF);
    float* stg_g = (float*)(smem + LDS_GST_OFF);

    const int blk  = blockIdx.x;
    const int tid  = threadIdx.x;
    const int wv   = tid >> 6;
    const int lane = tid & 63;
    float* stgw = stg_g + wv * 256;
    int nbar = 0;

    // recurrent per-thread state:
    //   blocks 0..63: c0,h0 of batch row blk; blocks 64..127: c1,h1 of row blk-64
    float c0reg = 0.f, h0reg = 0.f, c1reg = 0.f, h1reg = 0.f;

    // ---- prologue: LDS W1 strip (cols blk*16..+16, K=2048) ----
    {
        const size_t gcol = (size_t)(blk * 16 + wv) * 2048;
        for (int j = lane * 8; j < 2048; j += 512) {
            *(s8v*)(shW + wv * LDS_LDK + j)              = *(const s8v*)(W1thi + gcol + j);
            *(s8v*)(shW + LDS_LO_OFF + wv * LDS_LDK + j) = *(const s8v*)(W1tlo + gcol + j);
        }
    }
    grid_barrier(bar, ++nbar, false);

    // ---- prologue: xg chunk 0 (all blocks; 10240 tasks / 4096 waves) ----
    {
        const int g = blk * 16 + wv;
        for (int task = g; task < 10240; task += 4096)
            taskX(task, 0, lane, stgw, xhi, xlo, Wxthi, Wxtlo, xg);
    }
    grid_barrier(bar, ++nbar, false);
    // parts0 zeroed host-side (h0(-1)=0); h rings zeroed host-side.

    for (int t = 0; t < TSTEPS; ++t) {
        const int s0  = t & (HRING - 1);            // h0(t) slot
        const int s0p = (t - 1) & (HRING - 1);      // h0(t-1) / h1(t-1) slot
        const bool fence = ((t & 15) == 15);

        // ================= phase 1: cells =================
        if (blk < 64) {
            // ---- cell0(t): row b = blk ----
            const int b = blk, n = tid;
            const float* XG = xg + (size_t)((t >> 3) & 1) * CROWS * NX
                                 + (size_t)((t & 7) * BSZ + b) * NX;
            const float* P0 = parts0 + (size_t)b * G4;
            float gi = aldf(&XG[n])        + aldf(&P0[n])        + b0[n];
            float gf = aldf(&XG[1024 + n]) + aldf(&P0[1024 + n]) + b0[1024 + n];
            float gg = aldf(&XG[2048 + n]) + aldf(&P0[2048 + n]) + b0[2048 + n];
            float go = aldf(&XG[3072 + n]) + aldf(&P0[3072 + n]) + b0[3072 + n];
            float xp = aldf(&XG[4096 + n]);
            float cv = sigm(gf) * c0reg + expf(gi) * tanhf(gg);
            float2 r = blk_sum2(cv, cv * cv, red, tid);
            float cl = lnorm(cv, r, lncg[n], lncb[n]);
            c0reg = cl;
            float hv = sigm(go) * tanhf(cl);
            r = blk_sum2(hv, hv * hv, red, tid);
            float hl = lnorm(hv, r, lnhg[n], lnhb[n]) + xp;
            r = blk_sum2(hl, hl * hl, red, tid);
            float hn = lnorm(hl, r, lnog[n], lnob[n]);
            h0reg = hn;
            u16 hi = f2bf(hn);
            store_h_16B(stg, tid, hi, f2bf(hn - bf2f(hi)),
                        h0hi + (size_t)s0 * HSLOT, h0lo + (size_t)s0 * HSLOT,
                        b * HDIM);
        } else if (blk < 128 && t > 0) {
            // ---- cell1(t-1): row b = blk-64 ----
            const int b = blk - 64, n = tid;
            const float* P0 = parts1 + (size_t)b * G4;
            float gi = aldf(&P0[n])        + b1[n];
            float gf = aldf(&P0[1024 + n]) + b1[1024 + n];
            float gg = aldf(&P0[2048 + n]) + b1[2048 + n];
            float go = aldf(&P0[3072 + n]) + b1[3072 + n];
            float cv = sigm(gf) * c1reg + expf(gi) * tanhf(gg);
            float2 r = blk_sum2(cv, cv * cv, red, tid);
            float cl = lnorm(cv, r, lncg[HDIM + n], lncb[HDIM + n]);
            c1reg = cl;
            float hv = sigm(go) * tanhf(cl);
            r = blk_sum2(hv, hv * hv, red, tid);
            // residual h0(t-1): cached ring read (L2-hot: filled fresh at t-1)
            float h0v = bf2f(h0hi[(size_t)s0p * HSLOT + b * HDIM + n])
                      + bf2f(h0lo[(size_t)s0p * HSLOT + b * HDIM + n]);
            float hl = lnorm(hv, r, lnhg[HDIM + n], lnhb[HDIM + n]) + h0v;
            r = blk_sum2(hl, hl * hl, red, tid);
            float hn = lnorm(hl, r, lnog[HDIM + n], lnob[HDIM + n]);
            h1reg = hn;
            u16 hi = f2bf(hn);
            __builtin_nontemporal_store(hn, &out[(size_t)(t - 1) * BSZ * HDIM + b * HDIM + n]);
            store_h_16B(stg, tid, hi, f2bf(hn - bf2f(hi)),
                        h1hi + (size_t)s0p * HSLOT, h1lo + (size_t)s0p * HSLOT,
                        b * HDIM);
        }
        grid_barrier(bar, ++nbar, false);

        // ================= phase 2: GEMMs (all blocks) ====================
        // wv 0-3: taskC(t)  [h0(t) slot s0, h1(t-1) slot s0p] -> parts1
        // wv 4-7: taskA(t+1)[h0(t) slot s0]                   -> parts0
        // wv 8-15: spread taskX for chunk (t>>3)+1 (1280 tasks/step)
        if (wv < 4) {
            taskC(blk, wv, lane, stgw, shW,
                  h0hi + (size_t)s0 * HSLOT,  h0lo + (size_t)s0 * HSLOT,
                  h1hi + (size_t)s0p * HSLOT, h1lo + (size_t)s0p * HSLOT,
                  parts1);
        } else if (wv < 8) {
            if (t + 1 < TSTEPS)
                taskA(blk, wv - 4, lane, stgw,
                      h0hi + (size_t)s0 * HSLOT, h0lo + (size_t)s0 * HSLOT,
                      Whthi, Whtlo, parts0);
        } else {
            const int c = (t >> 3) + 1;
            if (c < NCHUNK) {
                float* xgbuf = xg + (size_t)(c & 1) * CROWS * NX;
                const int widx = blk * 8 + (wv - 8);        // 0..2047
                if (widx < 1280)
                    taskX((t & 7) * 1280 + widx, c, lane, stgw,
                          xhi, xlo, Wxthi, Wxtlo, xgbuf);
            }
        }
        grid_barrier(bar, ++nbar, fence);
    }

    // ---- epilogue: cell1(511) ----
    if (blk >= 64 && blk < 128) {
        const int b = blk - 64, n = tid;
        const int tp = TSTEPS - 1;
        const int sp = tp & (HRING - 1);
        const float* P0 = parts1 + (size_t)b * G4;
        float gi = aldf(&P0[n])        + b1[n];
        float gf = aldf(&P0[1024 + n]) + b1[1024 + n];
        float gg = aldf(&P0[2048 + n]) + b1[2048 + n];
        float go = aldf(&P0[3072 + n]) + b1[3072 + n];
        float cv = sigm(gf) * c1reg + expf(gi) * tanhf(gg);
        float2 r = blk_sum2(cv, cv * cv, red, tid);
        float cl = lnorm(cv, r, lncg[HDIM + n], lncb[HDIM + n]);
        c1reg = cl;
        float hv = sigm(go) * tanhf(cl);
        r = blk_sum2(hv, hv * hv, red, tid);
        float h0v = bf2f(h0hi[(size_t)sp * HSLOT + b * HDIM + n])
                  + bf2f(h0lo[(size_t)sp * HSLOT + b * HDIM + n]);
        float hl = lnorm(hv, r, lnhg[HDIM + n], lnhb[HDIM + n]) + h0v;
        r = blk_sum2(hl, hl * hl, red, tid);
        float hn = lnorm(hl, r, lnog[HDIM + n], lnob[HDIM + n]);
        h1reg = hn;
        out[(size_t)tp * BSZ * HDIM + b * HDIM + n] = hn;
    }

    // ---- final states: h0, h1, c0, c1 ----
    {
        const size_t F = (size_t)TSTEPS * BSZ * HDIM;
        if (blk < 64) {
            out[F +          blk * HDIM + tid] = h0reg;
            out[F + 131072 + blk * HDIM + tid] = c0reg;
        } else if (blk < 128) {
            const int b = blk - 64;
            out[F +  65536 + b * HDIM + tid] = h1reg;
            out[F + 196608 + b * HDIM + tid] = c1reg;
        }
    }
}

// =====================================================================
// prep kernels
// =====================================================================
__global__ __launch_bounds__(256) void transpose_split(
    const float* __restrict__ src, int N,
    u16* __restrict__ dsthi, u16* __restrict__ dstlo,
    int ldd, int noff, int koff)
{
    __shared__ float tile[32][33];
    const int n0 = blockIdx.x * 32, k0 = blockIdx.y * 32;
    const int tx = threadIdx.x & 31, ty = threadIdx.x >> 5;
#pragma unroll
    for (int i = 0; i < 4; ++i)
        tile[ty + i * 8][tx] = src[(size_t)(k0 + ty + i * 8) * N + n0 + tx];
    __syncthreads();
#pragma unroll
    for (int i = 0; i < 4; ++i) {
        float v = tile[tx][ty + i * 8];
        u16 hi = f2bf(v);
        u16 lo = f2bf(v - bf2f(hi));
        size_t idx = (size_t)(n0 + ty + i * 8 + noff) * ldd + k0 + koff + tx;
        dsthi[idx] = hi;
        dstlo[idx] = lo;
    }
}

__global__ void conv_split(const float* __restrict__ src,
                           u16* __restrict__ hi, u16* __restrict__ lo, int n4)
{
    int i = blockIdx.x * 256 + threadIdx.x;
    if (i < n4) {
        float4 v = ((const float4*)src)[i];
        ushort4 h, l;
        h.x = f2bf(v.x); l.x = f2bf(v.x - bf2f(h.x));
        h.y = f2bf(v.y); l.y = f2bf(v.y - bf2f(h.y));
        h.z = f2bf(v.z); l.z = f2bf(v.z - bf2f(h.z));
        h.w = f2bf(v.w); l.w = f2bf(v.w - bf2f(h.w));
        ((ushort4*)hi)[i] = h;
        ((ushort4*)lo)[i] = l;
    }
}

// =====================================================================
extern "C" void kernel_launch(void* const* d_in, const int* in_sizes, int n_in,
                              void* d_out, int out_size, void* d_ws, size_t ws_size,
                              hipStream_t stream)
{
    const float* x     = (const float*)d_in[0];
    const float* Wproj = (const float*)d_in[1];
    const float* Wx0   = (const float*)d_in[2];
    const float* Wh0   = (const float*)d_in[3];
    const float* b0    = (const float*)d_in[4];
    const float* Wx1   = (const float*)d_in[5];
    const float* Wh1   = (const float*)d_in[6];
    const float* b1    = (const float*)d_in[7];
    const float* lnc_g = (const float*)d_in[8];
    const float* lnc_b = (const float*)d_in[9];
    const float* lnh_g = (const float*)d_in[10];
    const float* lnh_b = (const float*)d_in[11];
    const float* lno_g = (const float*)d_in[12];
    const float* lno_b = (const float*)d_in[13];
    float* out = (float*)d_out;

    // ---- ws layout (~118 MB) ----
    char* base = (char*)d_ws;
    size_t o = 0;
    u16* x_hi  = (u16*)(base + o); o += (size_t)TSTEPS * BSZ * INDIM * 2;
    u16* x_lo  = (u16*)(base + o); o += (size_t)TSTEPS * BSZ * INDIM * 2;
    u16* Whthi = (u16*)(base + o); o += (size_t)G4 * HDIM * 2;
    u16* Whtlo = (u16*)(base + o); o += (size_t)G4 * HDIM * 2;
    u16* Wxthi = (u16*)(base + o); o += (size_t)NX * INDIM * 2;
    u16* Wxtlo = (u16*)(base + o); o += (size_t)NX * INDIM * 2;
    u16* W1thi = (u16*)(base + o); o += (size_t)G4 * 2048 * 2;
    u16* W1tlo = (u16*)(base + o); o += (size_t)G4 * 2048 * 2;
    float* xg     = (float*)(base + o); o += (size_t)2 * CROWS * NX * 4;
    float* parts0 = (float*)(base + o); o += (size_t)BSZ * G4 * 4;
    float* parts1 = (float*)(base + o); o += (size_t)BSZ * G4 * 4;
    u16* h0hi = (u16*)(base + o); o += (size_t)HRING * HSLOT * 2;
    u16* h0lo = (u16*)(base + o); o += (size_t)HRING * HSLOT * 2;
    u16* h1hi = (u16*)(base + o); o += (size_t)HRING * HSLOT * 2;
    u16* h1lo = (u16*)(base + o); o += (size_t)HRING * HSLOT * 2;
    int* bar  = (int*)(base + o); o += 40960;
    if (ws_size < o) return;   // fail loudly (poisoned out) if ws too small

    // ---- prep ----
    conv_split<<<dim3(8192), 256, 0, stream>>>(x, x_hi, x_lo, 2097152);
    transpose_split<<<dim3(128, 32), 256, 0, stream>>>(Wh0, G4, Whthi, Whtlo, HDIM, 0, 0);
    transpose_split<<<dim3(128, 8),  256, 0, stream>>>(Wx0,   G4,   Wxthi, Wxtlo, INDIM, 0,    0);
    transpose_split<<<dim3(32, 8),   256, 0, stream>>>(Wproj, HDIM, Wxthi, Wxtlo, INDIM, 4096, 0);
    transpose_split<<<dim3(128, 32), 256, 0, stream>>>(Wx1, G4, W1thi, W1tlo, 2048, 0, 0);
    transpose_split<<<dim3(128, 32), 256, 0, stream>>>(Wh1, G4, W1thi, W1tlo, 2048, 0, 1024);
    // zero: parts0 (h0(-1)=0), h rings (first reads must be 0), barrier block
    hipMemsetAsync(parts0, 0, (size_t)BSZ * G4 * 4, stream);
    hipMemsetAsync(h0hi, 0, (size_t)4 * HRING * HSLOT * 2, stream);  // contiguous
    hipMemsetAsync(bar, 0, 40960, stream);

    // ---- the whole recurrence: one persistent kernel ----
    persistent<<<dim3(NBLK), dim3(NTHR), LDS_BYTES, stream>>>(
        x_hi, x_lo, Whthi, Whtlo, Wxthi, Wxtlo, W1thi, W1tlo, b0, b1,
        lnc_g, lnc_b, lnh_g, lnh_b, lno_g, lno_b,
        xg, parts0, parts1,
        h0hi, h0lo, h1hi, h1lo, out, bar);
}